// Round 1
// baseline (1868.830 us; speedup 1.0000x reference)
//
#include <hip/hip_runtime.h>
#include <hip/hip_bf16.h>
#include <cstdint>

#define BN_EPS 1e-5f

// ---------- helpers ----------
__device__ __forceinline__ float bf16hi_to_f(uint32_t hi) {
    union { uint32_t u; float f; } c; c.u = hi; return c.f;
}
__device__ __forceinline__ uint32_t f_to_bf16(float f) {
    union { float f; uint32_t u; } c; c.f = f;
    uint32_t r = c.u + 0x7fffu + ((c.u >> 16) & 1u);  // RNE
    return r >> 16;
}

// ---------- K0: BN affine precompute ----------
// affQ[0:64]=scale, affQ[64:128]=shift (incl conv bias); same for affK; affD 512+512 (no bias)
__global__ void pam_aff_kernel(const float* bq, const float* qs, const float* qb, const float* qm, const float* qv,
                               const float* bk, const float* ks, const float* kb, const float* km, const float* kv,
                               const float* ds, const float* db, const float* dm, const float* dv,
                               float* affQ, float* affK, float* affD) {
    int t = threadIdx.x;
    if (t < 64) {
        float inv = qs[t] * rsqrtf(qv[t] + BN_EPS);
        affQ[t] = inv; affQ[64 + t] = bq[t] * inv + qb[t] - qm[t] * inv;
    } else if (t < 128) {
        int i = t - 64;
        float inv = ks[i] * rsqrtf(kv[i] + BN_EPS);
        affK[i] = inv; affK[64 + i] = bk[i] * inv + kb[i] - km[i] * inv;
    } else {
        int i = t - 128;
        if (i < 512) {
            float inv = ds[i] * rsqrtf(dv[i] + BN_EPS);
            affD[i] = inv; affD[512 + i] = db[i] - dm[i] * inv;
        }
    }
}

// ---------- K1: transpose w_d (256,512,3,3) -> wdT[k9][ci][co] ----------
__global__ void pam_wdt_kernel(const float* __restrict__ wd, float* __restrict__ wdT) {
    int o = blockIdx.x * 256 + threadIdx.x;       // < 9*256*512
    int co = o & 511; int ci = (o >> 9) & 255; int kk = o >> 17;
    wdT[o] = wd[(ci * 512 + co) * 9 + kk];
}

// ---------- K2: fused q (1x1 conv + BN) and v (1x1 conv + bias) as one GEMM ----------
// rows 0..63 -> q (affine), rows 64..319 -> v (+bias). Output transposed:
// qT[b][p][64], vT[b][p][256]
__global__ __launch_bounds__(256) void pam_qv_gemm(
    const float* __restrict__ x, const float* __restrict__ wq, const float* __restrict__ wv,
    const float* __restrict__ bv, const float* __restrict__ affQ,
    float* __restrict__ qT, float* __restrict__ vT) {
    __shared__ float As[64][17];
    __shared__ __align__(16) float Bs[16][64];
    int t = threadIdx.x;
    int b = blockIdx.z, row0 = blockIdx.y * 64, p0 = blockIdx.x * 64;
    int tc = t & 15, tr = t >> 4;
    float acc[4][4] = {};
    int ra = t >> 2, kk4 = (t & 3) * 4;
    int Ra = row0 + ra;
    const float* wrow = (Ra < 64) ? (wq + (size_t)Ra * 512) : (wv + (size_t)(Ra - 64) * 512);
    const float* xb = x + (size_t)b * 512 * 4096;
    int kb_ = t >> 4, pb4 = (t & 15) * 4;
    for (int k0 = 0; k0 < 512; k0 += 16) {
        float4 a4 = *(const float4*)(wrow + k0 + kk4);
        As[ra][kk4 + 0] = a4.x; As[ra][kk4 + 1] = a4.y;
        As[ra][kk4 + 2] = a4.z; As[ra][kk4 + 3] = a4.w;
        *(float4*)&Bs[kb_][pb4] = *(const float4*)(xb + (size_t)(k0 + kb_) * 4096 + p0 + pb4);
        __syncthreads();
        #pragma unroll
        for (int kk = 0; kk < 16; ++kk) {
            float a[4], bb[4];
            #pragma unroll
            for (int i = 0; i < 4; i++) a[i] = As[tr * 4 + i][kk];
            #pragma unroll
            for (int j = 0; j < 4; j++) bb[j] = Bs[kk][tc * 4 + j];
            #pragma unroll
            for (int i = 0; i < 4; i++)
                #pragma unroll
                for (int j = 0; j < 4; j++) acc[i][j] = fmaf(a[i], bb[j], acc[i][j]);
        }
        __syncthreads();
    }
    #pragma unroll
    for (int i = 0; i < 4; i++) {
        int R = row0 + tr * 4 + i;
        if (R < 64) {
            float sc = affQ[R], sh = affQ[64 + R];
            #pragma unroll
            for (int j = 0; j < 4; j++) {
                int p = p0 + tc * 4 + j;
                qT[((size_t)b * 4096 + p) * 64 + R] = fmaf(acc[i][j], sc, sh);
            }
        } else {
            float bb = bv[R - 64];
            #pragma unroll
            for (int j = 0; j < 4; j++) {
                int p = p0 + tc * 4 + j;
                vT[((size_t)b * 4096 + p) * 256 + (R - 64)] = acc[i][j] + bb;
            }
        }
    }
}

// ---------- K3: k = 3x3 stride-2 pad-1 conv + BN -> kT[b][m][64] ----------
// each thread computes 2 d x 2 m (m, m+512 and d, d+32)
__global__ __launch_bounds__(256) void pam_kconv(
    const float* __restrict__ x, const float* __restrict__ wk,
    const float* __restrict__ affK, float* __restrict__ kT) {
    int gid = blockIdx.x * 256 + threadIdx.x;   // 131072 total
    int m = gid & 511;
    int d = (gid >> 9) & 31;
    int b = gid >> 14;
    int hk = m >> 5, wkx = m & 31;
    const float* xb = x + (size_t)b * 512 * 4096;
    const float* w0 = wk + (size_t)d * 4608;
    const float* w1 = wk + (size_t)(d + 32) * 4608;
    float a00 = 0, a01 = 0, a10 = 0, a11 = 0;
    for (int r = 0; r < 3; r++) {
        int hi1 = 2 * hk - 1 + r;      // [-1, 31]
        int hi2 = hi1 + 32;            // [31, 63] always valid
        bool v1r = (hi1 >= 0);
        for (int s = 0; s < 3; s++) {
            int wi = 2 * wkx - 1 + s;  // [-1, 63]
            bool vw = (wi >= 0);
            bool v1 = v1r && vw;
            const float* x1 = xb + hi1 * 64 + wi;
            const float* x2 = xb + hi2 * 64 + wi;
            const float* wp0 = w0 + r * 3 + s;
            const float* wp1 = w1 + r * 3 + s;
            #pragma unroll 4
            for (int c = 0; c < 512; c++) {
                float xv1 = v1 ? x1[(size_t)c * 4096] : 0.f;
                float xv2 = vw ? x2[(size_t)c * 4096] : 0.f;
                float wv0 = wp0[c * 9], wv1 = wp1[c * 9];
                a00 = fmaf(wv0, xv1, a00);
                a01 = fmaf(wv0, xv2, a01);
                a10 = fmaf(wv1, xv1, a10);
                a11 = fmaf(wv1, xv2, a11);
            }
        }
    }
    float s0 = affK[d], h0 = affK[64 + d];
    float s1 = affK[d + 32], h1 = affK[64 + d + 32];
    size_t base = (size_t)b * 1024 * 64;
    kT[base + (size_t)m * 64 + d]              = fmaf(a00, s0, h0);
    kT[base + (size_t)(m + 512) * 64 + d]      = fmaf(a01, s0, h0);
    kT[base + (size_t)m * 64 + d + 32]         = fmaf(a10, s1, h1);
    kT[base + (size_t)(m + 512) * 64 + d + 32] = fmaf(a11, s1, h1);
}

// ---------- K4: fused attention: energy -> softmax -> PV ----------
// block = (m-tile of 16 rows, b), 512 threads. P (probabilities) bf16 in LDS.
__global__ __launch_bounds__(512, 2) void pam_attn(
    const float* __restrict__ qT, const float* __restrict__ kT,
    const float* __restrict__ vT, float* __restrict__ outsT) {
    __shared__ __align__(16) float kt[1024];            // [mm][d]
    __shared__ float red[16][8];
    __shared__ float sinv[16];
    __shared__ __align__(16) unsigned short P[4096][16]; // 128 KiB, bf16 probs
    int t = threadIdx.x;
    int b = blockIdx.y, m0 = blockIdx.x * 16;
    if (t < 256)
        *(float4*)&kt[t * 4] = *(const float4*)(kT + ((size_t)b * 1024 + m0) * 64 + t * 4);
    __syncthreads();

    float e[16][8];
    #pragma unroll
    for (int mm = 0; mm < 16; mm++)
        #pragma unroll
        for (int j = 0; j < 8; j++) e[mm][j] = 0.f;

    const float* qb = qT + (size_t)b * 4096 * 64;
    #pragma unroll 1
    for (int d4 = 0; d4 < 16; ++d4) {
        float4 kv[16];
        #pragma unroll
        for (int mm = 0; mm < 16; mm++) kv[mm] = *(float4*)&kt[mm * 64 + d4 * 4];
        #pragma unroll
        for (int j = 0; j < 8; j++) {
            int n = j * 512 + t;
            float4 qv = *(const float4*)(qb + (size_t)n * 64 + d4 * 4);
            #pragma unroll
            for (int mm = 0; mm < 16; mm++) {
                e[mm][j] = fmaf(qv.x, kv[mm].x, e[mm][j]);
                e[mm][j] = fmaf(qv.y, kv[mm].y, e[mm][j]);
                e[mm][j] = fmaf(qv.z, kv[mm].z, e[mm][j]);
                e[mm][j] = fmaf(qv.w, kv[mm].w, e[mm][j]);
            }
        }
    }

    int lane = t & 63, wid = t >> 6;
    // row max
    #pragma unroll
    for (int mm = 0; mm < 16; mm++) {
        float lm = e[mm][0];
        #pragma unroll
        for (int j = 1; j < 8; j++) lm = fmaxf(lm, e[mm][j]);
        #pragma unroll
        for (int off = 1; off < 64; off <<= 1) lm = fmaxf(lm, __shfl_xor(lm, off));
        if (lane == 0) red[mm][wid] = lm;
    }
    __syncthreads();
    float M[16];
    #pragma unroll
    for (int mm = 0; mm < 16; mm++) {
        float mv = red[mm][0];
        #pragma unroll
        for (int w = 1; w < 8; w++) mv = fmaxf(mv, red[mm][w]);
        M[mm] = mv;
    }
    __syncthreads();
    // exp + row sum
    #pragma unroll
    for (int mm = 0; mm < 16; mm++) {
        float ls = 0.f;
        #pragma unroll
        for (int j = 0; j < 8; j++) {
            float p = __expf(e[mm][j] - M[mm]);
            e[mm][j] = p; ls += p;
        }
        #pragma unroll
        for (int off = 1; off < 64; off <<= 1) ls += __shfl_xor(ls, off);
        if (lane == 0) red[mm][wid] = ls;
    }
    __syncthreads();
    if (t < 16) {
        float s = 0.f;
        #pragma unroll
        for (int w = 0; w < 8; w++) s += red[t][w];
        sinv[t] = 1.f / s;
    }
    // store probabilities bf16: P[n][mm]
    #pragma unroll
    for (int j = 0; j < 8; j++) {
        int n = j * 512 + t;
        uint32_t u[8];
        #pragma unroll
        for (int q = 0; q < 8; q++)
            u[q] = f_to_bf16(e[2 * q][j]) | (f_to_bf16(e[2 * q + 1][j]) << 16);
        uint4* dst = (uint4*)&P[n][0];
        dst[0] = make_uint4(u[0], u[1], u[2], u[3]);
        dst[1] = make_uint4(u[4], u[5], u[6], u[7]);
    }
    __syncthreads();

    // PV: thread -> (v-channel c, m-half)
    int c = t & 255, half = t >> 8;
    const float* vb = vT + (size_t)b * 4096 * 256 + c;
    float acc[8] = {};
    #pragma unroll 4
    for (int n = 0; n < 4096; n++) {
        float vv = vb[(size_t)n * 256];
        uint4 pw = *((uint4*)&P[n][0] + half);
        float p0 = bf16hi_to_f(pw.x << 16), p1 = bf16hi_to_f(pw.x & 0xffff0000u);
        float p2 = bf16hi_to_f(pw.y << 16), p3 = bf16hi_to_f(pw.y & 0xffff0000u);
        float p4 = bf16hi_to_f(pw.z << 16), p5 = bf16hi_to_f(pw.z & 0xffff0000u);
        float p6 = bf16hi_to_f(pw.w << 16), p7 = bf16hi_to_f(pw.w & 0xffff0000u);
        acc[0] = fmaf(p0, vv, acc[0]); acc[1] = fmaf(p1, vv, acc[1]);
        acc[2] = fmaf(p2, vv, acc[2]); acc[3] = fmaf(p3, vv, acc[3]);
        acc[4] = fmaf(p4, vv, acc[4]); acc[5] = fmaf(p5, vv, acc[5]);
        acc[6] = fmaf(p6, vv, acc[6]); acc[7] = fmaf(p7, vv, acc[7]);
    }
    #pragma unroll
    for (int r = 0; r < 8; r++) {
        int mm = half * 8 + r;
        outsT[((size_t)b * 1024 + m0 + mm) * 256 + c] = acc[r] * sinv[mm];
    }
}

// ---------- K5: transpose-conv 3x3 s2 p1 op1 + BN + ReLU + residual ----------
// y[co,ho,wo] = sum_{kh,kw valid} sum_ci wd[ci,co,kh,kw] * outs[ci,(ho+1-kh)/2,(wo+1-kw)/2]
__global__ __launch_bounds__(512, 4) void pam_deconv(
    const float* __restrict__ outsT, const float* __restrict__ wdT,
    const float* __restrict__ affD, const float* __restrict__ x, float* __restrict__ out) {
    __shared__ float os[2][33][256];   // wi==32 column is zero padding (out_pad edge)
    int t = threadIdx.x;
    int ho = blockIdx.x, b = blockIdx.y;
    int pe = ho & 1;
    int hh = pe ? ((ho - 1) >> 1) : (ho >> 1);
    // stage outs rows hh and hh+1 (zero-filled when OOB)
    for (int idx = t; idx < 2 * 33 * 256; idx += 512) {
        int rr = idx / (33 * 256);
        int rem = idx - rr * (33 * 256);
        int wi = rem >> 8, ci = rem & 255;
        int hi = hh + rr;
        float val = 0.f;
        if (wi < 32 && hi < 32)
            val = outsT[((size_t)b * 1024 + hi * 32 + wi) * 256 + ci];
        os[rr][wi][ci] = val;
    }
    __syncthreads();

    int co = t;     // 512 threads = 512 output channels
    float acc[64];
    #pragma unroll
    for (int i = 0; i < 64; i++) acc[i] = 0.f;

    int nrr = pe ? 2 : 1;
    for (int rri = 0; rri < nrr; ++rri) {
        // pe==0: only tap kh=1 (row hh). pe==1: rri=0 -> kh=2 (row hh), rri=1 -> kh=0 (row hh+1)
        int kh = pe ? (rri == 0 ? 2 : 0) : 1;
        const float* w0 = wdT + ((size_t)(kh * 3 + 0) * 256) * 512 + co;
        const float* w1 = wdT + ((size_t)(kh * 3 + 1) * 256) * 512 + co;
        const float* w2 = wdT + ((size_t)(kh * 3 + 2) * 256) * 512 + co;
        const float* osr = &os[rri][0][0];
        for (int ci = 0; ci < 256; ++ci) {
            float wv0 = w0[(size_t)ci * 512], wv1 = w1[(size_t)ci * 512], wv2 = w2[(size_t)ci * 512];
            const float* op = osr + ci;
            float ov = op[0];
            #pragma unroll
            for (int ww = 0; ww < 32; ++ww) {
                float ovn = op[(ww + 1) * 256];
                // even wo=2*ww: kw=1, wi=ww ; odd wo=2*ww+1: kw=2 wi=ww, kw=0 wi=ww+1
                acc[2 * ww]     = fmaf(wv1, ov, acc[2 * ww]);
                acc[2 * ww + 1] = fmaf(wv2, ov, fmaf(wv0, ovn, acc[2 * ww + 1]));
                ov = ovn;
            }
        }
    }
    float sc = affD[co], sh = affD[512 + co];
    const float* xr = x + (((size_t)b * 512 + co) * 64 + ho) * 64;
    float* orow = out + (((size_t)b * 512 + co) * 64 + ho) * 64;
    #pragma unroll
    for (int wo = 0; wo < 64; ++wo) {
        float v = fmaf(acc[wo], sc, sh);
        v = fmaxf(v, 0.f) + xr[wo];
        orow[wo] = v;
    }
}

// ---------- launcher ----------
extern "C" void kernel_launch(void* const* d_in, const int* in_sizes, int n_in,
                              void* d_out, int out_size, void* d_ws, size_t ws_size,
                              hipStream_t stream) {
    const float* x   = (const float*)d_in[0];
    const float* w_q = (const float*)d_in[1];
    const float* b_q = (const float*)d_in[2];
    const float* qs  = (const float*)d_in[3];
    const float* qb  = (const float*)d_in[4];
    const float* qm  = (const float*)d_in[5];
    const float* qv  = (const float*)d_in[6];
    const float* w_k = (const float*)d_in[7];
    const float* b_k = (const float*)d_in[8];
    const float* ks  = (const float*)d_in[9];
    const float* kb  = (const float*)d_in[10];
    const float* km  = (const float*)d_in[11];
    const float* kv  = (const float*)d_in[12];
    const float* w_v = (const float*)d_in[13];
    const float* b_v = (const float*)d_in[14];
    const float* w_d = (const float*)d_in[15];
    const float* ds  = (const float*)d_in[16];
    const float* db  = (const float*)d_in[17];
    const float* dm  = (const float*)d_in[18];
    const float* dv  = (const float*)d_in[19];
    float* out = (float*)d_out;

    float* ws = (float*)d_ws;
    float* qT    = ws;                    // 8*4096*64   = 2097152
    float* vT    = qT + 2097152;          // 8*4096*256  = 8388608
    float* kT    = vT + 8388608;          // 8*1024*64   = 524288
    float* outsT = kT + 524288;           // 8*1024*256  = 2097152
    float* wdT   = outsT + 2097152;       // 9*256*512   = 1179648
    float* affQ  = wdT + 1179648;         // 128
    float* affK  = affQ + 128;            // 128
    float* affD  = affK + 128;            // 1024
    // total 14,288,128 floats = 57.2 MB

    hipLaunchKernelGGL(pam_aff_kernel, dim3(1), dim3(640), 0, stream,
                       b_q, qs, qb, qm, qv, b_k, ks, kb, km, kv, ds, db, dm, dv,
                       affQ, affK, affD);
    hipLaunchKernelGGL(pam_wdt_kernel, dim3(4608), dim3(256), 0, stream, w_d, wdT);
    hipLaunchKernelGGL(pam_qv_gemm, dim3(64, 5, 8), dim3(256), 0, stream,
                       x, w_q, w_v, b_v, affQ, qT, vT);
    hipLaunchKernelGGL(pam_kconv, dim3(512), dim3(256), 0, stream, x, w_k, affK, kT);
    hipLaunchKernelGGL(pam_attn, dim3(64, 8), dim3(512), 0, stream, qT, kT, vT, outsT);
    hipLaunchKernelGGL(pam_deconv, dim3(64, 8), dim3(512), 0, stream,
                       outsT, wdT, affD, x, out);
}

// Round 2
// 1342.185 us; speedup vs baseline: 1.3924x; 1.3924x over previous
//
#include <hip/hip_runtime.h>
#include <hip/hip_bf16.h>
#include <cstdint>

#define BN_EPS 1e-5f

typedef short bf16x8 __attribute__((ext_vector_type(8)));
typedef float f32x4 __attribute__((ext_vector_type(4)));

// ---------- helpers ----------
__device__ __forceinline__ float bf16hi_to_f(uint32_t hi) {
    union { uint32_t u; float f; } c; c.u = hi; return c.f;
}
__device__ __forceinline__ uint32_t f_to_bf16(float f) {
    union { float f; uint32_t u; } c; c.f = f;
    uint32_t r = c.u + 0x7fffu + ((c.u >> 16) & 1u);  // RNE
    return r >> 16;
}
__device__ __forceinline__ void split_bf16(float v, unsigned short& hi, unsigned short& lo) {
    uint32_t h = f_to_bf16(v);
    float fh = bf16hi_to_f(h << 16);
    uint32_t l = f_to_bf16(v - fh);
    hi = (unsigned short)h; lo = (unsigned short)l;
}

// ---------- K0: BN affine precompute ----------
__global__ void pam_aff_kernel(const float* bq, const float* qs, const float* qb, const float* qm, const float* qv,
                               const float* bk, const float* ks, const float* kb, const float* km, const float* kv,
                               const float* ds, const float* db, const float* dm, const float* dv,
                               float* affQ, float* affK, float* affD) {
    int t = threadIdx.x;
    if (t < 64) {
        float inv = qs[t] * rsqrtf(qv[t] + BN_EPS);
        affQ[t] = inv; affQ[64 + t] = bq[t] * inv + qb[t] - qm[t] * inv;
    } else if (t < 128) {
        int i = t - 64;
        float inv = ks[i] * rsqrtf(kv[i] + BN_EPS);
        affK[i] = inv; affK[64 + i] = bk[i] * inv + kb[i] - km[i] * inv;
    } else {
        int i = t - 128;
        if (i < 512) {
            float inv = ds[i] * rsqrtf(dv[i] + BN_EPS);
            affD[i] = inv; affD[512 + i] = db[i] - dm[i] * inv;
        }
    }
}

// ---------- K1: transpose w_d (256,512,3,3) -> wdT[k9][ci][co] ----------
__global__ void pam_wdt_kernel(const float* __restrict__ wd, float* __restrict__ wdT) {
    int o = blockIdx.x * 256 + threadIdx.x;       // < 9*256*512
    int co = o & 511; int ci = (o >> 9) & 255; int kk = o >> 17;
    wdT[o] = wd[(ci * 512 + co) * 9 + kk];
}

// ---------- K2: fused q (1x1 conv + BN) and v (1x1 conv + bias) as one GEMM ----------
// rows 0..63 -> q (affine) -> qTbhi/lo [b][p][64] bf16
// rows 64..319 -> v (+bias) -> vTc [b][c][4096] bf16
__global__ __launch_bounds__(256) void pam_qv_gemm(
    const float* __restrict__ x, const float* __restrict__ wq, const float* __restrict__ wv,
    const float* __restrict__ bv, const float* __restrict__ affQ,
    unsigned short* __restrict__ qTbhi, unsigned short* __restrict__ qTblo,
    unsigned short* __restrict__ vTc) {
    __shared__ float As[64][17];
    __shared__ __align__(16) float Bs[16][64];
    int t = threadIdx.x;
    int b = blockIdx.z, row0 = blockIdx.y * 64, p0 = blockIdx.x * 64;
    int tc = t & 15, tr = t >> 4;
    float acc[4][4] = {};
    int ra = t >> 2, kk4 = (t & 3) * 4;
    int Ra = row0 + ra;
    const float* wrow = (Ra < 64) ? (wq + (size_t)Ra * 512) : (wv + (size_t)(Ra - 64) * 512);
    const float* xb = x + (size_t)b * 512 * 4096;
    int kb_ = t >> 4, pb4 = (t & 15) * 4;
    for (int k0 = 0; k0 < 512; k0 += 16) {
        float4 a4 = *(const float4*)(wrow + k0 + kk4);
        As[ra][kk4 + 0] = a4.x; As[ra][kk4 + 1] = a4.y;
        As[ra][kk4 + 2] = a4.z; As[ra][kk4 + 3] = a4.w;
        *(float4*)&Bs[kb_][pb4] = *(const float4*)(xb + (size_t)(k0 + kb_) * 4096 + p0 + pb4);
        __syncthreads();
        #pragma unroll
        for (int kk = 0; kk < 16; ++kk) {
            float a[4], bb[4];
            #pragma unroll
            for (int i = 0; i < 4; i++) a[i] = As[tr * 4 + i][kk];
            #pragma unroll
            for (int j = 0; j < 4; j++) bb[j] = Bs[kk][tc * 4 + j];
            #pragma unroll
            for (int i = 0; i < 4; i++)
                #pragma unroll
                for (int j = 0; j < 4; j++) acc[i][j] = fmaf(a[i], bb[j], acc[i][j]);
        }
        __syncthreads();
    }
    #pragma unroll
    for (int i = 0; i < 4; i++) {
        int R = row0 + tr * 4 + i;
        if (R < 64) {
            float sc = affQ[R], sh = affQ[64 + R];
            #pragma unroll
            for (int j = 0; j < 4; j++) {
                int p = p0 + tc * 4 + j;
                float val = fmaf(acc[i][j], sc, sh);
                unsigned short hi, lo;
                split_bf16(val, hi, lo);
                size_t idx = ((size_t)b * 4096 + p) * 64 + R;
                qTbhi[idx] = hi; qTblo[idx] = lo;
            }
        } else {
            int c = R - 64;
            float bb = bv[c];
            ushort4 u;
            u.x = (unsigned short)f_to_bf16(acc[i][0] + bb);
            u.y = (unsigned short)f_to_bf16(acc[i][1] + bb);
            u.z = (unsigned short)f_to_bf16(acc[i][2] + bb);
            u.w = (unsigned short)f_to_bf16(acc[i][3] + bb);
            *(ushort4*)(vTc + ((size_t)b * 256 + c) * 4096 + p0 + tc * 4) = u;
        }
    }
}

// ---------- K3: k = 3x3 stride-2 pad-1 conv + BN -> kBhi/lo [b][m][64] bf16 ----------
__global__ __launch_bounds__(256) void pam_kconv(
    const float* __restrict__ x, const float* __restrict__ wk,
    const float* __restrict__ affK,
    unsigned short* __restrict__ kBhi, unsigned short* __restrict__ kBlo) {
    int gid = blockIdx.x * 256 + threadIdx.x;   // 131072 total
    int m = gid & 511;
    int d = (gid >> 9) & 31;
    int b = gid >> 14;
    int hk = m >> 5, wkx = m & 31;
    const float* xb = x + (size_t)b * 512 * 4096;
    const float* w0 = wk + (size_t)d * 4608;
    const float* w1 = wk + (size_t)(d + 32) * 4608;
    float a00 = 0, a01 = 0, a10 = 0, a11 = 0;
    for (int r = 0; r < 3; r++) {
        int hi1 = 2 * hk - 1 + r;
        int hi2 = hi1 + 32;
        bool v1r = (hi1 >= 0);
        for (int s = 0; s < 3; s++) {
            int wi = 2 * wkx - 1 + s;
            bool vw = (wi >= 0);
            bool v1 = v1r && vw;
            const float* x1 = xb + hi1 * 64 + wi;
            const float* x2 = xb + hi2 * 64 + wi;
            const float* wp0 = w0 + r * 3 + s;
            const float* wp1 = w1 + r * 3 + s;
            #pragma unroll 4
            for (int c = 0; c < 512; c++) {
                float xv1 = v1 ? x1[(size_t)c * 4096] : 0.f;
                float xv2 = vw ? x2[(size_t)c * 4096] : 0.f;
                float wv0 = wp0[c * 9], wv1 = wp1[c * 9];
                a00 = fmaf(wv0, xv1, a00);
                a01 = fmaf(wv0, xv2, a01);
                a10 = fmaf(wv1, xv1, a10);
                a11 = fmaf(wv1, xv2, a11);
            }
        }
    }
    float s0 = affK[d], h0 = affK[64 + d];
    float s1 = affK[d + 32], h1 = affK[64 + d + 32];
    float v00 = fmaf(a00, s0, h0);
    float v01 = fmaf(a01, s0, h0);
    float v10 = fmaf(a10, s1, h1);
    float v11 = fmaf(a11, s1, h1);
    size_t base = (size_t)b * 1024 * 64;
    size_t i00 = base + (size_t)m * 64 + d;
    size_t i01 = base + (size_t)(m + 512) * 64 + d;
    size_t i10 = i00 + 32;
    size_t i11 = i01 + 32;
    unsigned short hi, lo;
    split_bf16(v00, hi, lo); kBhi[i00] = hi; kBlo[i00] = lo;
    split_bf16(v01, hi, lo); kBhi[i01] = hi; kBlo[i01] = lo;
    split_bf16(v10, hi, lo); kBhi[i10] = hi; kBlo[i10] = lo;
    split_bf16(v11, hi, lo); kBhi[i11] = hi; kBlo[i11] = lo;
}

// ---------- K4: MFMA attention: energy (split-bf16) -> softmax -> PV ----------
// block = (16 m-rows, b), 512 threads = 8 waves. Wave w: n-chunk [w*512,(w+1)*512) for
// energy, c-slice [w*32,(w+1)*32) for PV. P~ bf16 in LDS [16][4096], XOR-swizzled.
__global__ __launch_bounds__(512, 2) void pam_attn(
    const unsigned short* __restrict__ qTbhi, const unsigned short* __restrict__ qTblo,
    const unsigned short* __restrict__ kBhi, const unsigned short* __restrict__ kBlo,
    const unsigned short* __restrict__ vTc, float* __restrict__ outsT) {
    __shared__ unsigned short Pl[16][4096];   // 128 KiB
    __shared__ float redM[8][16];
    __shared__ float redS[8][16];
    int t = threadIdx.x;
    int b = blockIdx.y, m0 = blockIdx.x * 16;
    int wid = t >> 6, lane = t & 63;
    int g = lane >> 4, lm = lane & 15;

    // --- K fragments (hi/lo), rows m0+lm, d = s*32 + g*8 + j ---
    const unsigned short* kh = kBhi + ((size_t)(b * 1024 + m0 + lm)) * 64 + g * 8;
    const unsigned short* kl = kBlo + ((size_t)(b * 1024 + m0 + lm)) * 64 + g * 8;
    bf16x8 ah0 = *(const bf16x8*)kh;
    bf16x8 ah1 = *(const bf16x8*)(kh + 32);
    bf16x8 al0 = *(const bf16x8*)kl;
    bf16x8 al1 = *(const bf16x8*)(kl + 32);

    // --- energy: E[16][512-chunk] in registers (32 frags) ---
    f32x4 ev[32];
    #pragma unroll
    for (int f = 0; f < 32; f++) ev[f] = (f32x4){0.f, 0.f, 0.f, 0.f};

    const unsigned short* qh = qTbhi + ((size_t)(b * 4096 + wid * 512 + lm)) * 64 + g * 8;
    const unsigned short* ql = qTblo + ((size_t)(b * 4096 + wid * 512 + lm)) * 64 + g * 8;
    #pragma unroll
    for (int f = 0; f < 32; f++) {
        const unsigned short* qhp = qh + (size_t)f * 16 * 64;
        const unsigned short* qlp = ql + (size_t)f * 16 * 64;
        bf16x8 bh0 = *(const bf16x8*)(qhp);
        bf16x8 bh1 = *(const bf16x8*)(qhp + 32);
        bf16x8 bl0 = *(const bf16x8*)(qlp);
        bf16x8 bl1 = *(const bf16x8*)(qlp + 32);
        f32x4 e = ev[f];
        e = __builtin_amdgcn_mfma_f32_16x16x32_bf16(ah0, bh0, e, 0, 0, 0);
        e = __builtin_amdgcn_mfma_f32_16x16x32_bf16(ah1, bh1, e, 0, 0, 0);
        e = __builtin_amdgcn_mfma_f32_16x16x32_bf16(ah0, bl0, e, 0, 0, 0);
        e = __builtin_amdgcn_mfma_f32_16x16x32_bf16(ah1, bl1, e, 0, 0, 0);
        e = __builtin_amdgcn_mfma_f32_16x16x32_bf16(al0, bh0, e, 0, 0, 0);
        e = __builtin_amdgcn_mfma_f32_16x16x32_bf16(al1, bh1, e, 0, 0, 0);
        ev[f] = e;
    }

    // --- row max (rows g*4+i), reduce over 16 lanes then 8 waves ---
    float rmax[4];
    #pragma unroll
    for (int i = 0; i < 4; i++) {
        float m_ = ev[0][i];
        #pragma unroll
        for (int f = 1; f < 32; f++) m_ = fmaxf(m_, ev[f][i]);
        #pragma unroll
        for (int off = 1; off < 16; off <<= 1) m_ = fmaxf(m_, __shfl_xor(m_, off));
        rmax[i] = m_;
    }
    if (lm == 0) {
        #pragma unroll
        for (int i = 0; i < 4; i++) redM[wid][g * 4 + i] = rmax[i];
    }
    __syncthreads();
    #pragma unroll
    for (int i = 0; i < 4; i++) {
        float m_ = redM[0][g * 4 + i];
        #pragma unroll
        for (int ww = 1; ww < 8; ww++) m_ = fmaxf(m_, redM[ww][g * 4 + i]);
        rmax[i] = m_;
    }

    // --- exp, bf16 round, accumulate sums of ROUNDED values, store to LDS swizzled ---
    float rsum[4] = {0.f, 0.f, 0.f, 0.f};
    #pragma unroll
    for (int f = 0; f < 32; f++) {
        int n = wid * 512 + f * 16 + lm;
        #pragma unroll
        for (int i = 0; i < 4; i++) {
            int r = g * 4 + i;
            float p = __expf(ev[f][i] - rmax[i]);
            uint32_t u = f_to_bf16(p);
            rsum[i] += bf16hi_to_f(u << 16);
            uint32_t byte = (((uint32_t)r << 13) + ((uint32_t)n << 1)) ^ (((uint32_t)(r & 7)) << 4);
            *(unsigned short*)((char*)&Pl[0][0] + byte) = (unsigned short)u;
        }
    }
    #pragma unroll
    for (int i = 0; i < 4; i++) {
        float s_ = rsum[i];
        #pragma unroll
        for (int off = 1; off < 16; off <<= 1) s_ += __shfl_xor(s_, off);
        rsum[i] = s_;
    }
    if (lm == 0) {
        #pragma unroll
        for (int i = 0; i < 4; i++) redS[wid][g * 4 + i] = rsum[i];
    }
    __syncthreads();   // P fully written + sums available
    float sinv[4];
    #pragma unroll
    for (int i = 0; i < 4; i++) {
        float s_ = 0.f;
        #pragma unroll
        for (int ww = 0; ww < 8; ww++) s_ += redS[ww][g * 4 + i];
        sinv[i] = 1.f / s_;
    }

    // --- PV: out[16][c-slice 32] += P~[16][n] * V[n][c] over n ---
    int c0 = wid * 32;
    f32x4 o0 = (f32x4){0.f, 0.f, 0.f, 0.f};
    f32x4 o1 = (f32x4){0.f, 0.f, 0.f, 0.f};
    const unsigned short* vbase0 = vTc + ((size_t)(b * 256 + c0 + lm)) * 4096 + g * 8;
    const unsigned short* vbase1 = vbase0 + (size_t)16 * 4096;
    const char* pbase = (const char*)&Pl[0][0];
    uint32_t poff_base = ((uint32_t)lm << 13) + ((uint32_t)g << 4);
    uint32_t sw = ((uint32_t)(lm & 7)) << 4;
    #pragma unroll 4
    for (int ks = 0; ks < 128; ks++) {
        bf16x8 pa = *(const bf16x8*)(pbase + ((poff_base + (uint32_t)ks * 64) ^ sw));
        bf16x8 b0 = *(const bf16x8*)(vbase0 + ks * 32);
        bf16x8 b1 = *(const bf16x8*)(vbase1 + ks * 32);
        o0 = __builtin_amdgcn_mfma_f32_16x16x32_bf16(pa, b0, o0, 0, 0, 0);
        o1 = __builtin_amdgcn_mfma_f32_16x16x32_bf16(pa, b1, o1, 0, 0, 0);
    }

    float* ob = outsT + ((size_t)b * 1024 + m0) * 256;
    #pragma unroll
    for (int i = 0; i < 4; i++) {
        int r = g * 4 + i;
        ob[(size_t)r * 256 + c0 + lm]      = o0[i] * sinv[i];
        ob[(size_t)r * 256 + c0 + 16 + lm] = o1[i] * sinv[i];
    }
}

// ---------- K5: transpose-conv 3x3 s2 p1 op1 + BN + ReLU + residual ----------
__global__ __launch_bounds__(512, 4) void pam_deconv(
    const float* __restrict__ outsT, const float* __restrict__ wdT,
    const float* __restrict__ affD, const float* __restrict__ x, float* __restrict__ out) {
    __shared__ float os[2][33][256];
    int t = threadIdx.x;
    int ho = blockIdx.x, b = blockIdx.y;
    int pe = ho & 1;
    int hh = pe ? ((ho - 1) >> 1) : (ho >> 1);
    for (int idx = t; idx < 2 * 33 * 256; idx += 512) {
        int rr = idx / (33 * 256);
        int rem = idx - rr * (33 * 256);
        int wi = rem >> 8, ci = rem & 255;
        int hi = hh + rr;
        float val = 0.f;
        if (wi < 32 && hi < 32)
            val = outsT[((size_t)b * 1024 + hi * 32 + wi) * 256 + ci];
        os[rr][wi][ci] = val;
    }
    __syncthreads();

    int co = t;
    float acc[64];
    #pragma unroll
    for (int i = 0; i < 64; i++) acc[i] = 0.f;

    int nrr = pe ? 2 : 1;
    for (int rri = 0; rri < nrr; ++rri) {
        int kh = pe ? (rri == 0 ? 2 : 0) : 1;
        const float* w0 = wdT + ((size_t)(kh * 3 + 0) * 256) * 512 + co;
        const float* w1 = wdT + ((size_t)(kh * 3 + 1) * 256) * 512 + co;
        const float* w2 = wdT + ((size_t)(kh * 3 + 2) * 256) * 512 + co;
        const float* osr = &os[rri][0][0];
        for (int ci = 0; ci < 256; ++ci) {
            float wv0 = w0[(size_t)ci * 512], wv1 = w1[(size_t)ci * 512], wv2 = w2[(size_t)ci * 512];
            const float* op = osr + ci;
            float ov = op[0];
            #pragma unroll
            for (int ww = 0; ww < 32; ++ww) {
                float ovn = op[(ww + 1) * 256];
                acc[2 * ww]     = fmaf(wv1, ov, acc[2 * ww]);
                acc[2 * ww + 1] = fmaf(wv2, ov, fmaf(wv0, ovn, acc[2 * ww + 1]));
                ov = ovn;
            }
        }
    }
    float sc = affD[co], sh = affD[512 + co];
    const float* xr = x + (((size_t)b * 512 + co) * 64 + ho) * 64;
    float* orow = out + (((size_t)b * 512 + co) * 64 + ho) * 64;
    #pragma unroll
    for (int wo = 0; wo < 64; ++wo) {
        float v = fmaf(acc[wo], sc, sh);
        v = fmaxf(v, 0.f) + xr[wo];
        orow[wo] = v;
    }
}

// ---------- launcher ----------
extern "C" void kernel_launch(void* const* d_in, const int* in_sizes, int n_in,
                              void* d_out, int out_size, void* d_ws, size_t ws_size,
                              hipStream_t stream) {
    const float* x   = (const float*)d_in[0];
    const float* w_q = (const float*)d_in[1];
    const float* b_q = (const float*)d_in[2];
    const float* qs  = (const float*)d_in[3];
    const float* qb  = (const float*)d_in[4];
    const float* qm  = (const float*)d_in[5];
    const float* qv  = (const float*)d_in[6];
    const float* w_k = (const float*)d_in[7];
    const float* b_k = (const float*)d_in[8];
    const float* ks  = (const float*)d_in[9];
    const float* kb  = (const float*)d_in[10];
    const float* km  = (const float*)d_in[11];
    const float* kv  = (const float*)d_in[12];
    const float* w_v = (const float*)d_in[13];
    const float* b_v = (const float*)d_in[14];
    const float* w_d = (const float*)d_in[15];
    const float* ds  = (const float*)d_in[16];
    const float* db  = (const float*)d_in[17];
    const float* dm  = (const float*)d_in[18];
    const float* dv  = (const float*)d_in[19];
    float* out = (float*)d_out;

    char* wsb = (char*)d_ws;
    unsigned short* qTbhi = (unsigned short*)(wsb);              //  4,194,304 B
    unsigned short* qTblo = (unsigned short*)(wsb + 4194304);    //  4,194,304 B
    unsigned short* vTc   = (unsigned short*)(wsb + 8388608);    // 16,777,216 B
    unsigned short* kBhi  = (unsigned short*)(wsb + 25165824);   //  1,048,576 B
    unsigned short* kBlo  = (unsigned short*)(wsb + 26214400);   //  1,048,576 B
    float*          outsT = (float*)(wsb + 27262976);            //  8,388,608 B
    float*          wdT   = (float*)(wsb + 35651584);            //  4,718,592 B
    float*          affQ  = (float*)(wsb + 40370176);            //  512 B
    float*          affK  = affQ + 128;
    float*          affD  = affK + 128;
    // total ~40.4 MB

    hipLaunchKernelGGL(pam_aff_kernel, dim3(1), dim3(640), 0, stream,
                       b_q, qs, qb, qm, qv, b_k, ks, kb, km, kv, ds, db, dm, dv,
                       affQ, affK, affD);
    hipLaunchKernelGGL(pam_wdt_kernel, dim3(4608), dim3(256), 0, stream, w_d, wdT);
    hipLaunchKernelGGL(pam_qv_gemm, dim3(64, 5, 8), dim3(256), 0, stream,
                       x, w_q, w_v, b_v, affQ, qTbhi, qTblo, vTc);
    hipLaunchKernelGGL(pam_kconv, dim3(512), dim3(256), 0, stream, x, w_k, kBhi ? affK : affK, kBhi, kBlo);
    hipLaunchKernelGGL(pam_attn, dim3(64, 8), dim3(512), 0, stream,
                       qTbhi, qTblo, kBhi, kBlo, vTc, outsT);
    hipLaunchKernelGGL(pam_deconv, dim3(64, 8), dim3(512), 0, stream,
                       outsT, wdT, affD, x, out);
}

// Round 3
// 859.841 us; speedup vs baseline: 2.1735x; 1.5610x over previous
//
#include <hip/hip_runtime.h>
#include <hip/hip_bf16.h>
#include <cstdint>

#define BN_EPS 1e-5f

typedef short bf16x8 __attribute__((ext_vector_type(8)));
typedef float f32x4 __attribute__((ext_vector_type(4)));

// ---------- helpers ----------
__device__ __forceinline__ float bf16hi_to_f(uint32_t hi) {
    union { uint32_t u; float f; } c; c.u = hi; return c.f;
}
__device__ __forceinline__ uint32_t f_to_bf16(float f) {
    union { float f; uint32_t u; } c; c.f = f;
    uint32_t r = c.u + 0x7fffu + ((c.u >> 16) & 1u);  // RNE
    return r >> 16;
}
__device__ __forceinline__ void split_bf16(float v, unsigned short& hi, unsigned short& lo) {
    uint32_t h = f_to_bf16(v);
    float fh = bf16hi_to_f(h << 16);
    uint32_t l = f_to_bf16(v - fh);
    hi = (unsigned short)h; lo = (unsigned short)l;
}

// ---------- K0: BN affine precompute ----------
__global__ void pam_aff_kernel(const float* bq, const float* qs, const float* qb, const float* qm, const float* qv,
                               const float* bk, const float* ks, const float* kb, const float* km, const float* kv,
                               const float* ds, const float* db, const float* dm, const float* dv,
                               float* affQ, float* affK, float* affD) {
    int t = threadIdx.x;
    if (t < 64) {
        float inv = qs[t] * rsqrtf(qv[t] + BN_EPS);
        affQ[t] = inv; affQ[64 + t] = bq[t] * inv + qb[t] - qm[t] * inv;
    } else if (t < 128) {
        int i = t - 64;
        float inv = ks[i] * rsqrtf(kv[i] + BN_EPS);
        affK[i] = inv; affK[64 + i] = bk[i] * inv + kb[i] - km[i] * inv;
    } else {
        int i = t - 128;
        if (i < 512) {
            float inv = ds[i] * rsqrtf(dv[i] + BN_EPS);
            affD[i] = inv; affD[512 + i] = db[i] - dm[i] * inv;
        }
    }
}

// ---------- K1: transpose w_d (256,512,3,3) -> wdT[k9][ci][co] ----------
__global__ void pam_wdt_kernel(const float* __restrict__ wd, float* __restrict__ wdT) {
    int o = blockIdx.x * 256 + threadIdx.x;       // < 9*256*512
    int co = o & 511; int ci = (o >> 9) & 255; int kk = o >> 17;
    wdT[o] = wd[(ci * 512 + co) * 9 + kk];
}

// ---------- K1b: transpose+split w_k (64,512,3,3) -> wkT{hi,lo}[k9][d][c] ----------
__global__ void pam_wkt(const float* __restrict__ wk,
                        unsigned short* __restrict__ wkThi, unsigned short* __restrict__ wkTlo) {
    int o = blockIdx.x * 256 + threadIdx.x;       // < 9*64*512 = 294912
    int c = o & 511; int d = (o >> 9) & 63; int kk = o >> 15;
    float v = wk[((size_t)d * 512 + c) * 9 + kk];
    unsigned short h, l;
    split_bf16(v, h, l);
    wkThi[o] = h; wkTlo[o] = l;
}

// ---------- K1c: x -> xTp{hi,lo}[b][65][65][512]  (pixel-major, c-contig, -1 pad) ----------
__global__ __launch_bounds__(256) void pam_xt(const float* __restrict__ x,
                                              unsigned short* __restrict__ xTphi,
                                              unsigned short* __restrict__ xTplo) {
    int t = threadIdx.x;
    int ri = blockIdx.x;       // 0..64 ; input row hi = ri-1
    int b = blockIdx.y;
    size_t rowbase = ((size_t)b * 65 + ri) * 65 * 512;
    uint4 z = make_uint4(0, 0, 0, 0);
    if (ri == 0) {
        for (int idx = t; idx < 65 * 512 / 8; idx += 256) {
            *(uint4*)(xTphi + rowbase + (size_t)idx * 8) = z;
            *(uint4*)(xTplo + rowbase + (size_t)idx * 8) = z;
        }
        return;
    }
    // guard col (wi = -1)
    if (t < 64) {
        *(uint4*)(xTphi + rowbase + (size_t)t * 8) = z;
        *(uint4*)(xTplo + rowbase + (size_t)t * 8) = z;
    }
    int hi = ri - 1;
    int wi = t & 63;
    const float* xb = x + (size_t)b * 512 * 4096 + (size_t)hi * 64 + wi;
    for (int it = 0; it < 16; ++it) {
        int cg = (t >> 6) + it * 4;     // 0..63
        int c0 = cg * 8;
        unsigned short h[8], l[8];
        #pragma unroll
        for (int j = 0; j < 8; j++) {
            float v = xb[(size_t)(c0 + j) * 4096];
            split_bf16(v, h[j], l[j]);
        }
        size_t dst = rowbase + (size_t)(wi + 1) * 512 + c0;
        uint4 ph = make_uint4((uint32_t)h[0] | ((uint32_t)h[1] << 16),
                              (uint32_t)h[2] | ((uint32_t)h[3] << 16),
                              (uint32_t)h[4] | ((uint32_t)h[5] << 16),
                              (uint32_t)h[6] | ((uint32_t)h[7] << 16));
        uint4 pl = make_uint4((uint32_t)l[0] | ((uint32_t)l[1] << 16),
                              (uint32_t)l[2] | ((uint32_t)l[3] << 16),
                              (uint32_t)l[4] | ((uint32_t)l[5] << 16),
                              (uint32_t)l[6] | ((uint32_t)l[7] << 16));
        *(uint4*)(xTphi + dst) = ph;
        *(uint4*)(xTplo + dst) = pl;
    }
}

// ---------- K2: fused q (1x1 conv + BN) and v (1x1 conv + bias) as one GEMM ----------
__global__ __launch_bounds__(256) void pam_qv_gemm(
    const float* __restrict__ x, const float* __restrict__ wq, const float* __restrict__ wv,
    const float* __restrict__ bv, const float* __restrict__ affQ,
    unsigned short* __restrict__ qTbhi, unsigned short* __restrict__ qTblo,
    unsigned short* __restrict__ vTc) {
    __shared__ float As[64][17];
    __shared__ __align__(16) float Bs[16][64];
    int t = threadIdx.x;
    int b = blockIdx.z, row0 = blockIdx.y * 64, p0 = blockIdx.x * 64;
    int tc = t & 15, tr = t >> 4;
    float acc[4][4] = {};
    int ra = t >> 2, kk4 = (t & 3) * 4;
    int Ra = row0 + ra;
    const float* wrow = (Ra < 64) ? (wq + (size_t)Ra * 512) : (wv + (size_t)(Ra - 64) * 512);
    const float* xb = x + (size_t)b * 512 * 4096;
    int kb_ = t >> 4, pb4 = (t & 15) * 4;
    for (int k0 = 0; k0 < 512; k0 += 16) {
        float4 a4 = *(const float4*)(wrow + k0 + kk4);
        As[ra][kk4 + 0] = a4.x; As[ra][kk4 + 1] = a4.y;
        As[ra][kk4 + 2] = a4.z; As[ra][kk4 + 3] = a4.w;
        *(float4*)&Bs[kb_][pb4] = *(const float4*)(xb + (size_t)(k0 + kb_) * 4096 + p0 + pb4);
        __syncthreads();
        #pragma unroll
        for (int kk = 0; kk < 16; ++kk) {
            float a[4], bb[4];
            #pragma unroll
            for (int i = 0; i < 4; i++) a[i] = As[tr * 4 + i][kk];
            #pragma unroll
            for (int j = 0; j < 4; j++) bb[j] = Bs[kk][tc * 4 + j];
            #pragma unroll
            for (int i = 0; i < 4; i++)
                #pragma unroll
                for (int j = 0; j < 4; j++) acc[i][j] = fmaf(a[i], bb[j], acc[i][j]);
        }
        __syncthreads();
    }
    #pragma unroll
    for (int i = 0; i < 4; i++) {
        int R = row0 + tr * 4 + i;
        if (R < 64) {
            float sc = affQ[R], sh = affQ[64 + R];
            #pragma unroll
            for (int j = 0; j < 4; j++) {
                int p = p0 + tc * 4 + j;
                float val = fmaf(acc[i][j], sc, sh);
                unsigned short hi, lo;
                split_bf16(val, hi, lo);
                size_t idx = ((size_t)b * 4096 + p) * 64 + R;
                qTbhi[idx] = hi; qTblo[idx] = lo;
            }
        } else {
            int c = R - 64;
            float bb = bv[c];
            ushort4 u;
            u.x = (unsigned short)f_to_bf16(acc[i][0] + bb);
            u.y = (unsigned short)f_to_bf16(acc[i][1] + bb);
            u.z = (unsigned short)f_to_bf16(acc[i][2] + bb);
            u.w = (unsigned short)f_to_bf16(acc[i][3] + bb);
            *(ushort4*)(vTc + ((size_t)b * 256 + c) * 4096 + p0 + tc * 4) = u;
        }
    }
}

// ---------- K3: k-conv as tap-decomposed MFMA GEMM ----------
// block = (output row hk, b), 256 thr = 4 waves; wave -> 16 d cols.
// C[rows = 32 pixels of row hk][cols = 64 d], K = 9 taps x 512 c, 3-term hi/lo.
__global__ __launch_bounds__(256) void pam_kconv_mfma(
    const unsigned short* __restrict__ xTphi, const unsigned short* __restrict__ xTplo,
    const unsigned short* __restrict__ wkThi, const unsigned short* __restrict__ wkTlo,
    const float* __restrict__ affK,
    unsigned short* __restrict__ kBhi, unsigned short* __restrict__ kBlo) {
    int t = threadIdx.x;
    int hk = blockIdx.x, b = blockIdx.y;
    int wv = t >> 6, lane = t & 63, g = lane >> 4, lm = lane & 15;
    int goff = g * 8;
    f32x4 acc0 = (f32x4){0.f, 0.f, 0.f, 0.f};
    f32x4 acc1 = (f32x4){0.f, 0.f, 0.f, 0.f};
    #pragma unroll
    for (int r = 0; r < 3; r++) {
        size_t arow = ((size_t)(b * 65 + 2 * hk + r)) * 65 * 512;
        #pragma unroll
        for (int s = 0; s < 3; s++) {
            size_t aoff = arow + (size_t)(2 * lm + s) * 512 + goff;   // pixel wk=lm
            const unsigned short* pa0h = xTphi + aoff;
            const unsigned short* pa0l = xTplo + aoff;
            size_t boff = ((size_t)((r * 3 + s) * 64 + wv * 16 + lm)) * 512 + goff;
            const unsigned short* pb_h = wkThi + boff;
            const unsigned short* pb_l = wkTlo + boff;
            #pragma unroll 4
            for (int c0 = 0; c0 < 512; c0 += 32) {
                bf16x8 a0h = *(const bf16x8*)(pa0h + c0);
                bf16x8 a1h = *(const bf16x8*)(pa0h + 32 * 512 + c0);   // pixel wk=lm+16
                bf16x8 a0l = *(const bf16x8*)(pa0l + c0);
                bf16x8 a1l = *(const bf16x8*)(pa0l + 32 * 512 + c0);
                bf16x8 bh  = *(const bf16x8*)(pb_h + c0);
                bf16x8 bl  = *(const bf16x8*)(pb_l + c0);
                acc0 = __builtin_amdgcn_mfma_f32_16x16x32_bf16(a0h, bh, acc0, 0, 0, 0);
                acc1 = __builtin_amdgcn_mfma_f32_16x16x32_bf16(a1h, bh, acc1, 0, 0, 0);
                acc0 = __builtin_amdgcn_mfma_f32_16x16x32_bf16(a0l, bh, acc0, 0, 0, 0);
                acc1 = __builtin_amdgcn_mfma_f32_16x16x32_bf16(a1l, bh, acc1, 0, 0, 0);
                acc0 = __builtin_amdgcn_mfma_f32_16x16x32_bf16(a0h, bl, acc0, 0, 0, 0);
                acc1 = __builtin_amdgcn_mfma_f32_16x16x32_bf16(a1h, bl, acc1, 0, 0, 0);
            }
        }
    }
    int d = wv * 16 + lm;
    float sc = affK[d], sh = affK[64 + d];
    size_t base = (size_t)b * 1024 * 64 + (size_t)hk * 32 * 64 + d;
    #pragma unroll
    for (int i = 0; i < 4; i++) {
        int wk0 = g * 4 + i;                 // pixel within row (acc0)
        float v0 = fmaf(acc0[i], sc, sh);
        float v1 = fmaf(acc1[i], sc, sh);
        unsigned short hh, ll;
        split_bf16(v0, hh, ll);
        kBhi[base + (size_t)wk0 * 64] = hh; kBlo[base + (size_t)wk0 * 64] = ll;
        split_bf16(v1, hh, ll);
        kBhi[base + (size_t)(wk0 + 16) * 64] = hh; kBlo[base + (size_t)(wk0 + 16) * 64] = ll;
    }
}

// ---------- K4: MFMA attention: energy (split-bf16) -> softmax -> PV ----------
__global__ __launch_bounds__(512, 2) void pam_attn(
    const unsigned short* __restrict__ qTbhi, const unsigned short* __restrict__ qTblo,
    const unsigned short* __restrict__ kBhi, const unsigned short* __restrict__ kBlo,
    const unsigned short* __restrict__ vTc, float* __restrict__ outsT) {
    __shared__ unsigned short Pl[16][4096];   // 128 KiB
    __shared__ float redM[8][16];
    __shared__ float redS[8][16];
    int t = threadIdx.x;
    int b = blockIdx.y, m0 = blockIdx.x * 16;
    int wid = t >> 6, lane = t & 63;
    int g = lane >> 4, lm = lane & 15;

    const unsigned short* kh = kBhi + ((size_t)(b * 1024 + m0 + lm)) * 64 + g * 8;
    const unsigned short* kl = kBlo + ((size_t)(b * 1024 + m0 + lm)) * 64 + g * 8;
    bf16x8 ah0 = *(const bf16x8*)kh;
    bf16x8 ah1 = *(const bf16x8*)(kh + 32);
    bf16x8 al0 = *(const bf16x8*)kl;
    bf16x8 al1 = *(const bf16x8*)(kl + 32);

    f32x4 ev[32];
    #pragma unroll
    for (int f = 0; f < 32; f++) ev[f] = (f32x4){0.f, 0.f, 0.f, 0.f};

    const unsigned short* qh = qTbhi + ((size_t)(b * 4096 + wid * 512 + lm)) * 64 + g * 8;
    const unsigned short* ql = qTblo + ((size_t)(b * 4096 + wid * 512 + lm)) * 64 + g * 8;
    #pragma unroll
    for (int f = 0; f < 32; f++) {
        const unsigned short* qhp = qh + (size_t)f * 16 * 64;
        const unsigned short* qlp = ql + (size_t)f * 16 * 64;
        bf16x8 bh0 = *(const bf16x8*)(qhp);
        bf16x8 bh1 = *(const bf16x8*)(qhp + 32);
        bf16x8 bl0 = *(const bf16x8*)(qlp);
        bf16x8 bl1 = *(const bf16x8*)(qlp + 32);
        f32x4 e = ev[f];
        e = __builtin_amdgcn_mfma_f32_16x16x32_bf16(ah0, bh0, e, 0, 0, 0);
        e = __builtin_amdgcn_mfma_f32_16x16x32_bf16(ah1, bh1, e, 0, 0, 0);
        e = __builtin_amdgcn_mfma_f32_16x16x32_bf16(ah0, bl0, e, 0, 0, 0);
        e = __builtin_amdgcn_mfma_f32_16x16x32_bf16(ah1, bl1, e, 0, 0, 0);
        e = __builtin_amdgcn_mfma_f32_16x16x32_bf16(al0, bh0, e, 0, 0, 0);
        e = __builtin_amdgcn_mfma_f32_16x16x32_bf16(al1, bh1, e, 0, 0, 0);
        ev[f] = e;
    }

    float rmax[4];
    #pragma unroll
    for (int i = 0; i < 4; i++) {
        float m_ = ev[0][i];
        #pragma unroll
        for (int f = 1; f < 32; f++) m_ = fmaxf(m_, ev[f][i]);
        #pragma unroll
        for (int off = 1; off < 16; off <<= 1) m_ = fmaxf(m_, __shfl_xor(m_, off));
        rmax[i] = m_;
    }
    if (lm == 0) {
        #pragma unroll
        for (int i = 0; i < 4; i++) redM[wid][g * 4 + i] = rmax[i];
    }
    __syncthreads();
    #pragma unroll
    for (int i = 0; i < 4; i++) {
        float m_ = redM[0][g * 4 + i];
        #pragma unroll
        for (int ww = 1; ww < 8; ww++) m_ = fmaxf(m_, redM[ww][g * 4 + i]);
        rmax[i] = m_;
    }

    float rsum[4] = {0.f, 0.f, 0.f, 0.f};
    #pragma unroll
    for (int f = 0; f < 32; f++) {
        int n = wid * 512 + f * 16 + lm;
        #pragma unroll
        for (int i = 0; i < 4; i++) {
            int r = g * 4 + i;
            float p = __expf(ev[f][i] - rmax[i]);
            uint32_t u = f_to_bf16(p);
            rsum[i] += bf16hi_to_f(u << 16);
            uint32_t byte = (((uint32_t)r << 13) + ((uint32_t)n << 1)) ^ (((uint32_t)(r & 7)) << 4);
            *(unsigned short*)((char*)&Pl[0][0] + byte) = (unsigned short)u;
        }
    }
    #pragma unroll
    for (int i = 0; i < 4; i++) {
        float s_ = rsum[i];
        #pragma unroll
        for (int off = 1; off < 16; off <<= 1) s_ += __shfl_xor(s_, off);
        rsum[i] = s_;
    }
    if (lm == 0) {
        #pragma unroll
        for (int i = 0; i < 4; i++) redS[wid][g * 4 + i] = rsum[i];
    }
    __syncthreads();
    float sinv[4];
    #pragma unroll
    for (int i = 0; i < 4; i++) {
        float s_ = 0.f;
        #pragma unroll
        for (int ww = 0; ww < 8; ww++) s_ += redS[ww][g * 4 + i];
        sinv[i] = 1.f / s_;
    }

    int c0 = wid * 32;
    f32x4 o0 = (f32x4){0.f, 0.f, 0.f, 0.f};
    f32x4 o1 = (f32x4){0.f, 0.f, 0.f, 0.f};
    const unsigned short* vbase0 = vTc + ((size_t)(b * 256 + c0 + lm)) * 4096 + g * 8;
    const unsigned short* vbase1 = vbase0 + (size_t)16 * 4096;
    const char* pbase = (const char*)&Pl[0][0];
    uint32_t poff_base = ((uint32_t)lm << 13) + ((uint32_t)g << 4);
    uint32_t sw = ((uint32_t)(lm & 7)) << 4;
    #pragma unroll 4
    for (int ks = 0; ks < 128; ks++) {
        bf16x8 pa = *(const bf16x8*)(pbase + ((poff_base + (uint32_t)ks * 64) ^ sw));
        bf16x8 b0 = *(const bf16x8*)(vbase0 + ks * 32);
        bf16x8 b1 = *(const bf16x8*)(vbase1 + ks * 32);
        o0 = __builtin_amdgcn_mfma_f32_16x16x32_bf16(pa, b0, o0, 0, 0, 0);
        o1 = __builtin_amdgcn_mfma_f32_16x16x32_bf16(pa, b1, o1, 0, 0, 0);
    }

    float* ob = outsT + ((size_t)b * 1024 + m0) * 256;
    #pragma unroll
    for (int i = 0; i < 4; i++) {
        int r = g * 4 + i;
        ob[(size_t)r * 256 + c0 + lm]      = o0[i] * sinv[i];
        ob[(size_t)r * 256 + c0 + 16 + lm] = o1[i] * sinv[i];
    }
}

// ---------- K5: transpose-conv 3x3 s2 p1 op1 + BN + ReLU + residual ----------
__global__ __launch_bounds__(512, 4) void pam_deconv(
    const float* __restrict__ outsT, const float* __restrict__ wdT,
    const float* __restrict__ affD, const float* __restrict__ x, float* __restrict__ out) {
    __shared__ float os[2][33][256];
    int t = threadIdx.x;
    int ho = blockIdx.x, b = blockIdx.y;
    int pe = ho & 1;
    int hh = pe ? ((ho - 1) >> 1) : (ho >> 1);
    for (int idx = t; idx < 2 * 33 * 256; idx += 512) {
        int rr = idx / (33 * 256);
        int rem = idx - rr * (33 * 256);
        int wi = rem >> 8, ci = rem & 255;
        int hi = hh + rr;
        float val = 0.f;
        if (wi < 32 && hi < 32)
            val = outsT[((size_t)b * 1024 + hi * 32 + wi) * 256 + ci];
        os[rr][wi][ci] = val;
    }
    __syncthreads();

    int co = t;
    float acc[64];
    #pragma unroll
    for (int i = 0; i < 64; i++) acc[i] = 0.f;

    int nrr = pe ? 2 : 1;
    for (int rri = 0; rri < nrr; ++rri) {
        int kh = pe ? (rri == 0 ? 2 : 0) : 1;
        const float* w0 = wdT + ((size_t)(kh * 3 + 0) * 256) * 512 + co;
        const float* w1 = wdT + ((size_t)(kh * 3 + 1) * 256) * 512 + co;
        const float* w2 = wdT + ((size_t)(kh * 3 + 2) * 256) * 512 + co;
        const float* osr = &os[rri][0][0];
        for (int ci = 0; ci < 256; ++ci) {
            float wv0 = w0[(size_t)ci * 512], wv1 = w1[(size_t)ci * 512], wv2 = w2[(size_t)ci * 512];
            const float* op = osr + ci;
            float ov = op[0];
            #pragma unroll
            for (int ww = 0; ww < 32; ++ww) {
                float ovn = op[(ww + 1) * 256];
                acc[2 * ww]     = fmaf(wv1, ov, acc[2 * ww]);
                acc[2 * ww + 1] = fmaf(wv2, ov, fmaf(wv0, ovn, acc[2 * ww + 1]));
                ov = ovn;
            }
        }
    }
    float sc = affD[co], sh = affD[512 + co];
    const float* xr = x + (((size_t)b * 512 + co) * 64 + ho) * 64;
    float* orow = out + (((size_t)b * 512 + co) * 64 + ho) * 64;
    #pragma unroll
    for (int wo = 0; wo < 64; ++wo) {
        float v = fmaf(acc[wo], sc, sh);
        v = fmaxf(v, 0.f) + xr[wo];
        orow[wo] = v;
    }
}

// ---------- launcher ----------
extern "C" void kernel_launch(void* const* d_in, const int* in_sizes, int n_in,
                              void* d_out, int out_size, void* d_ws, size_t ws_size,
                              hipStream_t stream) {
    const float* x   = (const float*)d_in[0];
    const float* w_q = (const float*)d_in[1];
    const float* b_q = (const float*)d_in[2];
    const float* qs  = (const float*)d_in[3];
    const float* qb  = (const float*)d_in[4];
    const float* qm  = (const float*)d_in[5];
    const float* qv  = (const float*)d_in[6];
    const float* w_k = (const float*)d_in[7];
    const float* b_k = (const float*)d_in[8];
    const float* ks  = (const float*)d_in[9];
    const float* kb  = (const float*)d_in[10];
    const float* km  = (const float*)d_in[11];
    const float* kv  = (const float*)d_in[12];
    const float* w_v = (const float*)d_in[13];
    const float* b_v = (const float*)d_in[14];
    const float* w_d = (const float*)d_in[15];
    const float* ds  = (const float*)d_in[16];
    const float* db  = (const float*)d_in[17];
    const float* dm  = (const float*)d_in[18];
    const float* dv  = (const float*)d_in[19];
    float* out = (float*)d_out;

    char* wsb = (char*)d_ws;
    unsigned short* qTbhi = (unsigned short*)(wsb);               //  4,194,304
    unsigned short* qTblo = (unsigned short*)(wsb + 4194304);     //  4,194,304
    unsigned short* vTc   = (unsigned short*)(wsb + 8388608);     // 16,777,216
    unsigned short* kBhi  = (unsigned short*)(wsb + 25165824);    //  1,048,576
    unsigned short* kBlo  = (unsigned short*)(wsb + 26214400);    //  1,048,576
    unsigned short* wkThi = (unsigned short*)(wsb + 27262976);    //    589,824
    unsigned short* wkTlo = (unsigned short*)(wsb + 27852800);    //    589,824
    float*          affQ  = (float*)(wsb + 28442624);             //        512
    float*          affK  = (float*)(wsb + 28443136);             //        512
    float*          affD  = (float*)(wsb + 28443648);             //      4,096
    // X region: xTp{hi,lo} live [pam_xt .. pam_kconv_mfma]; outsT/wdT aliased after.
    unsigned short* xTphi = (unsigned short*)(wsb + 28447744);    // 34,611,200
    unsigned short* xTplo = (unsigned short*)(wsb + 63058944);    // 34,611,200 -> end 97,670,144
    float*          outsT = (float*)(wsb + 28447744);             //  8,388,608 (alias)
    float*          wdT   = (float*)(wsb + 36836352);             //  4,718,592 (alias)

    hipLaunchKernelGGL(pam_aff_kernel, dim3(1), dim3(640), 0, stream,
                       b_q, qs, qb, qm, qv, b_k, ks, kb, km, kv, ds, db, dm, dv,
                       affQ, affK, affD);
    hipLaunchKernelGGL(pam_wkt, dim3(1152), dim3(256), 0, stream, w_k, wkThi, wkTlo);
    hipLaunchKernelGGL(pam_xt, dim3(65, 8), dim3(256), 0, stream, x, xTphi, xTplo);
    hipLaunchKernelGGL(pam_qv_gemm, dim3(64, 5, 8), dim3(256), 0, stream,
                       x, w_q, w_v, b_v, affQ, qTbhi, qTblo, vTc);
    hipLaunchKernelGGL(pam_kconv_mfma, dim3(32, 8), dim3(256), 0, stream,
                       xTphi, xTplo, wkThi, wkTlo, affK, kBhi, kBlo);
    // xTp dead from here; outsT/wdT may reuse the region.
    hipLaunchKernelGGL(pam_wdt_kernel, dim3(4608), dim3(256), 0, stream, w_d, wdT);
    hipLaunchKernelGGL(pam_attn, dim3(64, 8), dim3(512), 0, stream,
                       qTbhi, qTblo, kBhi, kBlo, vTc, outsT);
    hipLaunchKernelGGL(pam_deconv, dim3(64, 8), dim3(512), 0, stream,
                       outsT, wdT, affD, x, out);
}

// Round 4
// 706.492 us; speedup vs baseline: 2.6452x; 1.2171x over previous
//
#include <hip/hip_runtime.h>
#include <hip/hip_bf16.h>
#include <cstdint>

#define BN_EPS 1e-5f

typedef short bf16x8 __attribute__((ext_vector_type(8)));
typedef float f32x4 __attribute__((ext_vector_type(4)));

// ---------- helpers ----------
__device__ __forceinline__ float bf16hi_to_f(uint32_t hi) {
    union { uint32_t u; float f; } c; c.u = hi; return c.f;
}
__device__ __forceinline__ uint32_t f_to_bf16(float f) {
    union { float f; uint32_t u; } c; c.f = f;
    uint32_t r = c.u + 0x7fffu + ((c.u >> 16) & 1u);  // RNE
    return r >> 16;
}
__device__ __forceinline__ void split_bf16(float v, unsigned short& hi, unsigned short& lo) {
    uint32_t h = f_to_bf16(v);
    float fh = bf16hi_to_f(h << 16);
    uint32_t l = f_to_bf16(v - fh);
    hi = (unsigned short)h; lo = (unsigned short)l;
}

// ---------- K0: BN affine precompute ----------
__global__ void pam_aff_kernel(const float* bq, const float* qs, const float* qb, const float* qm, const float* qv,
                               const float* bk, const float* ks, const float* kb, const float* km, const float* kv,
                               const float* ds, const float* db, const float* dm, const float* dv,
                               float* affQ, float* affK, float* affD) {
    int t = threadIdx.x;
    if (t < 64) {
        float inv = qs[t] * rsqrtf(qv[t] + BN_EPS);
        affQ[t] = inv; affQ[64 + t] = bq[t] * inv + qb[t] - qm[t] * inv;
    } else if (t < 128) {
        int i = t - 64;
        float inv = ks[i] * rsqrtf(kv[i] + BN_EPS);
        affK[i] = inv; affK[64 + i] = bk[i] * inv + kb[i] - km[i] * inv;
    } else {
        int i = t - 128;
        if (i < 512) {
            float inv = ds[i] * rsqrtf(dv[i] + BN_EPS);
            affD[i] = inv; affD[512 + i] = db[i] - dm[i] * inv;
        }
    }
}

// ---------- K1: transpose+split w_d (256,512,3,3) -> wdTb{hi,lo}[tap][co][ci] ----------
__global__ void pam_wdtb(const float* __restrict__ wd,
                         unsigned short* __restrict__ wdTbhi, unsigned short* __restrict__ wdTblo) {
    int o = blockIdx.x * 256 + threadIdx.x;       // < 9*512*256 = 1,179,648
    int ci = o & 255; int co = (o >> 8) & 511; int tap = o >> 17;
    float v = wd[(size_t)ci * 4608 + co * 9 + tap];
    unsigned short h, l;
    split_bf16(v, h, l);
    wdTbhi[o] = h; wdTblo[o] = l;
}

// ---------- K1b: transpose+split w_k (64,512,3,3) -> wkT{hi,lo}[k9][d][c] ----------
__global__ void pam_wkt(const float* __restrict__ wk,
                        unsigned short* __restrict__ wkThi, unsigned short* __restrict__ wkTlo) {
    int o = blockIdx.x * 256 + threadIdx.x;       // < 9*64*512 = 294912
    int c = o & 511; int d = (o >> 9) & 63; int kk = o >> 15;
    float v = wk[((size_t)d * 512 + c) * 9 + kk];
    unsigned short h, l;
    split_bf16(v, h, l);
    wkThi[o] = h; wkTlo[o] = l;
}

// ---------- K1c: x -> xTp{hi,lo}[b][65][65][512]  (pixel-major, c-contig, -1 pad) ----------
__global__ __launch_bounds__(256) void pam_xt(const float* __restrict__ x,
                                              unsigned short* __restrict__ xTphi,
                                              unsigned short* __restrict__ xTplo) {
    int t = threadIdx.x;
    int ri = blockIdx.x;       // 0..64 ; input row hi = ri-1
    int b = blockIdx.y;
    size_t rowbase = ((size_t)b * 65 + ri) * 65 * 512;
    uint4 z = make_uint4(0, 0, 0, 0);
    if (ri == 0) {
        for (int idx = t; idx < 65 * 512 / 8; idx += 256) {
            *(uint4*)(xTphi + rowbase + (size_t)idx * 8) = z;
            *(uint4*)(xTplo + rowbase + (size_t)idx * 8) = z;
        }
        return;
    }
    if (t < 64) {
        *(uint4*)(xTphi + rowbase + (size_t)t * 8) = z;
        *(uint4*)(xTplo + rowbase + (size_t)t * 8) = z;
    }
    int hi = ri - 1;
    int wi = t & 63;
    const float* xb = x + (size_t)b * 512 * 4096 + (size_t)hi * 64 + wi;
    for (int it = 0; it < 16; ++it) {
        int cg = (t >> 6) + it * 4;     // 0..63
        int c0 = cg * 8;
        unsigned short h[8], l[8];
        #pragma unroll
        for (int j = 0; j < 8; j++) {
            float v = xb[(size_t)(c0 + j) * 4096];
            split_bf16(v, h[j], l[j]);
        }
        size_t dst = rowbase + (size_t)(wi + 1) * 512 + c0;
        uint4 ph = make_uint4((uint32_t)h[0] | ((uint32_t)h[1] << 16),
                              (uint32_t)h[2] | ((uint32_t)h[3] << 16),
                              (uint32_t)h[4] | ((uint32_t)h[5] << 16),
                              (uint32_t)h[6] | ((uint32_t)h[7] << 16));
        uint4 pl = make_uint4((uint32_t)l[0] | ((uint32_t)l[1] << 16),
                              (uint32_t)l[2] | ((uint32_t)l[3] << 16),
                              (uint32_t)l[4] | ((uint32_t)l[5] << 16),
                              (uint32_t)l[6] | ((uint32_t)l[7] << 16));
        *(uint4*)(xTphi + dst) = ph;
        *(uint4*)(xTplo + dst) = pl;
    }
}

// ---------- K1d: zero-fill outsP pad entries ----------
__global__ void pam_zeroP(unsigned short* __restrict__ p) {
    size_t i = ((size_t)blockIdx.x * 256 + threadIdx.x) * 8;   // total 2,230,272 ushorts
    uint4 z = make_uint4(0, 0, 0, 0);
    *(uint4*)(p + i) = z;
}

// ---------- K2: fused q (1x1 conv + BN) and v (1x1 conv + bias) as one GEMM ----------
__global__ __launch_bounds__(256) void pam_qv_gemm(
    const float* __restrict__ x, const float* __restrict__ wq, const float* __restrict__ wv,
    const float* __restrict__ bv, const float* __restrict__ affQ,
    unsigned short* __restrict__ qTbhi, unsigned short* __restrict__ qTblo,
    unsigned short* __restrict__ vTc) {
    __shared__ float As[64][17];
    __shared__ __align__(16) float Bs[16][64];
    int t = threadIdx.x;
    int b = blockIdx.z, row0 = blockIdx.y * 64, p0 = blockIdx.x * 64;
    int tc = t & 15, tr = t >> 4;
    float acc[4][4] = {};
    int ra = t >> 2, kk4 = (t & 3) * 4;
    int Ra = row0 + ra;
    const float* wrow = (Ra < 64) ? (wq + (size_t)Ra * 512) : (wv + (size_t)(Ra - 64) * 512);
    const float* xb = x + (size_t)b * 512 * 4096;
    int kb_ = t >> 4, pb4 = (t & 15) * 4;
    for (int k0 = 0; k0 < 512; k0 += 16) {
        float4 a4 = *(const float4*)(wrow + k0 + kk4);
        As[ra][kk4 + 0] = a4.x; As[ra][kk4 + 1] = a4.y;
        As[ra][kk4 + 2] = a4.z; As[ra][kk4 + 3] = a4.w;
        *(float4*)&Bs[kb_][pb4] = *(const float4*)(xb + (size_t)(k0 + kb_) * 4096 + p0 + pb4);
        __syncthreads();
        #pragma unroll
        for (int kk = 0; kk < 16; ++kk) {
            float a[4], bb[4];
            #pragma unroll
            for (int i = 0; i < 4; i++) a[i] = As[tr * 4 + i][kk];
            #pragma unroll
            for (int j = 0; j < 4; j++) bb[j] = Bs[kk][tc * 4 + j];
            #pragma unroll
            for (int i = 0; i < 4; i++)
                #pragma unroll
                for (int j = 0; j < 4; j++) acc[i][j] = fmaf(a[i], bb[j], acc[i][j]);
        }
        __syncthreads();
    }
    #pragma unroll
    for (int i = 0; i < 4; i++) {
        int R = row0 + tr * 4 + i;
        if (R < 64) {
            float sc = affQ[R], sh = affQ[64 + R];
            #pragma unroll
            for (int j = 0; j < 4; j++) {
                int p = p0 + tc * 4 + j;
                float val = fmaf(acc[i][j], sc, sh);
                unsigned short hi, lo;
                split_bf16(val, hi, lo);
                size_t idx = ((size_t)b * 4096 + p) * 64 + R;
                qTbhi[idx] = hi; qTblo[idx] = lo;
            }
        } else {
            int c = R - 64;
            float bb = bv[c];
            ushort4 u;
            u.x = (unsigned short)f_to_bf16(acc[i][0] + bb);
            u.y = (unsigned short)f_to_bf16(acc[i][1] + bb);
            u.z = (unsigned short)f_to_bf16(acc[i][2] + bb);
            u.w = (unsigned short)f_to_bf16(acc[i][3] + bb);
            *(ushort4*)(vTc + ((size_t)b * 256 + c) * 4096 + p0 + tc * 4) = u;
        }
    }
}

// ---------- K3: k-conv as tap-decomposed MFMA GEMM ----------
__global__ __launch_bounds__(256) void pam_kconv_mfma(
    const unsigned short* __restrict__ xTphi, const unsigned short* __restrict__ xTplo,
    const unsigned short* __restrict__ wkThi, const unsigned short* __restrict__ wkTlo,
    const float* __restrict__ affK,
    unsigned short* __restrict__ kBhi, unsigned short* __restrict__ kBlo) {
    int t = threadIdx.x;
    int hk = blockIdx.x, b = blockIdx.y;
    int wv = t >> 6, lane = t & 63, g = lane >> 4, lm = lane & 15;
    int goff = g * 8;
    f32x4 acc0 = (f32x4){0.f, 0.f, 0.f, 0.f};
    f32x4 acc1 = (f32x4){0.f, 0.f, 0.f, 0.f};
    #pragma unroll
    for (int r = 0; r < 3; r++) {
        size_t arow = ((size_t)(b * 65 + 2 * hk + r)) * 65 * 512;
        #pragma unroll
        for (int s = 0; s < 3; s++) {
            size_t aoff = arow + (size_t)(2 * lm + s) * 512 + goff;   // pixel wk=lm
            const unsigned short* pa0h = xTphi + aoff;
            const unsigned short* pa0l = xTplo + aoff;
            size_t boff = ((size_t)((r * 3 + s) * 64 + wv * 16 + lm)) * 512 + goff;
            const unsigned short* pb_h = wkThi + boff;
            const unsigned short* pb_l = wkTlo + boff;
            #pragma unroll 4
            for (int c0 = 0; c0 < 512; c0 += 32) {
                bf16x8 a0h = *(const bf16x8*)(pa0h + c0);
                bf16x8 a1h = *(const bf16x8*)(pa0h + 32 * 512 + c0);   // pixel wk=lm+16
                bf16x8 a0l = *(const bf16x8*)(pa0l + c0);
                bf16x8 a1l = *(const bf16x8*)(pa0l + 32 * 512 + c0);
                bf16x8 bh  = *(const bf16x8*)(pb_h + c0);
                bf16x8 bl  = *(const bf16x8*)(pb_l + c0);
                acc0 = __builtin_amdgcn_mfma_f32_16x16x32_bf16(a0h, bh, acc0, 0, 0, 0);
                acc1 = __builtin_amdgcn_mfma_f32_16x16x32_bf16(a1h, bh, acc1, 0, 0, 0);
                acc0 = __builtin_amdgcn_mfma_f32_16x16x32_bf16(a0l, bh, acc0, 0, 0, 0);
                acc1 = __builtin_amdgcn_mfma_f32_16x16x32_bf16(a1l, bh, acc1, 0, 0, 0);
                acc0 = __builtin_amdgcn_mfma_f32_16x16x32_bf16(a0h, bl, acc0, 0, 0, 0);
                acc1 = __builtin_amdgcn_mfma_f32_16x16x32_bf16(a1h, bl, acc1, 0, 0, 0);
            }
        }
    }
    int d = wv * 16 + lm;
    float sc = affK[d], sh = affK[64 + d];
    size_t base = (size_t)b * 1024 * 64 + (size_t)hk * 32 * 64 + d;
    #pragma unroll
    for (int i = 0; i < 4; i++) {
        int wk0 = g * 4 + i;
        float v0 = fmaf(acc0[i], sc, sh);
        float v1 = fmaf(acc1[i], sc, sh);
        unsigned short hh, ll;
        split_bf16(v0, hh, ll);
        kBhi[base + (size_t)wk0 * 64] = hh; kBlo[base + (size_t)wk0 * 64] = ll;
        split_bf16(v1, hh, ll);
        kBhi[base + (size_t)(wk0 + 16) * 64] = hh; kBlo[base + (size_t)(wk0 + 16) * 64] = ll;
    }
}

// ---------- K4: MFMA attention: energy (split-bf16) -> softmax -> PV ----------
// writes outsP[b][33][33][256] bf16 (pad row/col written by pam_zeroP)
__global__ __launch_bounds__(512, 2) void pam_attn(
    const unsigned short* __restrict__ qTbhi, const unsigned short* __restrict__ qTblo,
    const unsigned short* __restrict__ kBhi, const unsigned short* __restrict__ kBlo,
    const unsigned short* __restrict__ vTc, unsigned short* __restrict__ outsP) {
    __shared__ unsigned short Pl[16][4096];   // 128 KiB
    __shared__ float redM[8][16];
    __shared__ float redS[8][16];
    int t = threadIdx.x;
    int b = blockIdx.y, m0 = blockIdx.x * 16;
    int wid = t >> 6, lane = t & 63;
    int g = lane >> 4, lm = lane & 15;

    const unsigned short* kh = kBhi + ((size_t)(b * 1024 + m0 + lm)) * 64 + g * 8;
    const unsigned short* kl = kBlo + ((size_t)(b * 1024 + m0 + lm)) * 64 + g * 8;
    bf16x8 ah0 = *(const bf16x8*)kh;
    bf16x8 ah1 = *(const bf16x8*)(kh + 32);
    bf16x8 al0 = *(const bf16x8*)kl;
    bf16x8 al1 = *(const bf16x8*)(kl + 32);

    f32x4 ev[32];
    #pragma unroll
    for (int f = 0; f < 32; f++) ev[f] = (f32x4){0.f, 0.f, 0.f, 0.f};

    const unsigned short* qh = qTbhi + ((size_t)(b * 4096 + wid * 512 + lm)) * 64 + g * 8;
    const unsigned short* ql = qTblo + ((size_t)(b * 4096 + wid * 512 + lm)) * 64 + g * 8;
    #pragma unroll
    for (int f = 0; f < 32; f++) {
        const unsigned short* qhp = qh + (size_t)f * 16 * 64;
        const unsigned short* qlp = ql + (size_t)f * 16 * 64;
        bf16x8 bh0 = *(const bf16x8*)(qhp);
        bf16x8 bh1 = *(const bf16x8*)(qhp + 32);
        bf16x8 bl0 = *(const bf16x8*)(qlp);
        bf16x8 bl1 = *(const bf16x8*)(qlp + 32);
        f32x4 e = ev[f];
        e = __builtin_amdgcn_mfma_f32_16x16x32_bf16(ah0, bh0, e, 0, 0, 0);
        e = __builtin_amdgcn_mfma_f32_16x16x32_bf16(ah1, bh1, e, 0, 0, 0);
        e = __builtin_amdgcn_mfma_f32_16x16x32_bf16(ah0, bl0, e, 0, 0, 0);
        e = __builtin_amdgcn_mfma_f32_16x16x32_bf16(ah1, bl1, e, 0, 0, 0);
        e = __builtin_amdgcn_mfma_f32_16x16x32_bf16(al0, bh0, e, 0, 0, 0);
        e = __builtin_amdgcn_mfma_f32_16x16x32_bf16(al1, bh1, e, 0, 0, 0);
        ev[f] = e;
    }

    float rmax[4];
    #pragma unroll
    for (int i = 0; i < 4; i++) {
        float m_ = ev[0][i];
        #pragma unroll
        for (int f = 1; f < 32; f++) m_ = fmaxf(m_, ev[f][i]);
        #pragma unroll
        for (int off = 1; off < 16; off <<= 1) m_ = fmaxf(m_, __shfl_xor(m_, off));
        rmax[i] = m_;
    }
    if (lm == 0) {
        #pragma unroll
        for (int i = 0; i < 4; i++) redM[wid][g * 4 + i] = rmax[i];
    }
    __syncthreads();
    #pragma unroll
    for (int i = 0; i < 4; i++) {
        float m_ = redM[0][g * 4 + i];
        #pragma unroll
        for (int ww = 1; ww < 8; ww++) m_ = fmaxf(m_, redM[ww][g * 4 + i]);
        rmax[i] = m_;
    }

    float rsum[4] = {0.f, 0.f, 0.f, 0.f};
    #pragma unroll
    for (int f = 0; f < 32; f++) {
        int n = wid * 512 + f * 16 + lm;
        #pragma unroll
        for (int i = 0; i < 4; i++) {
            int r = g * 4 + i;
            float p = __expf(ev[f][i] - rmax[i]);
            uint32_t u = f_to_bf16(p);
            rsum[i] += bf16hi_to_f(u << 16);
            uint32_t byte = (((uint32_t)r << 13) + ((uint32_t)n << 1)) ^ (((uint32_t)(r & 7)) << 4);
            *(unsigned short*)((char*)&Pl[0][0] + byte) = (unsigned short)u;
        }
    }
    #pragma unroll
    for (int i = 0; i < 4; i++) {
        float s_ = rsum[i];
        #pragma unroll
        for (int off = 1; off < 16; off <<= 1) s_ += __shfl_xor(s_, off);
        rsum[i] = s_;
    }
    if (lm == 0) {
        #pragma unroll
        for (int i = 0; i < 4; i++) redS[wid][g * 4 + i] = rsum[i];
    }
    __syncthreads();
    float sinv[4];
    #pragma unroll
    for (int i = 0; i < 4; i++) {
        float s_ = 0.f;
        #pragma unroll
        for (int ww = 0; ww < 8; ww++) s_ += redS[ww][g * 4 + i];
        sinv[i] = 1.f / s_;
    }

    int c0 = wid * 32;
    f32x4 o0 = (f32x4){0.f, 0.f, 0.f, 0.f};
    f32x4 o1 = (f32x4){0.f, 0.f, 0.f, 0.f};
    const unsigned short* vbase0 = vTc + ((size_t)(b * 256 + c0 + lm)) * 4096 + g * 8;
    const unsigned short* vbase1 = vbase0 + (size_t)16 * 4096;
    const char* pbase = (const char*)&Pl[0][0];
    uint32_t poff_base = ((uint32_t)lm << 13) + ((uint32_t)g << 4);
    uint32_t sw = ((uint32_t)(lm & 7)) << 4;
    #pragma unroll 4
    for (int ks = 0; ks < 128; ks++) {
        bf16x8 pa = *(const bf16x8*)(pbase + ((poff_base + (uint32_t)ks * 64) ^ sw));
        bf16x8 b0 = *(const bf16x8*)(vbase0 + ks * 32);
        bf16x8 b1 = *(const bf16x8*)(vbase1 + ks * 32);
        o0 = __builtin_amdgcn_mfma_f32_16x16x32_bf16(pa, b0, o0, 0, 0, 0);
        o1 = __builtin_amdgcn_mfma_f32_16x16x32_bf16(pa, b1, o1, 0, 0, 0);
    }

    #pragma unroll
    for (int i = 0; i < 4; i++) {
        int m = m0 + g * 4 + i;          // pixel index
        int hk2 = m >> 5, wk2 = m & 31;
        unsigned short* op = outsP + (((size_t)(b * 33 + hk2)) * 33 + wk2) * 256;
        op[c0 + lm]      = (unsigned short)f_to_bf16(o0[i] * sinv[i]);
        op[c0 + 16 + lm] = (unsigned short)f_to_bf16(o1[i] * sinv[i]);
    }
}

// ---------- K5: transpose-conv 3x3 s2 p1 op1 as parity-decomposed MFMA + BN + ReLU + res ----------
// block = (ho, b), 512 thr = 8 waves. Wave: co-slice 64 (4 mfrags), N = 32 w' x 2 wo-parities.
// A = wdTb (hi/lo split), B = outsP bf16. K = 256 * 3kw * nh.
__global__ __launch_bounds__(512) void pam_deconv_mfma(
    const unsigned short* __restrict__ outsP,
    const unsigned short* __restrict__ wdTbhi, const unsigned short* __restrict__ wdTblo,
    const float* __restrict__ affD, const float* __restrict__ x, float* __restrict__ out) {
    int t = threadIdx.x;
    int ho = blockIdx.x, b = blockIdx.y;
    int wv = t >> 6, lane = t & 63, g = lane >> 4, lm = lane & 15;
    int ph = ho & 1, h0 = ho >> 1;

    f32x4 acc[2][4][2];
    #pragma unroll
    for (int c = 0; c < 2; c++)
        #pragma unroll
        for (int mf = 0; mf < 4; mf++)
            #pragma unroll
            for (int nf = 0; nf < 2; nf++) acc[c][mf][nf] = (f32x4){0.f, 0.f, 0.f, 0.f};

    int nht = ph ? 2 : 1;
    for (int it = 0; it < nht; ++it) {
        // ph=0: kh=1, dh=0. ph=1: it0 -> kh=2,dh=0 ; it1 -> kh=0,dh=1
        int kh = ph ? (it == 0 ? 2 : 0) : 1;
        int dh = ph ? it : 0;
        size_t brow = ((size_t)(b * 33) + h0 + dh) * 33 * 256;
        #pragma unroll
        for (int kw = 0; kw < 3; kw++) {
            const int cls = (kw == 1) ? 0 : 1;        // even/odd wo
            const int dw = (kw == 0) ? 1 : 0;
            int tap = kh * 3 + kw;
            const unsigned short* bp0 = outsP + brow + (size_t)(lm + dw) * 256 + g * 8;
            const unsigned short* bp1 = bp0 + 16 * 256;
            size_t abase = ((size_t)tap * 512 + wv * 64 + lm) * 256 + g * 8;
            const unsigned short* aph = wdTbhi + abase;
            const unsigned short* apl = wdTblo + abase;
            #pragma unroll 2
            for (int c0 = 0; c0 < 256; c0 += 32) {
                bf16x8 b0 = *(const bf16x8*)(bp0 + c0);
                bf16x8 b1 = *(const bf16x8*)(bp1 + c0);
                bf16x8 ah[4], al[4];
                #pragma unroll
                for (int mf = 0; mf < 4; mf++) {
                    ah[mf] = *(const bf16x8*)(aph + mf * 16 * 256 + c0);
                    al[mf] = *(const bf16x8*)(apl + mf * 16 * 256 + c0);
                }
                #pragma unroll
                for (int mf = 0; mf < 4; mf++) {
                    acc[cls][mf][0] = __builtin_amdgcn_mfma_f32_16x16x32_bf16(ah[mf], b0, acc[cls][mf][0], 0, 0, 0);
                    acc[cls][mf][1] = __builtin_amdgcn_mfma_f32_16x16x32_bf16(ah[mf], b1, acc[cls][mf][1], 0, 0, 0);
                    acc[cls][mf][0] = __builtin_amdgcn_mfma_f32_16x16x32_bf16(al[mf], b0, acc[cls][mf][0], 0, 0, 0);
                    acc[cls][mf][1] = __builtin_amdgcn_mfma_f32_16x16x32_bf16(al[mf], b1, acc[cls][mf][1], 0, 0, 0);
                }
            }
        }
    }

    #pragma unroll
    for (int mf = 0; mf < 4; mf++) {
        #pragma unroll
        for (int i = 0; i < 4; i++) {
            int co = wv * 64 + mf * 16 + g * 4 + i;
            float sc = affD[co], sh = affD[512 + co];
            const float* xr = x + (((size_t)b * 512 + co) * 64 + ho) * 64;
            float* orow = out + (((size_t)b * 512 + co) * 64 + ho) * 64;
            #pragma unroll
            for (int nf = 0; nf < 2; nf++) {
                int wp = nf * 16 + lm;
                float ve = fmaxf(fmaf(acc[0][mf][nf][i], sc, sh), 0.f) + xr[2 * wp];
                float vo = fmaxf(fmaf(acc[1][mf][nf][i], sc, sh), 0.f) + xr[2 * wp + 1];
                float2 st; st.x = ve; st.y = vo;
                *(float2*)(orow + 2 * wp) = st;
            }
        }
    }
}

// ---------- launcher ----------
extern "C" void kernel_launch(void* const* d_in, const int* in_sizes, int n_in,
                              void* d_out, int out_size, void* d_ws, size_t ws_size,
                              hipStream_t stream) {
    const float* x   = (const float*)d_in[0];
    const float* w_q = (const float*)d_in[1];
    const float* b_q = (const float*)d_in[2];
    const float* qs  = (const float*)d_in[3];
    const float* qb  = (const float*)d_in[4];
    const float* qm  = (const float*)d_in[5];
    const float* qv  = (const float*)d_in[6];
    const float* w_k = (const float*)d_in[7];
    const float* b_k = (const float*)d_in[8];
    const float* ks  = (const float*)d_in[9];
    const float* kb  = (const float*)d_in[10];
    const float* km  = (const float*)d_in[11];
    const float* kv  = (const float*)d_in[12];
    const float* w_v = (const float*)d_in[13];
    const float* b_v = (const float*)d_in[14];
    const float* w_d = (const float*)d_in[15];
    const float* ds  = (const float*)d_in[16];
    const float* db  = (const float*)d_in[17];
    const float* dm  = (const float*)d_in[18];
    const float* dv  = (const float*)d_in[19];
    float* out = (float*)d_out;

    char* wsb = (char*)d_ws;
    unsigned short* qTbhi = (unsigned short*)(wsb);               //  4,194,304
    unsigned short* qTblo = (unsigned short*)(wsb + 4194304);     //  4,194,304
    unsigned short* vTc   = (unsigned short*)(wsb + 8388608);     // 16,777,216
    unsigned short* kBhi  = (unsigned short*)(wsb + 25165824);    //  1,048,576
    unsigned short* kBlo  = (unsigned short*)(wsb + 26214400);    //  1,048,576
    unsigned short* wkThi = (unsigned short*)(wsb + 27262976);    //    589,824
    unsigned short* wkTlo = (unsigned short*)(wsb + 27852800);    //    589,824
    float*          affQ  = (float*)(wsb + 28442624);             //        512
    float*          affK  = (float*)(wsb + 28443136);             //        512
    float*          affD  = (float*)(wsb + 28443648);             //      4,096
    // X region: xTp{hi,lo} live [pam_xt .. pam_kconv_mfma]; then reused:
    unsigned short* xTphi = (unsigned short*)(wsb + 28447744);    // 34,611,200
    unsigned short* xTplo = (unsigned short*)(wsb + 63058944);    // 34,611,200 -> end 97,670,144
    unsigned short* outsP  = (unsigned short*)(wsb + 28447744);   //  4,460,544 (alias)
    unsigned short* wdTbhi = (unsigned short*)(wsb + 32908288);   //  2,359,296 (alias)
    unsigned short* wdTblo = (unsigned short*)(wsb + 35267584);   //  2,359,296 (alias)

    hipLaunchKernelGGL(pam_aff_kernel, dim3(1), dim3(640), 0, stream,
                       b_q, qs, qb, qm, qv, b_k, ks, kb, km, kv, ds, db, dm, dv,
                       affQ, affK, affD);
    hipLaunchKernelGGL(pam_wkt, dim3(1152), dim3(256), 0, stream, w_k, wkThi, wkTlo);
    hipLaunchKernelGGL(pam_xt, dim3(65, 8), dim3(256), 0, stream, x, xTphi, xTplo);
    hipLaunchKernelGGL(pam_qv_gemm, dim3(64, 5, 8), dim3(256), 0, stream,
                       x, w_q, w_v, b_v, affQ, qTbhi, qTblo, vTc);
    hipLaunchKernelGGL(pam_kconv_mfma, dim3(32, 8), dim3(256), 0, stream,
                       xTphi, xTplo, wkThi, wkTlo, affK, kBhi, kBlo);
    // xTp dead from here; aliased region reused for outsP / wdTb.
    hipLaunchKernelGGL(pam_wdtb, dim3(4608), dim3(256), 0, stream, w_d, wdTbhi, wdTblo);
    hipLaunchKernelGGL(pam_zeroP, dim3(1089), dim3(256), 0, stream, outsP);
    hipLaunchKernelGGL(pam_attn, dim3(64, 8), dim3(512), 0, stream,
                       qTbhi, qTblo, kBhi, kBlo, vTc, outsP);
    hipLaunchKernelGGL(pam_deconv_mfma, dim3(64, 8), dim3(512), 0, stream,
                       outsP, wdTbhi, wdTblo, affD, x, out);
}

// Round 5
// 647.020 us; speedup vs baseline: 2.8884x; 1.0919x over previous
//
#include <hip/hip_runtime.h>
#include <hip/hip_bf16.h>
#include <cstdint>

#define BN_EPS 1e-5f

typedef short bf16x8 __attribute__((ext_vector_type(8)));
typedef float f32x4 __attribute__((ext_vector_type(4)));

// ---------- helpers ----------
__device__ __forceinline__ float bf16hi_to_f(uint32_t hi) {
    union { uint32_t u; float f; } c; c.u = hi; return c.f;
}
__device__ __forceinline__ uint32_t f_to_bf16(float f) {
    union { float f; uint32_t u; } c; c.f = f;
    uint32_t r = c.u + 0x7fffu + ((c.u >> 16) & 1u);  // RNE
    return r >> 16;
}
__device__ __forceinline__ void split_bf16(float v, unsigned short& hi, unsigned short& lo) {
    uint32_t h = f_to_bf16(v);
    float fh = bf16hi_to_f(h << 16);
    uint32_t l = f_to_bf16(v - fh);
    hi = (unsigned short)h; lo = (unsigned short)l;
}

// ---------- K0: BN affine precompute ----------
__global__ void pam_aff_kernel(const float* bq, const float* qs, const float* qb, const float* qm, const float* qv,
                               const float* bk, const float* ks, const float* kb, const float* km, const float* kv,
                               const float* ds, const float* db, const float* dm, const float* dv,
                               float* affQ, float* affK, float* affD) {
    int t = threadIdx.x;
    if (t < 64) {
        float inv = qs[t] * rsqrtf(qv[t] + BN_EPS);
        affQ[t] = inv; affQ[64 + t] = bq[t] * inv + qb[t] - qm[t] * inv;
    } else if (t < 128) {
        int i = t - 64;
        float inv = ks[i] * rsqrtf(kv[i] + BN_EPS);
        affK[i] = inv; affK[64 + i] = bk[i] * inv + kb[i] - km[i] * inv;
    } else {
        int i = t - 128;
        if (i < 512) {
            float inv = ds[i] * rsqrtf(dv[i] + BN_EPS);
            affD[i] = inv; affD[512 + i] = db[i] - dm[i] * inv;
        }
    }
}

// ---------- K1: transpose+split w_d (256,512,3,3) -> wdTb{hi,lo}[tap][co][ci] ----------
__global__ void pam_wdtb(const float* __restrict__ wd,
                         unsigned short* __restrict__ wdTbhi, unsigned short* __restrict__ wdTblo) {
    int o = blockIdx.x * 256 + threadIdx.x;       // < 9*512*256 = 1,179,648
    int ci = o & 255; int co = (o >> 8) & 511; int tap = o >> 17;
    float v = wd[(size_t)ci * 4608 + co * 9 + tap];
    unsigned short h, l;
    split_bf16(v, h, l);
    wdTbhi[o] = h; wdTblo[o] = l;
}

// ---------- K1b: transpose+split w_k (64,512,3,3) -> wkT{hi,lo}[k9][d][c] ----------
__global__ void pam_wkt(const float* __restrict__ wk,
                        unsigned short* __restrict__ wkThi, unsigned short* __restrict__ wkTlo) {
    int o = blockIdx.x * 256 + threadIdx.x;       // < 9*64*512 = 294912
    int c = o & 511; int d = (o >> 9) & 63; int kk = o >> 15;
    float v = wk[((size_t)d * 512 + c) * 9 + kk];
    unsigned short h, l;
    split_bf16(v, h, l);
    wkThi[o] = h; wkTlo[o] = l;
}

// ---------- K1c: x -> xTp{hi,lo}[b][65][65][512]  (pixel-major, c-contig, -1 pad) ----------
__global__ __launch_bounds__(256) void pam_xt(const float* __restrict__ x,
                                              unsigned short* __restrict__ xTphi,
                                              unsigned short* __restrict__ xTplo) {
    int t = threadIdx.x;
    int ri = blockIdx.x;       // 0..64 ; input row hi = ri-1
    int b = blockIdx.y;
    size_t rowbase = ((size_t)b * 65 + ri) * 65 * 512;
    uint4 z = make_uint4(0, 0, 0, 0);
    if (ri == 0) {
        for (int idx = t; idx < 65 * 512 / 8; idx += 256) {
            *(uint4*)(xTphi + rowbase + (size_t)idx * 8) = z;
            *(uint4*)(xTplo + rowbase + (size_t)idx * 8) = z;
        }
        return;
    }
    if (t < 64) {
        *(uint4*)(xTphi + rowbase + (size_t)t * 8) = z;
        *(uint4*)(xTplo + rowbase + (size_t)t * 8) = z;
    }
    int hi = ri - 1;
    int wi = t & 63;
    const float* xb = x + (size_t)b * 512 * 4096 + (size_t)hi * 64 + wi;
    for (int it = 0; it < 16; ++it) {
        int cg = (t >> 6) + it * 4;     // 0..63
        int c0 = cg * 8;
        unsigned short h[8], l[8];
        #pragma unroll
        for (int j = 0; j < 8; j++) {
            float v = xb[(size_t)(c0 + j) * 4096];
            split_bf16(v, h[j], l[j]);
        }
        size_t dst = rowbase + (size_t)(wi + 1) * 512 + c0;
        uint4 ph = make_uint4((uint32_t)h[0] | ((uint32_t)h[1] << 16),
                              (uint32_t)h[2] | ((uint32_t)h[3] << 16),
                              (uint32_t)h[4] | ((uint32_t)h[5] << 16),
                              (uint32_t)h[6] | ((uint32_t)h[7] << 16));
        uint4 pl = make_uint4((uint32_t)l[0] | ((uint32_t)l[1] << 16),
                              (uint32_t)l[2] | ((uint32_t)l[3] << 16),
                              (uint32_t)l[4] | ((uint32_t)l[5] << 16),
                              (uint32_t)l[6] | ((uint32_t)l[7] << 16));
        *(uint4*)(xTphi + dst) = ph;
        *(uint4*)(xTplo + dst) = pl;
    }
}

// ---------- K1d: zero-fill outsP pad entries ----------
__global__ void pam_zeroP(unsigned short* __restrict__ p) {
    size_t i = ((size_t)blockIdx.x * 256 + threadIdx.x) * 8;   // total 2,230,272 ushorts
    uint4 z = make_uint4(0, 0, 0, 0);
    *(uint4*)(p + i) = z;
}

// ---------- K2: fused q (1x1 conv + BN) and v (1x1 conv + bias) as one GEMM ----------
__global__ __launch_bounds__(256) void pam_qv_gemm(
    const float* __restrict__ x, const float* __restrict__ wq, const float* __restrict__ wv,
    const float* __restrict__ bv, const float* __restrict__ affQ,
    unsigned short* __restrict__ qTbhi, unsigned short* __restrict__ qTblo,
    unsigned short* __restrict__ vTc) {
    __shared__ float As[64][17];
    __shared__ __align__(16) float Bs[16][64];
    int t = threadIdx.x;
    int b = blockIdx.z, row0 = blockIdx.y * 64, p0 = blockIdx.x * 64;
    int tc = t & 15, tr = t >> 4;
    float acc[4][4] = {};
    int ra = t >> 2, kk4 = (t & 3) * 4;
    int Ra = row0 + ra;
    const float* wrow = (Ra < 64) ? (wq + (size_t)Ra * 512) : (wv + (size_t)(Ra - 64) * 512);
    const float* xb = x + (size_t)b * 512 * 4096;
    int kb_ = t >> 4, pb4 = (t & 15) * 4;
    for (int k0 = 0; k0 < 512; k0 += 16) {
        float4 a4 = *(const float4*)(wrow + k0 + kk4);
        As[ra][kk4 + 0] = a4.x; As[ra][kk4 + 1] = a4.y;
        As[ra][kk4 + 2] = a4.z; As[ra][kk4 + 3] = a4.w;
        *(float4*)&Bs[kb_][pb4] = *(const float4*)(xb + (size_t)(k0 + kb_) * 4096 + p0 + pb4);
        __syncthreads();
        #pragma unroll
        for (int kk = 0; kk < 16; ++kk) {
            float a[4], bb[4];
            #pragma unroll
            for (int i = 0; i < 4; i++) a[i] = As[tr * 4 + i][kk];
            #pragma unroll
            for (int j = 0; j < 4; j++) bb[j] = Bs[kk][tc * 4 + j];
            #pragma unroll
            for (int i = 0; i < 4; i++)
                #pragma unroll
                for (int j = 0; j < 4; j++) acc[i][j] = fmaf(a[i], bb[j], acc[i][j]);
        }
        __syncthreads();
    }
    #pragma unroll
    for (int i = 0; i < 4; i++) {
        int R = row0 + tr * 4 + i;
        if (R < 64) {
            float sc = affQ[R], sh = affQ[64 + R];
            #pragma unroll
            for (int j = 0; j < 4; j++) {
                int p = p0 + tc * 4 + j;
                float val = fmaf(acc[i][j], sc, sh);
                unsigned short hi, lo;
                split_bf16(val, hi, lo);
                size_t idx = ((size_t)b * 4096 + p) * 64 + R;
                qTbhi[idx] = hi; qTblo[idx] = lo;
            }
        } else {
            int c = R - 64;
            float bb = bv[c];
            ushort4 u;
            u.x = (unsigned short)f_to_bf16(acc[i][0] + bb);
            u.y = (unsigned short)f_to_bf16(acc[i][1] + bb);
            u.z = (unsigned short)f_to_bf16(acc[i][2] + bb);
            u.w = (unsigned short)f_to_bf16(acc[i][3] + bb);
            *(ushort4*)(vTc + ((size_t)b * 256 + c) * 4096 + p0 + tc * 4) = u;
        }
    }
}

// ---------- K3: k-conv as tap-decomposed MFMA GEMM ----------
__global__ __launch_bounds__(256) void pam_kconv_mfma(
    const unsigned short* __restrict__ xTphi, const unsigned short* __restrict__ xTplo,
    const unsigned short* __restrict__ wkThi, const unsigned short* __restrict__ wkTlo,
    const float* __restrict__ affK,
    unsigned short* __restrict__ kBhi, unsigned short* __restrict__ kBlo) {
    int t = threadIdx.x;
    int hk = blockIdx.x, b = blockIdx.y;
    int wv = t >> 6, lane = t & 63, g = lane >> 4, lm = lane & 15;
    int goff = g * 8;
    f32x4 acc0 = (f32x4){0.f, 0.f, 0.f, 0.f};
    f32x4 acc1 = (f32x4){0.f, 0.f, 0.f, 0.f};
    #pragma unroll
    for (int r = 0; r < 3; r++) {
        size_t arow = ((size_t)(b * 65 + 2 * hk + r)) * 65 * 512;
        #pragma unroll
        for (int s = 0; s < 3; s++) {
            size_t aoff = arow + (size_t)(2 * lm + s) * 512 + goff;   // pixel wk=lm
            const unsigned short* pa0h = xTphi + aoff;
            const unsigned short* pa0l = xTplo + aoff;
            size_t boff = ((size_t)((r * 3 + s) * 64 + wv * 16 + lm)) * 512 + goff;
            const unsigned short* pb_h = wkThi + boff;
            const unsigned short* pb_l = wkTlo + boff;
            #pragma unroll 4
            for (int c0 = 0; c0 < 512; c0 += 32) {
                bf16x8 a0h = *(const bf16x8*)(pa0h + c0);
                bf16x8 a1h = *(const bf16x8*)(pa0h + 32 * 512 + c0);   // pixel wk=lm+16
                bf16x8 a0l = *(const bf16x8*)(pa0l + c0);
                bf16x8 a1l = *(const bf16x8*)(pa0l + 32 * 512 + c0);
                bf16x8 bh  = *(const bf16x8*)(pb_h + c0);
                bf16x8 bl  = *(const bf16x8*)(pb_l + c0);
                acc0 = __builtin_amdgcn_mfma_f32_16x16x32_bf16(a0h, bh, acc0, 0, 0, 0);
                acc1 = __builtin_amdgcn_mfma_f32_16x16x32_bf16(a1h, bh, acc1, 0, 0, 0);
                acc0 = __builtin_amdgcn_mfma_f32_16x16x32_bf16(a0l, bh, acc0, 0, 0, 0);
                acc1 = __builtin_amdgcn_mfma_f32_16x16x32_bf16(a1l, bh, acc1, 0, 0, 0);
                acc0 = __builtin_amdgcn_mfma_f32_16x16x32_bf16(a0h, bl, acc0, 0, 0, 0);
                acc1 = __builtin_amdgcn_mfma_f32_16x16x32_bf16(a1h, bl, acc1, 0, 0, 0);
            }
        }
    }
    int d = wv * 16 + lm;
    float sc = affK[d], sh = affK[64 + d];
    size_t base = (size_t)b * 1024 * 64 + (size_t)hk * 32 * 64 + d;
    #pragma unroll
    for (int i = 0; i < 4; i++) {
        int wk0 = g * 4 + i;
        float v0 = fmaf(acc0[i], sc, sh);
        float v1 = fmaf(acc1[i], sc, sh);
        unsigned short hh, ll;
        split_bf16(v0, hh, ll);
        kBhi[base + (size_t)wk0 * 64] = hh; kBlo[base + (size_t)wk0 * 64] = ll;
        split_bf16(v1, hh, ll);
        kBhi[base + (size_t)(wk0 + 16) * 64] = hh; kBlo[base + (size_t)(wk0 + 16) * 64] = ll;
    }
}

// ---------- K4: MFMA attention: energy (split-bf16) -> softmax -> PV ----------
// writes outsP[b][33][33][256] bf16 (pad row/col written by pam_zeroP)
__global__ __launch_bounds__(512, 2) void pam_attn(
    const unsigned short* __restrict__ qTbhi, const unsigned short* __restrict__ qTblo,
    const unsigned short* __restrict__ kBhi, const unsigned short* __restrict__ kBlo,
    const unsigned short* __restrict__ vTc, unsigned short* __restrict__ outsP) {
    __shared__ unsigned short Pl[16][4096];   // 128 KiB
    __shared__ float redM[8][16];
    __shared__ float redS[8][16];
    int t = threadIdx.x;
    int b = blockIdx.y, m0 = blockIdx.x * 16;
    int wid = t >> 6, lane = t & 63;
    int g = lane >> 4, lm = lane & 15;

    const unsigned short* kh = kBhi + ((size_t)(b * 1024 + m0 + lm)) * 64 + g * 8;
    const unsigned short* kl = kBlo + ((size_t)(b * 1024 + m0 + lm)) * 64 + g * 8;
    bf16x8 ah0 = *(const bf16x8*)kh;
    bf16x8 ah1 = *(const bf16x8*)(kh + 32);
    bf16x8 al0 = *(const bf16x8*)kl;
    bf16x8 al1 = *(const bf16x8*)(kl + 32);

    f32x4 ev[32];
    #pragma unroll
    for (int f = 0; f < 32; f++) ev[f] = (f32x4){0.f, 0.f, 0.f, 0.f};

    const unsigned short* qh = qTbhi + ((size_t)(b * 4096 + wid * 512 + lm)) * 64 + g * 8;
    const unsigned short* ql = qTblo + ((size_t)(b * 4096 + wid * 512 + lm)) * 64 + g * 8;
    #pragma unroll
    for (int f = 0; f < 32; f++) {
        const unsigned short* qhp = qh + (size_t)f * 16 * 64;
        const unsigned short* qlp = ql + (size_t)f * 16 * 64;
        bf16x8 bh0 = *(const bf16x8*)(qhp);
        bf16x8 bh1 = *(const bf16x8*)(qhp + 32);
        bf16x8 bl0 = *(const bf16x8*)(qlp);
        bf16x8 bl1 = *(const bf16x8*)(qlp + 32);
        f32x4 e = ev[f];
        e = __builtin_amdgcn_mfma_f32_16x16x32_bf16(ah0, bh0, e, 0, 0, 0);
        e = __builtin_amdgcn_mfma_f32_16x16x32_bf16(ah1, bh1, e, 0, 0, 0);
        e = __builtin_amdgcn_mfma_f32_16x16x32_bf16(ah0, bl0, e, 0, 0, 0);
        e = __builtin_amdgcn_mfma_f32_16x16x32_bf16(ah1, bl1, e, 0, 0, 0);
        e = __builtin_amdgcn_mfma_f32_16x16x32_bf16(al0, bh0, e, 0, 0, 0);
        e = __builtin_amdgcn_mfma_f32_16x16x32_bf16(al1, bh1, e, 0, 0, 0);
        ev[f] = e;
    }

    float rmax[4];
    #pragma unroll
    for (int i = 0; i < 4; i++) {
        float m_ = ev[0][i];
        #pragma unroll
        for (int f = 1; f < 32; f++) m_ = fmaxf(m_, ev[f][i]);
        #pragma unroll
        for (int off = 1; off < 16; off <<= 1) m_ = fmaxf(m_, __shfl_xor(m_, off));
        rmax[i] = m_;
    }
    if (lm == 0) {
        #pragma unroll
        for (int i = 0; i < 4; i++) redM[wid][g * 4 + i] = rmax[i];
    }
    __syncthreads();
    #pragma unroll
    for (int i = 0; i < 4; i++) {
        float m_ = redM[0][g * 4 + i];
        #pragma unroll
        for (int ww = 1; ww < 8; ww++) m_ = fmaxf(m_, redM[ww][g * 4 + i]);
        rmax[i] = m_;
    }

    float rsum[4] = {0.f, 0.f, 0.f, 0.f};
    #pragma unroll
    for (int f = 0; f < 32; f++) {
        int n = wid * 512 + f * 16 + lm;
        #pragma unroll
        for (int i = 0; i < 4; i++) {
            int r = g * 4 + i;
            float p = __expf(ev[f][i] - rmax[i]);
            uint32_t u = f_to_bf16(p);
            rsum[i] += bf16hi_to_f(u << 16);
            uint32_t byte = (((uint32_t)r << 13) + ((uint32_t)n << 1)) ^ (((uint32_t)(r & 7)) << 4);
            *(unsigned short*)((char*)&Pl[0][0] + byte) = (unsigned short)u;
        }
    }
    #pragma unroll
    for (int i = 0; i < 4; i++) {
        float s_ = rsum[i];
        #pragma unroll
        for (int off = 1; off < 16; off <<= 1) s_ += __shfl_xor(s_, off);
        rsum[i] = s_;
    }
    if (lm == 0) {
        #pragma unroll
        for (int i = 0; i < 4; i++) redS[wid][g * 4 + i] = rsum[i];
    }
    __syncthreads();
    float sinv[4];
    #pragma unroll
    for (int i = 0; i < 4; i++) {
        float s_ = 0.f;
        #pragma unroll
        for (int ww = 0; ww < 8; ww++) s_ += redS[ww][g * 4 + i];
        sinv[i] = 1.f / s_;
    }

    int c0 = wid * 32;
    f32x4 o0 = (f32x4){0.f, 0.f, 0.f, 0.f};
    f32x4 o1 = (f32x4){0.f, 0.f, 0.f, 0.f};
    const unsigned short* vbase0 = vTc + ((size_t)(b * 256 + c0 + lm)) * 4096 + g * 8;
    const unsigned short* vbase1 = vbase0 + (size_t)16 * 4096;
    const char* pbase = (const char*)&Pl[0][0];
    uint32_t poff_base = ((uint32_t)lm << 13) + ((uint32_t)g << 4);
    uint32_t sw = ((uint32_t)(lm & 7)) << 4;
    #pragma unroll 4
    for (int ks = 0; ks < 128; ks++) {
        bf16x8 pa = *(const bf16x8*)(pbase + ((poff_base + (uint32_t)ks * 64) ^ sw));
        bf16x8 b0 = *(const bf16x8*)(vbase0 + ks * 32);
        bf16x8 b1 = *(const bf16x8*)(vbase1 + ks * 32);
        o0 = __builtin_amdgcn_mfma_f32_16x16x32_bf16(pa, b0, o0, 0, 0, 0);
        o1 = __builtin_amdgcn_mfma_f32_16x16x32_bf16(pa, b1, o1, 0, 0, 0);
    }

    #pragma unroll
    for (int i = 0; i < 4; i++) {
        int m = m0 + g * 4 + i;          // pixel index
        int hk2 = m >> 5, wk2 = m & 31;
        unsigned short* op = outsP + (((size_t)(b * 33 + hk2)) * 33 + wk2) * 256;
        op[c0 + lm]      = (unsigned short)f_to_bf16(o0[i] * sinv[i]);
        op[c0 + 16 + lm] = (unsigned short)f_to_bf16(o1[i] * sinv[i]);
    }
}

// ---------- K5: transpose-conv 3x3 s2 p1 op1 as balanced row-pair MFMA + BN + ReLU + res ----------
// block = (h0, b), 1024 thr = 16 waves; wave -> co-slice of 32 (2 mfrags).
// Both output rows 2h0 (kh=1) and 2h0+1 (kh=2 row h0, kh=0 row h0+1): 9 taps per wave.
// B (outsP rows h0,h0+1) staged once in LDS, XOR-swizzled.
template<int LROW, int KH, int KW>
__device__ __forceinline__ void deconv_tap(
    const unsigned short* __restrict__ wdTbhi, const unsigned short* __restrict__ wdTblo,
    const char* lb, int co0, int lm, int g, f32x4 (&acc)[2][2][2]) {
    constexpr int wop = (KW == 1) ? 0 : 1;
    constexpr int dw = (KW == 0) ? 1 : 0;
    constexpr int tap = KH * 3 + KW;
    int p0 = LROW * 33 + lm + dw;
    int p1 = p0 + 16;
    uint32_t s0 = ((uint32_t)(p0 & 7)) << 4;
    uint32_t s1 = ((uint32_t)(p1 & 7)) << 4;
    uint32_t b0a = (uint32_t)p0 * 512 + (uint32_t)g * 16;
    uint32_t b1a = (uint32_t)p1 * 512 + (uint32_t)g * 16;
    size_t a0 = ((size_t)tap * 512 + co0 + lm) * 256 + g * 8;
    size_t a1 = a0 + 16 * 256;
    #pragma unroll
    for (int c0 = 0; c0 < 256; c0 += 32) {
        bf16x8 bv0 = *(const bf16x8*)(lb + ((b0a + (uint32_t)c0 * 2) ^ s0));
        bf16x8 bv1 = *(const bf16x8*)(lb + ((b1a + (uint32_t)c0 * 2) ^ s1));
        bf16x8 ah0 = *(const bf16x8*)(wdTbhi + a0 + c0);
        bf16x8 ah1 = *(const bf16x8*)(wdTbhi + a1 + c0);
        bf16x8 al0 = *(const bf16x8*)(wdTblo + a0 + c0);
        bf16x8 al1 = *(const bf16x8*)(wdTblo + a1 + c0);
        acc[wop][0][0] = __builtin_amdgcn_mfma_f32_16x16x32_bf16(ah0, bv0, acc[wop][0][0], 0, 0, 0);
        acc[wop][0][1] = __builtin_amdgcn_mfma_f32_16x16x32_bf16(ah0, bv1, acc[wop][0][1], 0, 0, 0);
        acc[wop][1][0] = __builtin_amdgcn_mfma_f32_16x16x32_bf16(ah1, bv0, acc[wop][1][0], 0, 0, 0);
        acc[wop][1][1] = __builtin_amdgcn_mfma_f32_16x16x32_bf16(ah1, bv1, acc[wop][1][1], 0, 0, 0);
        acc[wop][0][0] = __builtin_amdgcn_mfma_f32_16x16x32_bf16(al0, bv0, acc[wop][0][0], 0, 0, 0);
        acc[wop][0][1] = __builtin_amdgcn_mfma_f32_16x16x32_bf16(al0, bv1, acc[wop][0][1], 0, 0, 0);
        acc[wop][1][0] = __builtin_amdgcn_mfma_f32_16x16x32_bf16(al1, bv0, acc[wop][1][0], 0, 0, 0);
        acc[wop][1][1] = __builtin_amdgcn_mfma_f32_16x16x32_bf16(al1, bv1, acc[wop][1][1], 0, 0, 0);
    }
}

__device__ __forceinline__ void deconv_epi(
    const f32x4 (&acc)[2][2][2], const float* __restrict__ affD,
    const float* __restrict__ x, float* __restrict__ out,
    int b, int ho, int co0, int lm, int g) {
    #pragma unroll
    for (int mf = 0; mf < 2; mf++) {
        #pragma unroll
        for (int i = 0; i < 4; i++) {
            int co = co0 + mf * 16 + g * 4 + i;
            float sc = affD[co], sh = affD[512 + co];
            const float* xr = x + (((size_t)b * 512 + co) * 64 + ho) * 64;
            float* orow = out + (((size_t)b * 512 + co) * 64 + ho) * 64;
            #pragma unroll
            for (int nf = 0; nf < 2; nf++) {
                int wp = nf * 16 + lm;
                float2 xv = *(const float2*)(xr + 2 * wp);
                float2 st;
                st.x = fmaxf(fmaf(acc[0][mf][nf][i], sc, sh), 0.f) + xv.x;
                st.y = fmaxf(fmaf(acc[1][mf][nf][i], sc, sh), 0.f) + xv.y;
                *(float2*)(orow + 2 * wp) = st;
            }
        }
    }
}

__global__ __launch_bounds__(1024, 4) void pam_deconv_mfma(
    const unsigned short* __restrict__ outsP,
    const unsigned short* __restrict__ wdTbhi, const unsigned short* __restrict__ wdTblo,
    const float* __restrict__ affD, const float* __restrict__ x, float* __restrict__ out) {
    __shared__ unsigned short Pb[16896];   // 2 rows x 33 px x 256 ci, 33,792 B
    int t = threadIdx.x;
    int h0 = blockIdx.x, b = blockIdx.y;
    const unsigned short* src = outsP + ((size_t)(b * 33 + h0) * 33) * 256;
    for (int idx = t; idx < 2112; idx += 1024) {
        uint4 v = *(const uint4*)(src + (size_t)idx * 8);
        uint32_t byte = (uint32_t)idx * 16;
        byte ^= ((byte >> 9) & 7) << 4;
        *(uint4*)((char*)Pb + byte) = v;
    }
    __syncthreads();

    int wid = t >> 6, lane = t & 63, g = lane >> 4, lm = lane & 15;
    int co0 = wid * 32;
    const char* lb = (const char*)Pb;

    {   // even output row ho = 2*h0 : kh=1, B row h0 (LDS row 0)
        f32x4 acc[2][2][2];
        #pragma unroll
        for (int a = 0; a < 2; a++)
            #pragma unroll
            for (int m = 0; m < 2; m++)
                #pragma unroll
                for (int n = 0; n < 2; n++) acc[a][m][n] = (f32x4){0.f, 0.f, 0.f, 0.f};
        deconv_tap<0, 1, 0>(wdTbhi, wdTblo, lb, co0, lm, g, acc);
        deconv_tap<0, 1, 1>(wdTbhi, wdTblo, lb, co0, lm, g, acc);
        deconv_tap<0, 1, 2>(wdTbhi, wdTblo, lb, co0, lm, g, acc);
        deconv_epi(acc, affD, x, out, b, 2 * h0, co0, lm, g);
    }
    {   // odd output row ho = 2*h0+1 : kh=2 B row h0 (LDS 0), kh=0 B row h0+1 (LDS 1)
        f32x4 acc[2][2][2];
        #pragma unroll
        for (int a = 0; a < 2; a++)
            #pragma unroll
            for (int m = 0; m < 2; m++)
                #pragma unroll
                for (int n = 0; n < 2; n++) acc[a][m][n] = (f32x4){0.f, 0.f, 0.f, 0.f};
        deconv_tap<0, 2, 0>(wdTbhi, wdTblo, lb, co0, lm, g, acc);
        deconv_tap<0, 2, 1>(wdTbhi, wdTblo, lb, co0, lm, g, acc);
        deconv_tap<0, 2, 2>(wdTbhi, wdTblo, lb, co0, lm, g, acc);
        deconv_tap<1, 0, 0>(wdTbhi, wdTblo, lb, co0, lm, g, acc);
        deconv_tap<1, 0, 1>(wdTbhi, wdTblo, lb, co0, lm, g, acc);
        deconv_tap<1, 0, 2>(wdTbhi, wdTblo, lb, co0, lm, g, acc);
        deconv_epi(acc, affD, x, out, b, 2 * h0 + 1, co0, lm, g);
    }
}

// ---------- launcher ----------
extern "C" void kernel_launch(void* const* d_in, const int* in_sizes, int n_in,
                              void* d_out, int out_size, void* d_ws, size_t ws_size,
                              hipStream_t stream) {
    const float* x   = (const float*)d_in[0];
    const float* w_q = (const float*)d_in[1];
    const float* b_q = (const float*)d_in[2];
    const float* qs  = (const float*)d_in[3];
    const float* qb  = (const float*)d_in[4];
    const float* qm  = (const float*)d_in[5];
    const float* qv  = (const float*)d_in[6];
    const float* w_k = (const float*)d_in[7];
    const float* b_k = (const float*)d_in[8];
    const float* ks  = (const float*)d_in[9];
    const float* kb  = (const float*)d_in[10];
    const float* km  = (const float*)d_in[11];
    const float* kv  = (const float*)d_in[12];
    const float* w_v = (const float*)d_in[13];
    const float* b_v = (const float*)d_in[14];
    const float* w_d = (const float*)d_in[15];
    const float* ds  = (const float*)d_in[16];
    const float* db  = (const float*)d_in[17];
    const float* dm  = (const float*)d_in[18];
    const float* dv  = (const float*)d_in[19];
    float* out = (float*)d_out;

    char* wsb = (char*)d_ws;
    unsigned short* qTbhi = (unsigned short*)(wsb);               //  4,194,304
    unsigned short* qTblo = (unsigned short*)(wsb + 4194304);     //  4,194,304
    unsigned short* vTc   = (unsigned short*)(wsb + 8388608);     // 16,777,216
    unsigned short* kBhi  = (unsigned short*)(wsb + 25165824);    //  1,048,576
    unsigned short* kBlo  = (unsigned short*)(wsb + 26214400);    //  1,048,576
    unsigned short* wkThi = (unsigned short*)(wsb + 27262976);    //    589,824
    unsigned short* wkTlo = (unsigned short*)(wsb + 27852800);    //    589,824
    float*          affQ  = (float*)(wsb + 28442624);             //        512
    float*          affK  = (float*)(wsb + 28443136);             //        512
    float*          affD  = (float*)(wsb + 28443648);             //      4,096
    // X region: xTp{hi,lo} live [pam_xt .. pam_kconv_mfma]; then reused:
    unsigned short* xTphi = (unsigned short*)(wsb + 28447744);    // 34,611,200
    unsigned short* xTplo = (unsigned short*)(wsb + 63058944);    // 34,611,200 -> end 97,670,144
    unsigned short* outsP  = (unsigned short*)(wsb + 28447744);   //  4,460,544 (alias)
    unsigned short* wdTbhi = (unsigned short*)(wsb + 32908288);   //  2,359,296 (alias)
    unsigned short* wdTblo = (unsigned short*)(wsb + 35267584);   //  2,359,296 (alias)

    hipLaunchKernelGGL(pam_aff_kernel, dim3(1), dim3(640), 0, stream,
                       b_q, qs, qb, qm, qv, b_k, ks, kb, km, kv, ds, db, dm, dv,
                       affQ, affK, affD);
    hipLaunchKernelGGL(pam_wkt, dim3(1152), dim3(256), 0, stream, w_k, wkThi, wkTlo);
    hipLaunchKernelGGL(pam_xt, dim3(65, 8), dim3(256), 0, stream, x, xTphi, xTplo);
    hipLaunchKernelGGL(pam_qv_gemm, dim3(64, 5, 8), dim3(256), 0, stream,
                       x, w_q, w_v, b_v, affQ, qTbhi, qTblo, vTc);
    hipLaunchKernelGGL(pam_kconv_mfma, dim3(32, 8), dim3(256), 0, stream,
                       xTphi, xTplo, wkThi, wkTlo, affK, kBhi, kBlo);
    // xTp dead from here; aliased region reused for outsP / wdTb.
    hipLaunchKernelGGL(pam_wdtb, dim3(4608), dim3(256), 0, stream, w_d, wdTbhi, wdTblo);
    hipLaunchKernelGGL(pam_zeroP, dim3(1089), dim3(256), 0, stream, outsP);
    hipLaunchKernelGGL(pam_attn, dim3(64, 8), dim3(512), 0, stream,
                       qTbhi, qTblo, kBhi, kBlo, vTc, outsP);
    hipLaunchKernelGGL(pam_deconv_mfma, dim3(32, 8), dim3(1024), 0, stream,
                       outsP, wdTbhi, wdTblo, affD, x, out);
}

// Round 6
// 551.915 us; speedup vs baseline: 3.3861x; 1.1723x over previous
//
#include <hip/hip_runtime.h>
#include <hip/hip_bf16.h>
#include <cstdint>

#define BN_EPS 1e-5f

typedef short bf16x8 __attribute__((ext_vector_type(8)));
typedef float f32x4 __attribute__((ext_vector_type(4)));

// ---------- helpers ----------
__device__ __forceinline__ float bf16hi_to_f(uint32_t hi) {
    union { uint32_t u; float f; } c; c.u = hi; return c.f;
}
__device__ __forceinline__ uint32_t f_to_bf16(float f) {
    union { float f; uint32_t u; } c; c.f = f;
    uint32_t r = c.u + 0x7fffu + ((c.u >> 16) & 1u);  // RNE
    return r >> 16;
}
__device__ __forceinline__ void split_bf16(float v, unsigned short& hi, unsigned short& lo) {
    uint32_t h = f_to_bf16(v);
    float fh = bf16hi_to_f(h << 16);
    uint32_t l = f_to_bf16(v - fh);
    hi = (unsigned short)h; lo = (unsigned short)l;
}

// ---------- K0: BN affine precompute ----------
__global__ void pam_aff_kernel(const float* bq, const float* qs, const float* qb, const float* qm, const float* qv,
                               const float* bk, const float* ks, const float* kb, const float* km, const float* kv,
                               const float* ds, const float* db, const float* dm, const float* dv,
                               float* affQ, float* affK, float* affD) {
    int t = threadIdx.x;
    if (t < 64) {
        float inv = qs[t] * rsqrtf(qv[t] + BN_EPS);
        affQ[t] = inv; affQ[64 + t] = bq[t] * inv + qb[t] - qm[t] * inv;
    } else if (t < 128) {
        int i = t - 64;
        float inv = ks[i] * rsqrtf(kv[i] + BN_EPS);
        affK[i] = inv; affK[64 + i] = bk[i] * inv + kb[i] - km[i] * inv;
    } else {
        int i = t - 128;
        if (i < 512) {
            float inv = ds[i] * rsqrtf(dv[i] + BN_EPS);
            affD[i] = inv; affD[512 + i] = db[i] - dm[i] * inv;
        }
    }
}

// ---------- K1: transpose+split w_d (256,512,3,3) -> wdTb{hi,lo}[tap][co][ci] ----------
__global__ void pam_wdtb(const float* __restrict__ wd,
                         unsigned short* __restrict__ wdTbhi, unsigned short* __restrict__ wdTblo) {
    int o = blockIdx.x * 256 + threadIdx.x;       // < 9*512*256 = 1,179,648
    int ci = o & 255; int co = (o >> 8) & 511; int tap = o >> 17;
    float v = wd[(size_t)ci * 4608 + co * 9 + tap];
    unsigned short h, l;
    split_bf16(v, h, l);
    wdTbhi[o] = h; wdTblo[o] = l;
}

// ---------- K1b: transpose+split w_k (64,512,3,3) -> wkT{hi,lo}[k9][d][c] ----------
__global__ void pam_wkt(const float* __restrict__ wk,
                        unsigned short* __restrict__ wkThi, unsigned short* __restrict__ wkTlo) {
    int o = blockIdx.x * 256 + threadIdx.x;       // < 9*64*512 = 294912
    int c = o & 511; int d = (o >> 9) & 63; int kk = o >> 15;
    float v = wk[((size_t)d * 512 + c) * 9 + kk];
    unsigned short h, l;
    split_bf16(v, h, l);
    wkThi[o] = h; wkTlo[o] = l;
}

// ---------- K1c: x -> xTp{hi,lo}[b][65][65][512]  (pixel-major, c-contig, -1 pad) ----------
__global__ __launch_bounds__(256) void pam_xt(const float* __restrict__ x,
                                              unsigned short* __restrict__ xTphi,
                                              unsigned short* __restrict__ xTplo) {
    int t = threadIdx.x;
    int ri = blockIdx.x;       // 0..64 ; input row hi = ri-1
    int b = blockIdx.y;
    size_t rowbase = ((size_t)b * 65 + ri) * 65 * 512;
    uint4 z = make_uint4(0, 0, 0, 0);
    if (ri == 0) {
        for (int idx = t; idx < 65 * 512 / 8; idx += 256) {
            *(uint4*)(xTphi + rowbase + (size_t)idx * 8) = z;
            *(uint4*)(xTplo + rowbase + (size_t)idx * 8) = z;
        }
        return;
    }
    if (t < 64) {
        *(uint4*)(xTphi + rowbase + (size_t)t * 8) = z;
        *(uint4*)(xTplo + rowbase + (size_t)t * 8) = z;
    }
    int hi = ri - 1;
    int wi = t & 63;
    const float* xb = x + (size_t)b * 512 * 4096 + (size_t)hi * 64 + wi;
    for (int it = 0; it < 16; ++it) {
        int cg = (t >> 6) + it * 4;     // 0..63
        int c0 = cg * 8;
        unsigned short h[8], l[8];
        #pragma unroll
        for (int j = 0; j < 8; j++) {
            float v = xb[(size_t)(c0 + j) * 4096];
            split_bf16(v, h[j], l[j]);
        }
        size_t dst = rowbase + (size_t)(wi + 1) * 512 + c0;
        uint4 ph = make_uint4((uint32_t)h[0] | ((uint32_t)h[1] << 16),
                              (uint32_t)h[2] | ((uint32_t)h[3] << 16),
                              (uint32_t)h[4] | ((uint32_t)h[5] << 16),
                              (uint32_t)h[6] | ((uint32_t)h[7] << 16));
        uint4 pl = make_uint4((uint32_t)l[0] | ((uint32_t)l[1] << 16),
                              (uint32_t)l[2] | ((uint32_t)l[3] << 16),
                              (uint32_t)l[4] | ((uint32_t)l[5] << 16),
                              (uint32_t)l[6] | ((uint32_t)l[7] << 16));
        *(uint4*)(xTphi + dst) = ph;
        *(uint4*)(xTplo + dst) = pl;
    }
}

// ---------- K1d: zero-fill outsP pad entries ----------
__global__ void pam_zeroP(unsigned short* __restrict__ p) {
    size_t i = ((size_t)blockIdx.x * 256 + threadIdx.x) * 8;   // total 2,230,272 ushorts
    uint4 z = make_uint4(0, 0, 0, 0);
    *(uint4*)(p + i) = z;
}

// ---------- K2: fused q (1x1 conv + BN) and v (1x1 conv + bias) as one GEMM ----------
// q rows -> qF{hi,lo}[b][ntile 256][s 2][g 4][lm 16][j 8]  (frag-linear, elem Q[n][d])
// v rows -> vF[b][ks 128][ct 16][g 4][lm 16][j 8] bf16     (elem V[n][c])
__global__ __launch_bounds__(256) void pam_qv_gemm(
    const float* __restrict__ x, const float* __restrict__ wq, const float* __restrict__ wv,
    const float* __restrict__ bv, const float* __restrict__ affQ,
    unsigned short* __restrict__ qFhi, unsigned short* __restrict__ qFlo,
    unsigned short* __restrict__ vF) {
    __shared__ float As[64][17];
    __shared__ __align__(16) float Bs[16][64];
    int t = threadIdx.x;
    int b = blockIdx.z, row0 = blockIdx.y * 64, p0 = blockIdx.x * 64;
    int tc = t & 15, tr = t >> 4;
    float acc[4][4] = {};
    int ra = t >> 2, kk4 = (t & 3) * 4;
    int Ra = row0 + ra;
    const float* wrow = (Ra < 64) ? (wq + (size_t)Ra * 512) : (wv + (size_t)(Ra - 64) * 512);
    const float* xb = x + (size_t)b * 512 * 4096;
    int kb_ = t >> 4, pb4 = (t & 15) * 4;
    for (int k0 = 0; k0 < 512; k0 += 16) {
        float4 a4 = *(const float4*)(wrow + k0 + kk4);
        As[ra][kk4 + 0] = a4.x; As[ra][kk4 + 1] = a4.y;
        As[ra][kk4 + 2] = a4.z; As[ra][kk4 + 3] = a4.w;
        *(float4*)&Bs[kb_][pb4] = *(const float4*)(xb + (size_t)(k0 + kb_) * 4096 + p0 + pb4);
        __syncthreads();
        #pragma unroll
        for (int kk = 0; kk < 16; ++kk) {
            float a[4], bb[4];
            #pragma unroll
            for (int i = 0; i < 4; i++) a[i] = As[tr * 4 + i][kk];
            #pragma unroll
            for (int j = 0; j < 4; j++) bb[j] = Bs[kk][tc * 4 + j];
            #pragma unroll
            for (int i = 0; i < 4; i++)
                #pragma unroll
                for (int j = 0; j < 4; j++) acc[i][j] = fmaf(a[i], bb[j], acc[i][j]);
        }
        __syncthreads();
    }
    #pragma unroll
    for (int i = 0; i < 4; i++) {
        int R = row0 + tr * 4 + i;
        if (R < 64) {
            float sc = affQ[R], sh = affQ[64 + R];
            int s_ = R >> 5, gF = (R >> 3) & 3, jF = R & 7;
            #pragma unroll
            for (int j = 0; j < 4; j++) {
                int p = p0 + tc * 4 + j;
                float val = fmaf(acc[i][j], sc, sh);
                unsigned short hi, lo;
                split_bf16(val, hi, lo);
                size_t idx = (size_t)(b * 256 + (p >> 4)) * 1024 + s_ * 512 + gF * 128 + (p & 15) * 8 + jF;
                qFhi[idx] = hi; qFlo[idx] = lo;
            }
        } else {
            int c = R - 64;
            float bb = bv[c];
            int pb = p0 + tc * 4;
            ushort4 u;
            u.x = (unsigned short)f_to_bf16(acc[i][0] + bb);
            u.y = (unsigned short)f_to_bf16(acc[i][1] + bb);
            u.z = (unsigned short)f_to_bf16(acc[i][2] + bb);
            u.w = (unsigned short)f_to_bf16(acc[i][3] + bb);
            size_t idx = (size_t)(b * 128 + (pb >> 5)) * 8192 + (c >> 4) * 512 +
                         ((pb >> 3) & 3) * 128 + (c & 15) * 8 + (pb & 7);
            *(ushort4*)(vF + idx) = u;
        }
    }
}

// ---------- K3: k-conv as tap-decomposed MFMA GEMM ----------
// output kF{hi,lo}[b][mt 64][s 2][g 4][lm 16][j 8]  (elem K[m][d])
__global__ __launch_bounds__(256) void pam_kconv_mfma(
    const unsigned short* __restrict__ xTphi, const unsigned short* __restrict__ xTplo,
    const unsigned short* __restrict__ wkThi, const unsigned short* __restrict__ wkTlo,
    const float* __restrict__ affK,
    unsigned short* __restrict__ kFhi, unsigned short* __restrict__ kFlo) {
    int t = threadIdx.x;
    int hk = blockIdx.x, b = blockIdx.y;
    int wv = t >> 6, lane = t & 63, g = lane >> 4, lm = lane & 15;
    int goff = g * 8;
    f32x4 acc0 = (f32x4){0.f, 0.f, 0.f, 0.f};
    f32x4 acc1 = (f32x4){0.f, 0.f, 0.f, 0.f};
    #pragma unroll
    for (int r = 0; r < 3; r++) {
        size_t arow = ((size_t)(b * 65 + 2 * hk + r)) * 65 * 512;
        #pragma unroll
        for (int s = 0; s < 3; s++) {
            size_t aoff = arow + (size_t)(2 * lm + s) * 512 + goff;   // pixel wk=lm
            const unsigned short* pa0h = xTphi + aoff;
            const unsigned short* pa0l = xTplo + aoff;
            size_t boff = ((size_t)((r * 3 + s) * 64 + wv * 16 + lm)) * 512 + goff;
            const unsigned short* pb_h = wkThi + boff;
            const unsigned short* pb_l = wkTlo + boff;
            #pragma unroll 4
            for (int c0 = 0; c0 < 512; c0 += 32) {
                bf16x8 a0h = *(const bf16x8*)(pa0h + c0);
                bf16x8 a1h = *(const bf16x8*)(pa0h + 32 * 512 + c0);   // pixel wk=lm+16
                bf16x8 a0l = *(const bf16x8*)(pa0l + c0);
                bf16x8 a1l = *(const bf16x8*)(pa0l + 32 * 512 + c0);
                bf16x8 bh  = *(const bf16x8*)(pb_h + c0);
                bf16x8 bl  = *(const bf16x8*)(pb_l + c0);
                acc0 = __builtin_amdgcn_mfma_f32_16x16x32_bf16(a0h, bh, acc0, 0, 0, 0);
                acc1 = __builtin_amdgcn_mfma_f32_16x16x32_bf16(a1h, bh, acc1, 0, 0, 0);
                acc0 = __builtin_amdgcn_mfma_f32_16x16x32_bf16(a0l, bh, acc0, 0, 0, 0);
                acc1 = __builtin_amdgcn_mfma_f32_16x16x32_bf16(a1l, bh, acc1, 0, 0, 0);
                acc0 = __builtin_amdgcn_mfma_f32_16x16x32_bf16(a0h, bl, acc0, 0, 0, 0);
                acc1 = __builtin_amdgcn_mfma_f32_16x16x32_bf16(a1h, bl, acc1, 0, 0, 0);
            }
        }
    }
    int d = wv * 16 + lm;
    float sc = affK[d], sh = affK[64 + d];
    int s_ = d >> 5, gF = (d >> 3) & 3, jF = d & 7;
    #pragma unroll
    for (int i = 0; i < 4; i++) {
        int m1 = hk * 32 + g * 4 + i;         // acc0 pixel
        int m2 = m1 + 16;                     // acc1 pixel
        float v0 = fmaf(acc0[i], sc, sh);
        float v1 = fmaf(acc1[i], sc, sh);
        unsigned short hh, ll;
        split_bf16(v0, hh, ll);
        size_t i1 = (size_t)(b * 64 + (m1 >> 4)) * 1024 + s_ * 512 + gF * 128 + (m1 & 15) * 8 + jF;
        kFhi[i1] = hh; kFlo[i1] = ll;
        split_bf16(v1, hh, ll);
        size_t i2 = (size_t)(b * 64 + (m2 >> 4)) * 1024 + s_ * 512 + gF * 128 + (m2 & 15) * 8 + jF;
        kFhi[i2] = hh; kFlo[i2] = ll;
    }
}

// ---------- K4: MFMA attention, frag-linear layouts, XCD-pinned grid ----------
// grid (8 b, 64 mt): linear wg id % 8 == b -> each XCD keeps one batch L2-resident.
// All MFMA operand loads are contiguous 1KB per wave; P in LDS frag-linear
// Pl[ks 128][g 4][m 16][j 8] -> conflict-free ds_read_b128 in PV.
__global__ __launch_bounds__(512, 2) void pam_attn(
    const unsigned short* __restrict__ qFhi, const unsigned short* __restrict__ qFlo,
    const unsigned short* __restrict__ kFhi, const unsigned short* __restrict__ kFlo,
    const unsigned short* __restrict__ vF, unsigned short* __restrict__ outsP) {
    __shared__ unsigned short Pl[65536];   // 128 KiB
    __shared__ float redM[8][16];
    __shared__ float redS[8][16];
    int t = threadIdx.x;
    int b = blockIdx.x, mt = blockIdx.y;
    int wid = t >> 6, lane = t & 63;
    int g = lane >> 4, lm = lane & 15;

    // K frags: kF[b][mt][s][g][lm][8], s-stride 512
    size_t kidx = (size_t)(b * 64 + mt) * 1024 + g * 128 + lm * 8;
    bf16x8 ah0 = *(const bf16x8*)(kFhi + kidx);
    bf16x8 ah1 = *(const bf16x8*)(kFhi + kidx + 512);
    bf16x8 al0 = *(const bf16x8*)(kFlo + kidx);
    bf16x8 al1 = *(const bf16x8*)(kFlo + kidx + 512);

    f32x4 ev[32];
    #pragma unroll
    for (int f = 0; f < 32; f++) ev[f] = (f32x4){0.f, 0.f, 0.f, 0.f};

    // Q frags: qF[b][ftile][s][g][lm][8]; ftile = wid*32 + f
    const unsigned short* qh = qFhi + (size_t)(b * 256 + wid * 32) * 1024 + g * 128 + lm * 8;
    const unsigned short* ql = qFlo + (size_t)(b * 256 + wid * 32) * 1024 + g * 128 + lm * 8;
    #pragma unroll
    for (int f = 0; f < 32; f++) {
        const unsigned short* qhp = qh + (size_t)f * 1024;
        const unsigned short* qlp = ql + (size_t)f * 1024;
        bf16x8 bh0 = *(const bf16x8*)(qhp);
        bf16x8 bh1 = *(const bf16x8*)(qhp + 512);
        bf16x8 bl0 = *(const bf16x8*)(qlp);
        bf16x8 bl1 = *(const bf16x8*)(qlp + 512);
        f32x4 e = ev[f];
        e = __builtin_amdgcn_mfma_f32_16x16x32_bf16(ah0, bh0, e, 0, 0, 0);
        e = __builtin_amdgcn_mfma_f32_16x16x32_bf16(ah1, bh1, e, 0, 0, 0);
        e = __builtin_amdgcn_mfma_f32_16x16x32_bf16(ah0, bl0, e, 0, 0, 0);
        e = __builtin_amdgcn_mfma_f32_16x16x32_bf16(ah1, bl1, e, 0, 0, 0);
        e = __builtin_amdgcn_mfma_f32_16x16x32_bf16(al0, bh0, e, 0, 0, 0);
        e = __builtin_amdgcn_mfma_f32_16x16x32_bf16(al1, bh1, e, 0, 0, 0);
        ev[f] = e;
    }

    float rmax[4];
    #pragma unroll
    for (int i = 0; i < 4; i++) {
        float m_ = ev[0][i];
        #pragma unroll
        for (int f = 1; f < 32; f++) m_ = fmaxf(m_, ev[f][i]);
        #pragma unroll
        for (int off = 1; off < 16; off <<= 1) m_ = fmaxf(m_, __shfl_xor(m_, off));
        rmax[i] = m_;
    }
    if (lm == 0) {
        #pragma unroll
        for (int i = 0; i < 4; i++) redM[wid][g * 4 + i] = rmax[i];
    }
    __syncthreads();
    #pragma unroll
    for (int i = 0; i < 4; i++) {
        float m_ = redM[0][g * 4 + i];
        #pragma unroll
        for (int ww = 1; ww < 8; ww++) m_ = fmaxf(m_, redM[ww][g * 4 + i]);
        rmax[i] = m_;
    }

    // exp, round to bf16, sum ROUNDED values, store frag-linear:
    // n = (wid*32+f)*16 + lm -> ks = wid*16 + (f>>1); k = (f&1)*16+lm
    float rsum[4] = {0.f, 0.f, 0.f, 0.f};
    #pragma unroll
    for (int f = 0; f < 32; f++) {
        int ks = wid * 16 + (f >> 1);
        int gF = (f & 1) * 2 + (lm >> 3);
        int jF = lm & 7;
        #pragma unroll
        for (int i = 0; i < 4; i++) {
            float p = __expf(ev[f][i] - rmax[i]);
            uint32_t u = f_to_bf16(p);
            rsum[i] += bf16hi_to_f(u << 16);
            Pl[((ks * 4 + gF) * 16 + (g * 4 + i)) * 8 + jF] = (unsigned short)u;
        }
    }
    #pragma unroll
    for (int i = 0; i < 4; i++) {
        float s_ = rsum[i];
        #pragma unroll
        for (int off = 1; off < 16; off <<= 1) s_ += __shfl_xor(s_, off);
        rsum[i] = s_;
    }
    if (lm == 0) {
        #pragma unroll
        for (int i = 0; i < 4; i++) redS[wid][g * 4 + i] = rsum[i];
    }
    __syncthreads();   // P fully written + sums available
    float sinv[4];
    #pragma unroll
    for (int i = 0; i < 4; i++) {
        float s_ = 0.f;
        #pragma unroll
        for (int ww = 0; ww < 8; ww++) s_ += redS[ww][g * 4 + i];
        sinv[i] = 1.f / s_;
    }

    // PV: wave -> c-slices ct0 = wid*2, ct0+1. vF[b][ks][ct][g][lm][8]
    f32x4 o0 = (f32x4){0.f, 0.f, 0.f, 0.f};
    f32x4 o1 = (f32x4){0.f, 0.f, 0.f, 0.f};
    const unsigned short* vb = vF + (size_t)b * 1048576 + (wid * 2) * 512 + g * 128 + lm * 8;
    #pragma unroll 4
    for (int ks = 0; ks < 128; ks++) {
        bf16x8 pa = *(const bf16x8*)(Pl + ((ks * 4 + g) * 16 + lm) * 8);
        bf16x8 b0 = *(const bf16x8*)(vb + (size_t)ks * 8192);
        bf16x8 b1 = *(const bf16x8*)(vb + (size_t)ks * 8192 + 512);
        o0 = __builtin_amdgcn_mfma_f32_16x16x32_bf16(pa, b0, o0, 0, 0, 0);
        o1 = __builtin_amdgcn_mfma_f32_16x16x32_bf16(pa, b1, o1, 0, 0, 0);
    }

    int c0 = wid * 32;
    #pragma unroll
    for (int i = 0; i < 4; i++) {
        int m = mt * 16 + g * 4 + i;          // pixel index
        int hk2 = m >> 5, wk2 = m & 31;
        unsigned short* op = outsP + (((size_t)(b * 33 + hk2)) * 33 + wk2) * 256;
        op[c0 + lm]      = (unsigned short)f_to_bf16(o0[i] * sinv[i]);
        op[c0 + 16 + lm] = (unsigned short)f_to_bf16(o1[i] * sinv[i]);
    }
}

// ---------- K5: transpose-conv 3x3 s2 p1 op1 as balanced row-pair MFMA + BN + ReLU + res ----------
template<int LROW, int KH, int KW>
__device__ __forceinline__ void deconv_tap(
    const unsigned short* __restrict__ wdTbhi, const unsigned short* __restrict__ wdTblo,
    const char* lb, int co0, int lm, int g, f32x4 (&acc)[2][2][2]) {
    constexpr int wop = (KW == 1) ? 0 : 1;
    constexpr int dw = (KW == 0) ? 1 : 0;
    constexpr int tap = KH * 3 + KW;
    int p0 = LROW * 33 + lm + dw;
    int p1 = p0 + 16;
    uint32_t s0 = ((uint32_t)(p0 & 7)) << 4;
    uint32_t s1 = ((uint32_t)(p1 & 7)) << 4;
    uint32_t b0a = (uint32_t)p0 * 512 + (uint32_t)g * 16;
    uint32_t b1a = (uint32_t)p1 * 512 + (uint32_t)g * 16;
    size_t a0 = ((size_t)tap * 512 + co0 + lm) * 256 + g * 8;
    size_t a1 = a0 + 16 * 256;
    #pragma unroll
    for (int c0 = 0; c0 < 256; c0 += 32) {
        bf16x8 bv0 = *(const bf16x8*)(lb + ((b0a + (uint32_t)c0 * 2) ^ s0));
        bf16x8 bv1 = *(const bf16x8*)(lb + ((b1a + (uint32_t)c0 * 2) ^ s1));
        bf16x8 ah0 = *(const bf16x8*)(wdTbhi + a0 + c0);
        bf16x8 ah1 = *(const bf16x8*)(wdTbhi + a1 + c0);
        bf16x8 al0 = *(const bf16x8*)(wdTblo + a0 + c0);
        bf16x8 al1 = *(const bf16x8*)(wdTblo + a1 + c0);
        acc[wop][0][0] = __builtin_amdgcn_mfma_f32_16x16x32_bf16(ah0, bv0, acc[wop][0][0], 0, 0, 0);
        acc[wop][0][1] = __builtin_amdgcn_mfma_f32_16x16x32_bf16(ah0, bv1, acc[wop][0][1], 0, 0, 0);
        acc[wop][1][0] = __builtin_amdgcn_mfma_f32_16x16x32_bf16(ah1, bv0, acc[wop][1][0], 0, 0, 0);
        acc[wop][1][1] = __builtin_amdgcn_mfma_f32_16x16x32_bf16(ah1, bv1, acc[wop][1][1], 0, 0, 0);
        acc[wop][0][0] = __builtin_amdgcn_mfma_f32_16x16x32_bf16(al0, bv0, acc[wop][0][0], 0, 0, 0);
        acc[wop][0][1] = __builtin_amdgcn_mfma_f32_16x16x32_bf16(al0, bv1, acc[wop][0][1], 0, 0, 0);
        acc[wop][1][0] = __builtin_amdgcn_mfma_f32_16x16x32_bf16(al1, bv0, acc[wop][1][0], 0, 0, 0);
        acc[wop][1][1] = __builtin_amdgcn_mfma_f32_16x16x32_bf16(al1, bv1, acc[wop][1][1], 0, 0, 0);
    }
}

__device__ __forceinline__ void deconv_epi(
    const f32x4 (&acc)[2][2][2], const float* __restrict__ affD,
    const float* __restrict__ x, float* __restrict__ out,
    int b, int ho, int co0, int lm, int g) {
    #pragma unroll
    for (int mf = 0; mf < 2; mf++) {
        #pragma unroll
        for (int i = 0; i < 4; i++) {
            int co = co0 + mf * 16 + g * 4 + i;
            float sc = affD[co], sh = affD[512 + co];
            const float* xr = x + (((size_t)b * 512 + co) * 64 + ho) * 64;
            float* orow = out + (((size_t)b * 512 + co) * 64 + ho) * 64;
            #pragma unroll
            for (int nf = 0; nf < 2; nf++) {
                int wp = nf * 16 + lm;
                float2 xv = *(const float2*)(xr + 2 * wp);
                float2 st;
                st.x = fmaxf(fmaf(acc[0][mf][nf][i], sc, sh), 0.f) + xv.x;
                st.y = fmaxf(fmaf(acc[1][mf][nf][i], sc, sh), 0.f) + xv.y;
                *(float2*)(orow + 2 * wp) = st;
            }
        }
    }
}

__global__ __launch_bounds__(1024, 4) void pam_deconv_mfma(
    const unsigned short* __restrict__ outsP,
    const unsigned short* __restrict__ wdTbhi, const unsigned short* __restrict__ wdTblo,
    const float* __restrict__ affD, const float* __restrict__ x, float* __restrict__ out) {
    __shared__ unsigned short Pb[16896];   // 2 rows x 33 px x 256 ci
    int t = threadIdx.x;
    int h0 = blockIdx.x, b = blockIdx.y;
    const unsigned short* src = outsP + ((size_t)(b * 33 + h0) * 33) * 256;
    for (int idx = t; idx < 2112; idx += 1024) {
        uint4 v = *(const uint4*)(src + (size_t)idx * 8);
        uint32_t byte = (uint32_t)idx * 16;
        byte ^= ((byte >> 9) & 7) << 4;
        *(uint4*)((char*)Pb + byte) = v;
    }
    __syncthreads();

    int wid = t >> 6, lane = t & 63, g = lane >> 4, lm = lane & 15;
    int co0 = wid * 32;
    const char* lb = (const char*)Pb;

    {   // even output row ho = 2*h0 : kh=1, B row h0 (LDS row 0)
        f32x4 acc[2][2][2];
        #pragma unroll
        for (int a = 0; a < 2; a++)
            #pragma unroll
            for (int m = 0; m < 2; m++)
                #pragma unroll
                for (int n = 0; n < 2; n++) acc[a][m][n] = (f32x4){0.f, 0.f, 0.f, 0.f};
        deconv_tap<0, 1, 0>(wdTbhi, wdTblo, lb, co0, lm, g, acc);
        deconv_tap<0, 1, 1>(wdTbhi, wdTblo, lb, co0, lm, g, acc);
        deconv_tap<0, 1, 2>(wdTbhi, wdTblo, lb, co0, lm, g, acc);
        deconv_epi(acc, affD, x, out, b, 2 * h0, co0, lm, g);
    }
    {   // odd output row ho = 2*h0+1 : kh=2 B row h0, kh=0 B row h0+1
        f32x4 acc[2][2][2];
        #pragma unroll
        for (int a = 0; a < 2; a++)
            #pragma unroll
            for (int m = 0; m < 2; m++)
                #pragma unroll
                for (int n = 0; n < 2; n++) acc[a][m][n] = (f32x4){0.f, 0.f, 0.f, 0.f};
        deconv_tap<0, 2, 0>(wdTbhi, wdTblo, lb, co0, lm, g, acc);
        deconv_tap<0, 2, 1>(wdTbhi, wdTblo, lb, co0, lm, g, acc);
        deconv_tap<0, 2, 2>(wdTbhi, wdTblo, lb, co0, lm, g, acc);
        deconv_tap<1, 0, 0>(wdTbhi, wdTblo, lb, co0, lm, g, acc);
        deconv_tap<1, 0, 1>(wdTbhi, wdTblo, lb, co0, lm, g, acc);
        deconv_tap<1, 0, 2>(wdTbhi, wdTblo, lb, co0, lm, g, acc);
        deconv_epi(acc, affD, x, out, b, 2 * h0 + 1, co0, lm, g);
    }
}

// ---------- launcher ----------
extern "C" void kernel_launch(void* const* d_in, const int* in_sizes, int n_in,
                              void* d_out, int out_size, void* d_ws, size_t ws_size,
                              hipStream_t stream) {
    const float* x   = (const float*)d_in[0];
    const float* w_q = (const float*)d_in[1];
    const float* b_q = (const float*)d_in[2];
    const float* qs  = (const float*)d_in[3];
    const float* qb  = (const float*)d_in[4];
    const float* qm  = (const float*)d_in[5];
    const float* qv  = (const float*)d_in[6];
    const float* w_k = (const float*)d_in[7];
    const float* b_k = (const float*)d_in[8];
    const float* ks  = (const float*)d_in[9];
    const float* kb  = (const float*)d_in[10];
    const float* km  = (const float*)d_in[11];
    const float* kv  = (const float*)d_in[12];
    const float* w_v = (const float*)d_in[13];
    const float* b_v = (const float*)d_in[14];
    const float* w_d = (const float*)d_in[15];
    const float* ds  = (const float*)d_in[16];
    const float* db  = (const float*)d_in[17];
    const float* dm  = (const float*)d_in[18];
    const float* dv  = (const float*)d_in[19];
    float* out = (float*)d_out;

    char* wsb = (char*)d_ws;
    unsigned short* qFhi  = (unsigned short*)(wsb);               //  4,194,304
    unsigned short* qFlo  = (unsigned short*)(wsb + 4194304);     //  4,194,304
    unsigned short* vF    = (unsigned short*)(wsb + 8388608);     // 16,777,216
    unsigned short* kFhi  = (unsigned short*)(wsb + 25165824);    //  1,048,576
    unsigned short* kFlo  = (unsigned short*)(wsb + 26214400);    //  1,048,576
    unsigned short* wkThi = (unsigned short*)(wsb + 27262976);    //    589,824
    unsigned short* wkTlo = (unsigned short*)(wsb + 27852800);    //    589,824
    float*          affQ  = (float*)(wsb + 28442624);             //        512
    float*          affK  = (float*)(wsb + 28443136);             //        512
    float*          affD  = (float*)(wsb + 28443648);             //      4,096
    // X region: xTp{hi,lo} live [pam_xt .. pam_kconv_mfma]; then reused:
    unsigned short* xTphi = (unsigned short*)(wsb + 28447744);    // 34,611,200
    unsigned short* xTplo = (unsigned short*)(wsb + 63058944);    // 34,611,200 -> end 97,670,144
    unsigned short* outsP  = (unsigned short*)(wsb + 28447744);   //  4,460,544 (alias)
    unsigned short* wdTbhi = (unsigned short*)(wsb + 32908288);   //  2,359,296 (alias)
    unsigned short* wdTblo = (unsigned short*)(wsb + 35267584);   //  2,359,296 (alias)

    hipLaunchKernelGGL(pam_aff_kernel, dim3(1), dim3(640), 0, stream,
                       b_q, qs, qb, qm, qv, b_k, ks, kb, km, kv, ds, db, dm, dv,
                       affQ, affK, affD);
    hipLaunchKernelGGL(pam_wkt, dim3(1152), dim3(256), 0, stream, w_k, wkThi, wkTlo);
    hipLaunchKernelGGL(pam_xt, dim3(65, 8), dim3(256), 0, stream, x, xTphi, xTplo);
    hipLaunchKernelGGL(pam_qv_gemm, dim3(64, 5, 8), dim3(256), 0, stream,
                       x, w_q, w_v, b_v, affQ, qFhi, qFlo, vF);
    hipLaunchKernelGGL(pam_kconv_mfma, dim3(32, 8), dim3(256), 0, stream,
                       xTphi, xTplo, wkThi, wkTlo, affK, kFhi, kFlo);
    // xTp dead from here; aliased region reused for outsP / wdTb.
    hipLaunchKernelGGL(pam_wdtb, dim3(4608), dim3(256), 0, stream, w_d, wdTbhi, wdTblo);
    hipLaunchKernelGGL(pam_zeroP, dim3(1089), dim3(256), 0, stream, outsP);
    hipLaunchKernelGGL(pam_attn, dim3(8, 64), dim3(512), 0, stream,
                       qFhi, qFlo, kFhi, kFlo, vF, outsP);
    hipLaunchKernelGGL(pam_deconv_mfma, dim3(32, 8), dim3(1024), 0, stream,
                       outsP, wdTbhi, wdTblo, affD, x, out);
}

// Round 7
// 464.315 us; speedup vs baseline: 4.0249x; 1.1887x over previous
//
#include <hip/hip_runtime.h>
#include <hip/hip_bf16.h>
#include <cstdint>

#define BN_EPS 1e-5f

typedef short bf16x8 __attribute__((ext_vector_type(8)));
typedef float f32x4 __attribute__((ext_vector_type(4)));

// ---------- helpers ----------
__device__ __forceinline__ float bf16hi_to_f(uint32_t hi) {
    union { uint32_t u; float f; } c; c.u = hi; return c.f;
}
__device__ __forceinline__ uint32_t f_to_bf16(float f) {
    union { float f; uint32_t u; } c; c.f = f;
    uint32_t r = c.u + 0x7fffu + ((c.u >> 16) & 1u);  // RNE
    return r >> 16;
}
__device__ __forceinline__ void split_bf16(float v, unsigned short& hi, unsigned short& lo) {
    uint32_t h = f_to_bf16(v);
    float fh = bf16hi_to_f(h << 16);
    uint32_t l = f_to_bf16(v - fh);
    hi = (unsigned short)h; lo = (unsigned short)l;
}

// ---------- K0: BN affine precompute ----------
__global__ void pam_aff_kernel(const float* bq, const float* qs, const float* qb, const float* qm, const float* qv,
                               const float* bk, const float* ks, const float* kb, const float* km, const float* kv,
                               const float* ds, const float* db, const float* dm, const float* dv,
                               float* affQ, float* affK, float* affD) {
    int t = threadIdx.x;
    if (t < 64) {
        float inv = qs[t] * rsqrtf(qv[t] + BN_EPS);
        affQ[t] = inv; affQ[64 + t] = bq[t] * inv + qb[t] - qm[t] * inv;
    } else if (t < 128) {
        int i = t - 64;
        float inv = ks[i] * rsqrtf(kv[i] + BN_EPS);
        affK[i] = inv; affK[64 + i] = bk[i] * inv + kb[i] - km[i] * inv;
    } else {
        int i = t - 128;
        if (i < 512) {
            float inv = ds[i] * rsqrtf(dv[i] + BN_EPS);
            affD[i] = inv; affD[512 + i] = db[i] - dm[i] * inv;
        }
    }
}

// ---------- K1: w_d (256,512,3,3) -> frag-linear bf16 wdF[tap][ct 32][cs 8][lane 64][j 8] ----------
// element: wdF for A-frag of mfma16x16x32: A[co=ct*16+lm][ci=cs*32+g*8+j], lane=g*16+lm
__global__ void pam_wdtb(const float* __restrict__ wd, unsigned short* __restrict__ wdF) {
    int o = blockIdx.x * 256 + threadIdx.x;       // < 9*512*256 = 1,179,648
    int ci = o & 255; int co = (o >> 8) & 511; int tap = o >> 17;
    float v = wd[(size_t)ci * 4608 + co * 9 + tap];
    int ct = co >> 4, lmr = co & 15, cs = ci >> 5, g = (ci >> 3) & 3, j = ci & 7;
    size_t idx = (((size_t)(tap * 32 + ct) * 8 + cs) * 512) + g * 128 + lmr * 8 + j;
    wdF[idx] = (unsigned short)f_to_bf16(v);
}

// ---------- K1b: transpose+split w_k (64,512,3,3) -> wkT{hi,lo}[k9][d][c] ----------
__global__ void pam_wkt(const float* __restrict__ wk,
                        unsigned short* __restrict__ wkThi, unsigned short* __restrict__ wkTlo) {
    int o = blockIdx.x * 256 + threadIdx.x;       // < 9*64*512 = 294912
    int c = o & 511; int d = (o >> 9) & 63; int kk = o >> 15;
    float v = wk[((size_t)d * 512 + c) * 9 + kk];
    unsigned short h, l;
    split_bf16(v, h, l);
    wkThi[o] = h; wkTlo[o] = l;
}

// ---------- K1c: x -> xTp{hi,lo}[b][65][65][512]  (pixel-major, c-contig, -1 pad) ----------
__global__ __launch_bounds__(256) void pam_xt(const float* __restrict__ x,
                                              unsigned short* __restrict__ xTphi,
                                              unsigned short* __restrict__ xTplo) {
    int t = threadIdx.x;
    int ri = blockIdx.x;       // 0..64 ; input row hi = ri-1
    int b = blockIdx.y;
    size_t rowbase = ((size_t)b * 65 + ri) * 65 * 512;
    uint4 z = make_uint4(0, 0, 0, 0);
    if (ri == 0) {
        for (int idx = t; idx < 65 * 512 / 8; idx += 256) {
            *(uint4*)(xTphi + rowbase + (size_t)idx * 8) = z;
            *(uint4*)(xTplo + rowbase + (size_t)idx * 8) = z;
        }
        return;
    }
    if (t < 64) {
        *(uint4*)(xTphi + rowbase + (size_t)t * 8) = z;
        *(uint4*)(xTplo + rowbase + (size_t)t * 8) = z;
    }
    int hi = ri - 1;
    int wi = t & 63;
    const float* xb = x + (size_t)b * 512 * 4096 + (size_t)hi * 64 + wi;
    for (int it = 0; it < 16; ++it) {
        int cg = (t >> 6) + it * 4;     // 0..63
        int c0 = cg * 8;
        unsigned short h[8], l[8];
        #pragma unroll
        for (int j = 0; j < 8; j++) {
            float v = xb[(size_t)(c0 + j) * 4096];
            split_bf16(v, h[j], l[j]);
        }
        size_t dst = rowbase + (size_t)(wi + 1) * 512 + c0;
        uint4 ph = make_uint4((uint32_t)h[0] | ((uint32_t)h[1] << 16),
                              (uint32_t)h[2] | ((uint32_t)h[3] << 16),
                              (uint32_t)h[4] | ((uint32_t)h[5] << 16),
                              (uint32_t)h[6] | ((uint32_t)h[7] << 16));
        uint4 pl = make_uint4((uint32_t)l[0] | ((uint32_t)l[1] << 16),
                              (uint32_t)l[2] | ((uint32_t)l[3] << 16),
                              (uint32_t)l[4] | ((uint32_t)l[5] << 16),
                              (uint32_t)l[6] | ((uint32_t)l[7] << 16));
        *(uint4*)(xTphi + dst) = ph;
        *(uint4*)(xTplo + dst) = pl;
    }
}

// ---------- K1d: zero-fill outsP pad entries ----------
__global__ void pam_zeroP(unsigned short* __restrict__ p) {
    size_t i = ((size_t)blockIdx.x * 256 + threadIdx.x) * 8;   // total 2,230,272 ushorts
    uint4 z = make_uint4(0, 0, 0, 0);
    *(uint4*)(p + i) = z;
}

// ---------- K2: fused q (1x1 conv + BN) and v (1x1 conv + bias) as one GEMM ----------
// q rows -> qF{hi,lo}[b][ntile 256][s 2][g 4][lm 16][j 8]  (frag-linear, elem Q[n][d])
// v rows -> vF[b][ks 128][ct 16][g 4][lm 16][j 8] bf16     (elem V[n][c])
__global__ __launch_bounds__(256) void pam_qv_gemm(
    const float* __restrict__ x, const float* __restrict__ wq, const float* __restrict__ wv,
    const float* __restrict__ bv, const float* __restrict__ affQ,
    unsigned short* __restrict__ qFhi, unsigned short* __restrict__ qFlo,
    unsigned short* __restrict__ vF) {
    __shared__ float As[64][17];
    __shared__ __align__(16) float Bs[16][64];
    int t = threadIdx.x;
    int b = blockIdx.z, row0 = blockIdx.y * 64, p0 = blockIdx.x * 64;
    int tc = t & 15, tr = t >> 4;
    float acc[4][4] = {};
    int ra = t >> 2, kk4 = (t & 3) * 4;
    int Ra = row0 + ra;
    const float* wrow = (Ra < 64) ? (wq + (size_t)Ra * 512) : (wv + (size_t)(Ra - 64) * 512);
    const float* xb = x + (size_t)b * 512 * 4096;
    int kb_ = t >> 4, pb4 = (t & 15) * 4;
    for (int k0 = 0; k0 < 512; k0 += 16) {
        float4 a4 = *(const float4*)(wrow + k0 + kk4);
        As[ra][kk4 + 0] = a4.x; As[ra][kk4 + 1] = a4.y;
        As[ra][kk4 + 2] = a4.z; As[ra][kk4 + 3] = a4.w;
        *(float4*)&Bs[kb_][pb4] = *(const float4*)(xb + (size_t)(k0 + kb_) * 4096 + p0 + pb4);
        __syncthreads();
        #pragma unroll
        for (int kk = 0; kk < 16; ++kk) {
            float a[4], bb[4];
            #pragma unroll
            for (int i = 0; i < 4; i++) a[i] = As[tr * 4 + i][kk];
            #pragma unroll
            for (int j = 0; j < 4; j++) bb[j] = Bs[kk][tc * 4 + j];
            #pragma unroll
            for (int i = 0; i < 4; i++)
                #pragma unroll
                for (int j = 0; j < 4; j++) acc[i][j] = fmaf(a[i], bb[j], acc[i][j]);
        }
        __syncthreads();
    }
    #pragma unroll
    for (int i = 0; i < 4; i++) {
        int R = row0 + tr * 4 + i;
        if (R < 64) {
            float sc = affQ[R], sh = affQ[64 + R];
            int s_ = R >> 5, gF = (R >> 3) & 3, jF = R & 7;
            #pragma unroll
            for (int j = 0; j < 4; j++) {
                int p = p0 + tc * 4 + j;
                float val = fmaf(acc[i][j], sc, sh);
                unsigned short hi, lo;
                split_bf16(val, hi, lo);
                size_t idx = (size_t)(b * 256 + (p >> 4)) * 1024 + s_ * 512 + gF * 128 + (p & 15) * 8 + jF;
                qFhi[idx] = hi; qFlo[idx] = lo;
            }
        } else {
            int c = R - 64;
            float bb = bv[c];
            int pb = p0 + tc * 4;
            ushort4 u;
            u.x = (unsigned short)f_to_bf16(acc[i][0] + bb);
            u.y = (unsigned short)f_to_bf16(acc[i][1] + bb);
            u.z = (unsigned short)f_to_bf16(acc[i][2] + bb);
            u.w = (unsigned short)f_to_bf16(acc[i][3] + bb);
            size_t idx = (size_t)(b * 128 + (pb >> 5)) * 8192 + (c >> 4) * 512 +
                         ((pb >> 3) & 3) * 128 + (c & 15) * 8 + (pb & 7);
            *(ushort4*)(vF + idx) = u;
        }
    }
}

// ---------- K3: k-conv as tap-decomposed MFMA GEMM ----------
// output kF{hi,lo}[b][mt 64][s 2][g 4][lm 16][j 8]  (elem K[m][d])
__global__ __launch_bounds__(256) void pam_kconv_mfma(
    const unsigned short* __restrict__ xTphi, const unsigned short* __restrict__ xTplo,
    const unsigned short* __restrict__ wkThi, const unsigned short* __restrict__ wkTlo,
    const float* __restrict__ affK,
    unsigned short* __restrict__ kFhi, unsigned short* __restrict__ kFlo) {
    int t = threadIdx.x;
    int hk = blockIdx.x, b = blockIdx.y;
    int wv = t >> 6, lane = t & 63, g = lane >> 4, lm = lane & 15;
    int goff = g * 8;
    f32x4 acc0 = (f32x4){0.f, 0.f, 0.f, 0.f};
    f32x4 acc1 = (f32x4){0.f, 0.f, 0.f, 0.f};
    #pragma unroll
    for (int r = 0; r < 3; r++) {
        size_t arow = ((size_t)(b * 65 + 2 * hk + r)) * 65 * 512;
        #pragma unroll
        for (int s = 0; s < 3; s++) {
            size_t aoff = arow + (size_t)(2 * lm + s) * 512 + goff;   // pixel wk=lm
            const unsigned short* pa0h = xTphi + aoff;
            const unsigned short* pa0l = xTplo + aoff;
            size_t boff = ((size_t)((r * 3 + s) * 64 + wv * 16 + lm)) * 512 + goff;
            const unsigned short* pb_h = wkThi + boff;
            const unsigned short* pb_l = wkTlo + boff;
            #pragma unroll 4
            for (int c0 = 0; c0 < 512; c0 += 32) {
                bf16x8 a0h = *(const bf16x8*)(pa0h + c0);
                bf16x8 a1h = *(const bf16x8*)(pa0h + 32 * 512 + c0);   // pixel wk=lm+16
                bf16x8 a0l = *(const bf16x8*)(pa0l + c0);
                bf16x8 a1l = *(const bf16x8*)(pa0l + 32 * 512 + c0);
                bf16x8 bh  = *(const bf16x8*)(pb_h + c0);
                bf16x8 bl  = *(const bf16x8*)(pb_l + c0);
                acc0 = __builtin_amdgcn_mfma_f32_16x16x32_bf16(a0h, bh, acc0, 0, 0, 0);
                acc1 = __builtin_amdgcn_mfma_f32_16x16x32_bf16(a1h, bh, acc1, 0, 0, 0);
                acc0 = __builtin_amdgcn_mfma_f32_16x16x32_bf16(a0l, bh, acc0, 0, 0, 0);
                acc1 = __builtin_amdgcn_mfma_f32_16x16x32_bf16(a1l, bh, acc1, 0, 0, 0);
                acc0 = __builtin_amdgcn_mfma_f32_16x16x32_bf16(a0h, bl, acc0, 0, 0, 0);
                acc1 = __builtin_amdgcn_mfma_f32_16x16x32_bf16(a1h, bl, acc1, 0, 0, 0);
            }
        }
    }
    int d = wv * 16 + lm;
    float sc = affK[d], sh = affK[64 + d];
    int s_ = d >> 5, gF = (d >> 3) & 3, jF = d & 7;
    #pragma unroll
    for (int i = 0; i < 4; i++) {
        int m1 = hk * 32 + g * 4 + i;         // acc0 pixel
        int m2 = m1 + 16;                     // acc1 pixel
        float v0 = fmaf(acc0[i], sc, sh);
        float v1 = fmaf(acc1[i], sc, sh);
        unsigned short hh, ll;
        split_bf16(v0, hh, ll);
        size_t i1 = (size_t)(b * 64 + (m1 >> 4)) * 1024 + s_ * 512 + gF * 128 + (m1 & 15) * 8 + jF;
        kFhi[i1] = hh; kFlo[i1] = ll;
        split_bf16(v1, hh, ll);
        size_t i2 = (size_t)(b * 64 + (m2 >> 4)) * 1024 + s_ * 512 + gF * 128 + (m2 & 15) * 8 + jF;
        kFhi[i2] = hh; kFlo[i2] = ll;
    }
}

// ---------- K4: MFMA attention, frag-linear layouts, XCD-pinned grid ----------
__global__ __launch_bounds__(512, 2) void pam_attn(
    const unsigned short* __restrict__ qFhi, const unsigned short* __restrict__ qFlo,
    const unsigned short* __restrict__ kFhi, const unsigned short* __restrict__ kFlo,
    const unsigned short* __restrict__ vF, unsigned short* __restrict__ outsP) {
    __shared__ unsigned short Pl[65536];   // 128 KiB
    __shared__ float redM[8][16];
    __shared__ float redS[8][16];
    int t = threadIdx.x;
    int b = blockIdx.x, mt = blockIdx.y;
    int wid = t >> 6, lane = t & 63;
    int g = lane >> 4, lm = lane & 15;

    size_t kidx = (size_t)(b * 64 + mt) * 1024 + g * 128 + lm * 8;
    bf16x8 ah0 = *(const bf16x8*)(kFhi + kidx);
    bf16x8 ah1 = *(const bf16x8*)(kFhi + kidx + 512);
    bf16x8 al0 = *(const bf16x8*)(kFlo + kidx);
    bf16x8 al1 = *(const bf16x8*)(kFlo + kidx + 512);

    f32x4 ev[32];
    #pragma unroll
    for (int f = 0; f < 32; f++) ev[f] = (f32x4){0.f, 0.f, 0.f, 0.f};

    const unsigned short* qh = qFhi + (size_t)(b * 256 + wid * 32) * 1024 + g * 128 + lm * 8;
    const unsigned short* ql = qFlo + (size_t)(b * 256 + wid * 32) * 1024 + g * 128 + lm * 8;
    #pragma unroll
    for (int f = 0; f < 32; f++) {
        const unsigned short* qhp = qh + (size_t)f * 1024;
        const unsigned short* qlp = ql + (size_t)f * 1024;
        bf16x8 bh0 = *(const bf16x8*)(qhp);
        bf16x8 bh1 = *(const bf16x8*)(qhp + 512);
        bf16x8 bl0 = *(const bf16x8*)(qlp);
        bf16x8 bl1 = *(const bf16x8*)(qlp + 512);
        f32x4 e = ev[f];
        e = __builtin_amdgcn_mfma_f32_16x16x32_bf16(ah0, bh0, e, 0, 0, 0);
        e = __builtin_amdgcn_mfma_f32_16x16x32_bf16(ah1, bh1, e, 0, 0, 0);
        e = __builtin_amdgcn_mfma_f32_16x16x32_bf16(ah0, bl0, e, 0, 0, 0);
        e = __builtin_amdgcn_mfma_f32_16x16x32_bf16(ah1, bl1, e, 0, 0, 0);
        e = __builtin_amdgcn_mfma_f32_16x16x32_bf16(al0, bh0, e, 0, 0, 0);
        e = __builtin_amdgcn_mfma_f32_16x16x32_bf16(al1, bh1, e, 0, 0, 0);
        ev[f] = e;
    }

    float rmax[4];
    #pragma unroll
    for (int i = 0; i < 4; i++) {
        float m_ = ev[0][i];
        #pragma unroll
        for (int f = 1; f < 32; f++) m_ = fmaxf(m_, ev[f][i]);
        #pragma unroll
        for (int off = 1; off < 16; off <<= 1) m_ = fmaxf(m_, __shfl_xor(m_, off));
        rmax[i] = m_;
    }
    if (lm == 0) {
        #pragma unroll
        for (int i = 0; i < 4; i++) redM[wid][g * 4 + i] = rmax[i];
    }
    __syncthreads();
    #pragma unroll
    for (int i = 0; i < 4; i++) {
        float m_ = redM[0][g * 4 + i];
        #pragma unroll
        for (int ww = 1; ww < 8; ww++) m_ = fmaxf(m_, redM[ww][g * 4 + i]);
        rmax[i] = m_;
    }

    float rsum[4] = {0.f, 0.f, 0.f, 0.f};
    #pragma unroll
    for (int f = 0; f < 32; f++) {
        int ks = wid * 16 + (f >> 1);
        int gF = (f & 1) * 2 + (lm >> 3);
        int jF = lm & 7;
        #pragma unroll
        for (int i = 0; i < 4; i++) {
            float p = __expf(ev[f][i] - rmax[i]);
            uint32_t u = f_to_bf16(p);
            rsum[i] += bf16hi_to_f(u << 16);
            Pl[((ks * 4 + gF) * 16 + (g * 4 + i)) * 8 + jF] = (unsigned short)u;
        }
    }
    #pragma unroll
    for (int i = 0; i < 4; i++) {
        float s_ = rsum[i];
        #pragma unroll
        for (int off = 1; off < 16; off <<= 1) s_ += __shfl_xor(s_, off);
        rsum[i] = s_;
    }
    if (lm == 0) {
        #pragma unroll
        for (int i = 0; i < 4; i++) redS[wid][g * 4 + i] = rsum[i];
    }
    __syncthreads();
    float sinv[4];
    #pragma unroll
    for (int i = 0; i < 4; i++) {
        float s_ = 0.f;
        #pragma unroll
        for (int ww = 0; ww < 8; ww++) s_ += redS[ww][g * 4 + i];
        sinv[i] = 1.f / s_;
    }

    f32x4 o0 = (f32x4){0.f, 0.f, 0.f, 0.f};
    f32x4 o1 = (f32x4){0.f, 0.f, 0.f, 0.f};
    const unsigned short* vb = vF + (size_t)b * 1048576 + (wid * 2) * 512 + g * 128 + lm * 8;
    #pragma unroll 4
    for (int ks = 0; ks < 128; ks++) {
        bf16x8 pa = *(const bf16x8*)(Pl + ((ks * 4 + g) * 16 + lm) * 8);
        bf16x8 b0 = *(const bf16x8*)(vb + (size_t)ks * 8192);
        bf16x8 b1 = *(const bf16x8*)(vb + (size_t)ks * 8192 + 512);
        o0 = __builtin_amdgcn_mfma_f32_16x16x32_bf16(pa, b0, o0, 0, 0, 0);
        o1 = __builtin_amdgcn_mfma_f32_16x16x32_bf16(pa, b1, o1, 0, 0, 0);
    }

    int c0 = wid * 32;
    #pragma unroll
    for (int i = 0; i < 4; i++) {
        int m = mt * 16 + g * 4 + i;          // pixel index
        int hk2 = m >> 5, wk2 = m & 31;
        unsigned short* op = outsP + (((size_t)(b * 33 + hk2)) * 33 + wk2) * 256;
        op[c0 + lm]      = (unsigned short)f_to_bf16(o0[i] * sinv[i]);
        op[c0 + 16 + lm] = (unsigned short)f_to_bf16(o1[i] * sinv[i]);
    }
}

// ---------- K5: transpose-conv as balanced row-pair MFMA, frag-linear bf16 weights ----------
template<int LROW, int KH, int KW>
__device__ __forceinline__ void deconv_tap(
    const unsigned short* __restrict__ wdF,
    const char* lb, int ct0, int lane, int lm, f32x4 (&acc)[2][2][2]) {
    constexpr int wop = (KW == 1) ? 0 : 1;
    constexpr int dw = (KW == 0) ? 1 : 0;
    constexpr int tap = KH * 3 + KW;
    int g = lane >> 4;
    int p0 = LROW * 33 + lm + dw;
    int p1 = p0 + 16;
    uint32_t s0 = ((uint32_t)(p0 & 7)) << 4;
    uint32_t s1 = ((uint32_t)(p1 & 7)) << 4;
    uint32_t b0a = (uint32_t)p0 * 512 + (uint32_t)g * 16;
    uint32_t b1a = (uint32_t)p1 * 512 + (uint32_t)g * 16;
    const unsigned short* a0p = wdF + ((size_t)(tap * 32 + ct0) * 8) * 512 + lane * 8;
    const unsigned short* a1p = a0p + 8 * 512;     // ct0+1
    #pragma unroll
    for (int cs = 0; cs < 8; cs++) {
        bf16x8 bv0 = *(const bf16x8*)(lb + ((b0a + (uint32_t)cs * 64) ^ s0));
        bf16x8 bv1 = *(const bf16x8*)(lb + ((b1a + (uint32_t)cs * 64) ^ s1));
        bf16x8 a0 = *(const bf16x8*)(a0p + cs * 512);
        bf16x8 a1 = *(const bf16x8*)(a1p + cs * 512);
        acc[wop][0][0] = __builtin_amdgcn_mfma_f32_16x16x32_bf16(a0, bv0, acc[wop][0][0], 0, 0, 0);
        acc[wop][0][1] = __builtin_amdgcn_mfma_f32_16x16x32_bf16(a0, bv1, acc[wop][0][1], 0, 0, 0);
        acc[wop][1][0] = __builtin_amdgcn_mfma_f32_16x16x32_bf16(a1, bv0, acc[wop][1][0], 0, 0, 0);
        acc[wop][1][1] = __builtin_amdgcn_mfma_f32_16x16x32_bf16(a1, bv1, acc[wop][1][1], 0, 0, 0);
    }
}

__device__ __forceinline__ void deconv_epi(
    const f32x4 (&acc)[2][2][2], const float* __restrict__ affD,
    const float* __restrict__ x, float* __restrict__ out,
    int b, int ho, int co0, int lm, int g) {
    #pragma unroll
    for (int mf = 0; mf < 2; mf++) {
        #pragma unroll
        for (int i = 0; i < 4; i++) {
            int co = co0 + mf * 16 + g * 4 + i;
            float sc = affD[co], sh = affD[512 + co];
            const float* xr = x + (((size_t)b * 512 + co) * 64 + ho) * 64;
            float* orow = out + (((size_t)b * 512 + co) * 64 + ho) * 64;
            #pragma unroll
            for (int nf = 0; nf < 2; nf++) {
                int wp = nf * 16 + lm;
                float2 xv = *(const float2*)(xr + 2 * wp);
                float2 st;
                st.x = fmaxf(fmaf(acc[0][mf][nf][i], sc, sh), 0.f) + xv.x;
                st.y = fmaxf(fmaf(acc[1][mf][nf][i], sc, sh), 0.f) + xv.y;
                *(float2*)(orow + 2 * wp) = st;
            }
        }
    }
}

__global__ __launch_bounds__(1024, 4) void pam_deconv_mfma(
    const unsigned short* __restrict__ outsP,
    const unsigned short* __restrict__ wdF,
    const float* __restrict__ affD, const float* __restrict__ x, float* __restrict__ out) {
    __shared__ unsigned short Pb[16896];   // 2 rows x 33 px x 256 ci
    int t = threadIdx.x;
    int h0 = blockIdx.x, b = blockIdx.y;
    const unsigned short* src = outsP + ((size_t)(b * 33 + h0) * 33) * 256;
    for (int idx = t; idx < 2112; idx += 1024) {
        uint4 v = *(const uint4*)(src + (size_t)idx * 8);
        uint32_t byte = (uint32_t)idx * 16;
        byte ^= ((byte >> 9) & 7) << 4;
        *(uint4*)((char*)Pb + byte) = v;
    }
    __syncthreads();

    int wid = t >> 6, lane = t & 63, g = lane >> 4, lm = lane & 15;
    int ct0 = wid * 2, co0 = wid * 32;
    const char* lb = (const char*)Pb;

    {   // even output row ho = 2*h0 : kh=1, B row h0 (LDS row 0)
        f32x4 acc[2][2][2];
        #pragma unroll
        for (int a = 0; a < 2; a++)
            #pragma unroll
            for (int m = 0; m < 2; m++)
                #pragma unroll
                for (int n = 0; n < 2; n++) acc[a][m][n] = (f32x4){0.f, 0.f, 0.f, 0.f};
        deconv_tap<0, 1, 0>(wdF, lb, ct0, lane, lm, acc);
        deconv_tap<0, 1, 1>(wdF, lb, ct0, lane, lm, acc);
        deconv_tap<0, 1, 2>(wdF, lb, ct0, lane, lm, acc);
        deconv_epi(acc, affD, x, out, b, 2 * h0, co0, lm, g);
    }
    {   // odd output row ho = 2*h0+1 : kh=2 B row h0, kh=0 B row h0+1
        f32x4 acc[2][2][2];
        #pragma unroll
        for (int a = 0; a < 2; a++)
            #pragma unroll
            for (int m = 0; m < 2; m++)
                #pragma unroll
                for (int n = 0; n < 2; n++) acc[a][m][n] = (f32x4){0.f, 0.f, 0.f, 0.f};
        deconv_tap<0, 2, 0>(wdF, lb, ct0, lane, lm, acc);
        deconv_tap<0, 2, 1>(wdF, lb, ct0, lane, lm, acc);
        deconv_tap<0, 2, 2>(wdF, lb, ct0, lane, lm, acc);
        deconv_tap<1, 0, 0>(wdF, lb, ct0, lane, lm, acc);
        deconv_tap<1, 0, 1>(wdF, lb, ct0, lane, lm, acc);
        deconv_tap<1, 0, 2>(wdF, lb, ct0, lane, lm, acc);
        deconv_epi(acc, affD, x, out, b, 2 * h0 + 1, co0, lm, g);
    }
}

// ---------- launcher ----------
extern "C" void kernel_launch(void* const* d_in, const int* in_sizes, int n_in,
                              void* d_out, int out_size, void* d_ws, size_t ws_size,
                              hipStream_t stream) {
    const float* x   = (const float*)d_in[0];
    const float* w_q = (const float*)d_in[1];
    const float* b_q = (const float*)d_in[2];
    const float* qs  = (const float*)d_in[3];
    const float* qb  = (const float*)d_in[4];
    const float* qm  = (const float*)d_in[5];
    const float* qv  = (const float*)d_in[6];
    const float* w_k = (const float*)d_in[7];
    const float* b_k = (const float*)d_in[8];
    const float* ks  = (const float*)d_in[9];
    const float* kb  = (const float*)d_in[10];
    const float* km  = (const float*)d_in[11];
    const float* kv  = (const float*)d_in[12];
    const float* w_v = (const float*)d_in[13];
    const float* b_v = (const float*)d_in[14];
    const float* w_d = (const float*)d_in[15];
    const float* ds  = (const float*)d_in[16];
    const float* db  = (const float*)d_in[17];
    const float* dm  = (const float*)d_in[18];
    const float* dv  = (const float*)d_in[19];
    float* out = (float*)d_out;

    char* wsb = (char*)d_ws;
    unsigned short* qFhi  = (unsigned short*)(wsb);               //  4,194,304
    unsigned short* qFlo  = (unsigned short*)(wsb + 4194304);     //  4,194,304
    unsigned short* vF    = (unsigned short*)(wsb + 8388608);     // 16,777,216
    unsigned short* kFhi  = (unsigned short*)(wsb + 25165824);    //  1,048,576
    unsigned short* kFlo  = (unsigned short*)(wsb + 26214400);    //  1,048,576
    unsigned short* wkThi = (unsigned short*)(wsb + 27262976);    //    589,824
    unsigned short* wkTlo = (unsigned short*)(wsb + 27852800);    //    589,824
    float*          affQ  = (float*)(wsb + 28442624);             //        512
    float*          affK  = (float*)(wsb + 28443136);             //        512
    float*          affD  = (float*)(wsb + 28443648);             //      4,096
    // X region: xTp{hi,lo} live [pam_xt .. pam_kconv_mfma]; then reused:
    unsigned short* xTphi = (unsigned short*)(wsb + 28447744);    // 34,611,200
    unsigned short* xTplo = (unsigned short*)(wsb + 63058944);    // 34,611,200 -> end 97,670,144
    unsigned short* outsP = (unsigned short*)(wsb + 28447744);    //  4,460,544 (alias)
    unsigned short* wdF   = (unsigned short*)(wsb + 32908288);    //  2,359,296 (alias)

    hipLaunchKernelGGL(pam_aff_kernel, dim3(1), dim3(640), 0, stream,
                       b_q, qs, qb, qm, qv, b_k, ks, kb, km, kv, ds, db, dm, dv,
                       affQ, affK, affD);
    hipLaunchKernelGGL(pam_wkt, dim3(1152), dim3(256), 0, stream, w_k, wkThi, wkTlo);
    hipLaunchKernelGGL(pam_xt, dim3(65, 8), dim3(256), 0, stream, x, xTphi, xTplo);
    hipLaunchKernelGGL(pam_qv_gemm, dim3(64, 5, 8), dim3(256), 0, stream,
                       x, w_q, w_v, b_v, affQ, qFhi, qFlo, vF);
    hipLaunchKernelGGL(pam_kconv_mfma, dim3(32, 8), dim3(256), 0, stream,
                       xTphi, xTplo, wkThi, wkTlo, affK, kFhi, kFlo);
    // xTp dead from here; aliased region reused for outsP / wdF.
    hipLaunchKernelGGL(pam_wdtb, dim3(4608), dim3(256), 0, stream, w_d, wdF);
    hipLaunchKernelGGL(pam_zeroP, dim3(1089), dim3(256), 0, stream, outsP);
    hipLaunchKernelGGL(pam_attn, dim3(8, 64), dim3(512), 0, stream,
                       qFhi, qFlo, kFhi, kFlo, vF, outsP);
    hipLaunchKernelGGL(pam_deconv_mfma, dim3(32, 8), dim3(1024), 0, stream,
                       outsP, wdF, affD, x, out);
}

// Round 8
// 399.854 us; speedup vs baseline: 4.6738x; 1.1612x over previous
//
#include <hip/hip_runtime.h>
#include <hip/hip_bf16.h>
#include <cstdint>

#define BN_EPS 1e-5f

typedef short bf16x8 __attribute__((ext_vector_type(8)));
typedef float f32x4 __attribute__((ext_vector_type(4)));

// ---------- helpers ----------
__device__ __forceinline__ float bf16hi_to_f(uint32_t hi) {
    union { uint32_t u; float f; } c; c.u = hi; return c.f;
}
__device__ __forceinline__ uint32_t f_to_bf16(float f) {
    union { float f; uint32_t u; } c; c.f = f;
    uint32_t r = c.u + 0x7fffu + ((c.u >> 16) & 1u);  // RNE
    return r >> 16;
}
__device__ __forceinline__ void split_bf16(float v, unsigned short& hi, unsigned short& lo) {
    uint32_t h = f_to_bf16(v);
    float fh = bf16hi_to_f(h << 16);
    uint32_t l = f_to_bf16(v - fh);
    hi = (unsigned short)h; lo = (unsigned short)l;
}

// ---------- K0: BN affine precompute ----------
__global__ void pam_aff_kernel(const float* bq, const float* qs, const float* qb, const float* qm, const float* qv,
                               const float* bk, const float* ks, const float* kb, const float* km, const float* kv,
                               const float* ds, const float* db, const float* dm, const float* dv,
                               float* affQ, float* affK, float* affD) {
    int t = threadIdx.x;
    if (t < 64) {
        float inv = qs[t] * rsqrtf(qv[t] + BN_EPS);
        affQ[t] = inv; affQ[64 + t] = bq[t] * inv + qb[t] - qm[t] * inv;
    } else if (t < 128) {
        int i = t - 64;
        float inv = ks[i] * rsqrtf(kv[i] + BN_EPS);
        affK[i] = inv; affK[64 + i] = bk[i] * inv + kb[i] - km[i] * inv;
    } else {
        int i = t - 128;
        if (i < 512) {
            float inv = ds[i] * rsqrtf(dv[i] + BN_EPS);
            affD[i] = inv; affD[512 + i] = db[i] - dm[i] * inv;
        }
    }
}

// ---------- K1: w_d (256,512,3,3) -> frag-linear bf16 wdF[tap][ct 32][cs 8][lane 64][j 8] ----------
__global__ void pam_wdtb(const float* __restrict__ wd, unsigned short* __restrict__ wdF) {
    int o = blockIdx.x * 256 + threadIdx.x;       // < 9*512*256 = 1,179,648
    int ci = o & 255; int co = (o >> 8) & 511; int tap = o >> 17;
    float v = wd[(size_t)ci * 4608 + co * 9 + tap];
    int ct = co >> 4, lmr = co & 15, cs = ci >> 5, g = (ci >> 3) & 3, j = ci & 7;
    size_t idx = (((size_t)(tap * 32 + ct) * 8 + cs) * 512) + g * 128 + lmr * 8 + j;
    wdF[idx] = (unsigned short)f_to_bf16(v);
}

// ---------- K1b: transpose+split w_k (64,512,3,3) -> wkT{hi,lo}[k9][d][c] ----------
__global__ void pam_wkt(const float* __restrict__ wk,
                        unsigned short* __restrict__ wkThi, unsigned short* __restrict__ wkTlo) {
    int o = blockIdx.x * 256 + threadIdx.x;       // < 9*64*512 = 294912
    int c = o & 511; int d = (o >> 9) & 63; int kk = o >> 15;
    float v = wk[((size_t)d * 512 + c) * 9 + kk];
    unsigned short h, l;
    split_bf16(v, h, l);
    wkThi[o] = h; wkTlo[o] = l;
}

// ---------- K1e: w_q (scaled) + w_v -> frag-linear hi/lo wqvF[ct 20][cs 16][lane 64][j 8] ----------
// rows 0..63 = q (weight pre-scaled by BN scale), rows 64..319 = v
__global__ void pam_wqv(const float* __restrict__ wq, const float* __restrict__ wv,
                        const float* __restrict__ affQ,
                        unsigned short* __restrict__ wqvFhi, unsigned short* __restrict__ wqvFlo) {
    int o = blockIdx.x * 256 + threadIdx.x;   // < 320*512 = 163840
    int c = o & 511, R = o >> 9;
    float v = (R < 64) ? wq[(size_t)R * 512 + c] * affQ[R] : wv[(size_t)(R - 64) * 512 + c];
    unsigned short h, l;
    split_bf16(v, h, l);
    int ct = R >> 4, lmr = R & 15, cs = c >> 5, g = (c >> 3) & 3, j = c & 7;
    size_t idx = (((size_t)(ct * 16 + cs)) * 64 + g * 16 + lmr) * 8 + j;
    wqvFhi[idx] = h; wqvFlo[idx] = l;
}

// ---------- K1c: x -> xTp{hi,lo}[b][65][65][512]  (pixel-major, c-contig, -1 pad) ----------
__global__ __launch_bounds__(256) void pam_xt(const float* __restrict__ x,
                                              unsigned short* __restrict__ xTphi,
                                              unsigned short* __restrict__ xTplo) {
    int t = threadIdx.x;
    int ri = blockIdx.x;       // 0..64 ; input row hi = ri-1
    int b = blockIdx.y;
    size_t rowbase = ((size_t)b * 65 + ri) * 65 * 512;
    uint4 z = make_uint4(0, 0, 0, 0);
    if (ri == 0) {
        for (int idx = t; idx < 65 * 512 / 8; idx += 256) {
            *(uint4*)(xTphi + rowbase + (size_t)idx * 8) = z;
            *(uint4*)(xTplo + rowbase + (size_t)idx * 8) = z;
        }
        return;
    }
    if (t < 64) {
        *(uint4*)(xTphi + rowbase + (size_t)t * 8) = z;
        *(uint4*)(xTplo + rowbase + (size_t)t * 8) = z;
    }
    int hi = ri - 1;
    int wi = t & 63;
    const float* xb = x + (size_t)b * 512 * 4096 + (size_t)hi * 64 + wi;
    for (int it = 0; it < 16; ++it) {
        int cg = (t >> 6) + it * 4;     // 0..63
        int c0 = cg * 8;
        unsigned short h[8], l[8];
        #pragma unroll
        for (int j = 0; j < 8; j++) {
            float v = xb[(size_t)(c0 + j) * 4096];
            split_bf16(v, h[j], l[j]);
        }
        size_t dst = rowbase + (size_t)(wi + 1) * 512 + c0;
        uint4 ph = make_uint4((uint32_t)h[0] | ((uint32_t)h[1] << 16),
                              (uint32_t)h[2] | ((uint32_t)h[3] << 16),
                              (uint32_t)h[4] | ((uint32_t)h[5] << 16),
                              (uint32_t)h[6] | ((uint32_t)h[7] << 16));
        uint4 pl = make_uint4((uint32_t)l[0] | ((uint32_t)l[1] << 16),
                              (uint32_t)l[2] | ((uint32_t)l[3] << 16),
                              (uint32_t)l[4] | ((uint32_t)l[5] << 16),
                              (uint32_t)l[6] | ((uint32_t)l[7] << 16));
        *(uint4*)(xTphi + dst) = ph;
        *(uint4*)(xTplo + dst) = pl;
    }
}

// ---------- K1d: zero-fill outsP pad entries ----------
__global__ void pam_zeroP(unsigned short* __restrict__ p) {
    size_t i = ((size_t)blockIdx.x * 256 + threadIdx.x) * 8;   // total 2,230,272 ushorts
    uint4 z = make_uint4(0, 0, 0, 0);
    *(uint4*)(p + i) = z;
}

// ---------- K2: fused q+v 1x1 conv as MFMA GEMM (3-term hi/lo) ----------
// block = (image row h, b), 256 thr = 4 waves; wave -> 5 row-tiles (80 of 320 rows), 4 px-tiles.
// A = wqvF (pre-scaled weights), B = xTp row h. Epilogue: +shift -> qF{hi,lo} / vF frag-linear.
__global__ __launch_bounds__(256) void pam_qv_mfma(
    const unsigned short* __restrict__ xTphi, const unsigned short* __restrict__ xTplo,
    const unsigned short* __restrict__ wqvFhi, const unsigned short* __restrict__ wqvFlo,
    const float* __restrict__ affQ, const float* __restrict__ bv,
    unsigned short* __restrict__ qFhi, unsigned short* __restrict__ qFlo,
    unsigned short* __restrict__ vF) {
    int t = threadIdx.x;
    int h = blockIdx.x, b = blockIdx.y;
    int wv_ = t >> 6, lane = t & 63, g = lane >> 4, lm = lane & 15;
    int ct0 = wv_ * 5;

    f32x4 acc[5][4];
    #pragma unroll
    for (int m = 0; m < 5; m++)
        #pragma unroll
        for (int n = 0; n < 4; n++) acc[m][n] = (f32x4){0.f, 0.f, 0.f, 0.f};

    const unsigned short* xbh = xTphi + (((size_t)(b * 65) + h + 1) * 65 + 1) * 512 + (size_t)lm * 512 + g * 8;
    const unsigned short* xbl = xTplo + (((size_t)(b * 65) + h + 1) * 65 + 1) * 512 + (size_t)lm * 512 + g * 8;
    const unsigned short* wh = wqvFhi + (size_t)lane * 8;
    const unsigned short* wl = wqvFlo + (size_t)lane * 8;

    #pragma unroll 2
    for (int cs = 0; cs < 16; cs++) {
        int coff = cs * 32;
        bf16x8 bh[4], bl[4];
        #pragma unroll
        for (int nt = 0; nt < 4; nt++) {
            bh[nt] = *(const bf16x8*)(xbh + (size_t)nt * 16 * 512 + coff);
            bl[nt] = *(const bf16x8*)(xbl + (size_t)nt * 16 * 512 + coff);
        }
        bf16x8 ah[5], al[5];
        #pragma unroll
        for (int m = 0; m < 5; m++) {
            size_t aoff = (size_t)((ct0 + m) * 16 + cs) * 512;
            ah[m] = *(const bf16x8*)(wh + aoff);
            al[m] = *(const bf16x8*)(wl + aoff);
        }
        #pragma unroll
        for (int m = 0; m < 5; m++)
            #pragma unroll
            for (int n = 0; n < 4; n++) {
                acc[m][n] = __builtin_amdgcn_mfma_f32_16x16x32_bf16(ah[m], bh[n], acc[m][n], 0, 0, 0);
                acc[m][n] = __builtin_amdgcn_mfma_f32_16x16x32_bf16(ah[m], bl[n], acc[m][n], 0, 0, 0);
                acc[m][n] = __builtin_amdgcn_mfma_f32_16x16x32_bf16(al[m], bh[n], acc[m][n], 0, 0, 0);
            }
    }

    #pragma unroll
    for (int m = 0; m < 5; m++) {
        #pragma unroll
        for (int i = 0; i < 4; i++) {
            int R = (ct0 + m) * 16 + g * 4 + i;
            float shift = (R < 64) ? affQ[64 + R] : bv[R - 64];
            if (R < 64) {
                int s_ = R >> 5, gF = (R >> 3) & 3, jF = R & 7;
                #pragma unroll
                for (int nt = 0; nt < 4; nt++) {
                    int p = h * 64 + nt * 16 + lm;
                    float val = acc[m][nt][i] + shift;
                    unsigned short hh, ll;
                    split_bf16(val, hh, ll);
                    size_t idx = (size_t)(b * 256 + (p >> 4)) * 1024 + s_ * 512 + gF * 128 + (p & 15) * 8 + jF;
                    qFhi[idx] = hh; qFlo[idx] = ll;
                }
            } else {
                int c = R - 64;
                #pragma unroll
                for (int nt = 0; nt < 4; nt++) {
                    int p = h * 64 + nt * 16 + lm;
                    float val = acc[m][nt][i] + shift;
                    size_t idx = (size_t)(b * 128 + (p >> 5)) * 8192 + (c >> 4) * 512 +
                                 ((p >> 3) & 3) * 128 + (c & 15) * 8 + (p & 7);
                    vF[idx] = (unsigned short)f_to_bf16(val);
                }
            }
        }
    }
}

// ---------- K3: k-conv as tap-decomposed MFMA GEMM ----------
// output kF{hi,lo}[b][mt 64][s 2][g 4][lm 16][j 8]  (elem K[m][d])
__global__ __launch_bounds__(256) void pam_kconv_mfma(
    const unsigned short* __restrict__ xTphi, const unsigned short* __restrict__ xTplo,
    const unsigned short* __restrict__ wkThi, const unsigned short* __restrict__ wkTlo,
    const float* __restrict__ affK,
    unsigned short* __restrict__ kFhi, unsigned short* __restrict__ kFlo) {
    int t = threadIdx.x;
    int hk = blockIdx.x, b = blockIdx.y;
    int wv = t >> 6, lane = t & 63, g = lane >> 4, lm = lane & 15;
    int goff = g * 8;
    f32x4 acc0 = (f32x4){0.f, 0.f, 0.f, 0.f};
    f32x4 acc1 = (f32x4){0.f, 0.f, 0.f, 0.f};
    #pragma unroll
    for (int r = 0; r < 3; r++) {
        size_t arow = ((size_t)(b * 65 + 2 * hk + r)) * 65 * 512;
        #pragma unroll
        for (int s = 0; s < 3; s++) {
            size_t aoff = arow + (size_t)(2 * lm + s) * 512 + goff;   // pixel wk=lm
            const unsigned short* pa0h = xTphi + aoff;
            const unsigned short* pa0l = xTplo + aoff;
            size_t boff = ((size_t)((r * 3 + s) * 64 + wv * 16 + lm)) * 512 + goff;
            const unsigned short* pb_h = wkThi + boff;
            const unsigned short* pb_l = wkTlo + boff;
            #pragma unroll 4
            for (int c0 = 0; c0 < 512; c0 += 32) {
                bf16x8 a0h = *(const bf16x8*)(pa0h + c0);
                bf16x8 a1h = *(const bf16x8*)(pa0h + 32 * 512 + c0);   // pixel wk=lm+16
                bf16x8 a0l = *(const bf16x8*)(pa0l + c0);
                bf16x8 a1l = *(const bf16x8*)(pa0l + 32 * 512 + c0);
                bf16x8 bh  = *(const bf16x8*)(pb_h + c0);
                bf16x8 bl  = *(const bf16x8*)(pb_l + c0);
                acc0 = __builtin_amdgcn_mfma_f32_16x16x32_bf16(a0h, bh, acc0, 0, 0, 0);
                acc1 = __builtin_amdgcn_mfma_f32_16x16x32_bf16(a1h, bh, acc1, 0, 0, 0);
                acc0 = __builtin_amdgcn_mfma_f32_16x16x32_bf16(a0l, bh, acc0, 0, 0, 0);
                acc1 = __builtin_amdgcn_mfma_f32_16x16x32_bf16(a1l, bh, acc1, 0, 0, 0);
                acc0 = __builtin_amdgcn_mfma_f32_16x16x32_bf16(a0h, bl, acc0, 0, 0, 0);
                acc1 = __builtin_amdgcn_mfma_f32_16x16x32_bf16(a1h, bl, acc1, 0, 0, 0);
            }
        }
    }
    int d = wv * 16 + lm;
    float sc = affK[d], sh = affK[64 + d];
    int s_ = d >> 5, gF = (d >> 3) & 3, jF = d & 7;
    #pragma unroll
    for (int i = 0; i < 4; i++) {
        int m1 = hk * 32 + g * 4 + i;         // acc0 pixel
        int m2 = m1 + 16;                     // acc1 pixel
        float v0 = fmaf(acc0[i], sc, sh);
        float v1 = fmaf(acc1[i], sc, sh);
        unsigned short hh, ll;
        split_bf16(v0, hh, ll);
        size_t i1 = (size_t)(b * 64 + (m1 >> 4)) * 1024 + s_ * 512 + gF * 128 + (m1 & 15) * 8 + jF;
        kFhi[i1] = hh; kFlo[i1] = ll;
        split_bf16(v1, hh, ll);
        size_t i2 = (size_t)(b * 64 + (m2 >> 4)) * 1024 + s_ * 512 + gF * 128 + (m2 & 15) * 8 + jF;
        kFhi[i2] = hh; kFlo[i2] = ll;
    }
}

// ---------- K4: MFMA attention, frag-linear layouts, XCD-pinned grid ----------
__global__ __launch_bounds__(512, 2) void pam_attn(
    const unsigned short* __restrict__ qFhi, const unsigned short* __restrict__ qFlo,
    const unsigned short* __restrict__ kFhi, const unsigned short* __restrict__ kFlo,
    const unsigned short* __restrict__ vF, unsigned short* __restrict__ outsP) {
    __shared__ unsigned short Pl[65536];   // 128 KiB
    __shared__ float redM[8][16];
    __shared__ float redS[8][16];
    int t = threadIdx.x;
    int b = blockIdx.x, mt = blockIdx.y;
    int wid = t >> 6, lane = t & 63;
    int g = lane >> 4, lm = lane & 15;

    size_t kidx = (size_t)(b * 64 + mt) * 1024 + g * 128 + lm * 8;
    bf16x8 ah0 = *(const bf16x8*)(kFhi + kidx);
    bf16x8 ah1 = *(const bf16x8*)(kFhi + kidx + 512);
    bf16x8 al0 = *(const bf16x8*)(kFlo + kidx);
    bf16x8 al1 = *(const bf16x8*)(kFlo + kidx + 512);

    f32x4 ev[32];
    #pragma unroll
    for (int f = 0; f < 32; f++) ev[f] = (f32x4){0.f, 0.f, 0.f, 0.f};

    const unsigned short* qh = qFhi + (size_t)(b * 256 + wid * 32) * 1024 + g * 128 + lm * 8;
    const unsigned short* ql = qFlo + (size_t)(b * 256 + wid * 32) * 1024 + g * 128 + lm * 8;
    #pragma unroll
    for (int f = 0; f < 32; f++) {
        const unsigned short* qhp = qh + (size_t)f * 1024;
        const unsigned short* qlp = ql + (size_t)f * 1024;
        bf16x8 bh0 = *(const bf16x8*)(qhp);
        bf16x8 bh1 = *(const bf16x8*)(qhp + 512);
        bf16x8 bl0 = *(const bf16x8*)(qlp);
        bf16x8 bl1 = *(const bf16x8*)(qlp + 512);
        f32x4 e = ev[f];
        e = __builtin_amdgcn_mfma_f32_16x16x32_bf16(ah0, bh0, e, 0, 0, 0);
        e = __builtin_amdgcn_mfma_f32_16x16x32_bf16(ah1, bh1, e, 0, 0, 0);
        e = __builtin_amdgcn_mfma_f32_16x16x32_bf16(ah0, bl0, e, 0, 0, 0);
        e = __builtin_amdgcn_mfma_f32_16x16x32_bf16(ah1, bl1, e, 0, 0, 0);
        e = __builtin_amdgcn_mfma_f32_16x16x32_bf16(al0, bh0, e, 0, 0, 0);
        e = __builtin_amdgcn_mfma_f32_16x16x32_bf16(al1, bh1, e, 0, 0, 0);
        ev[f] = e;
    }

    float rmax[4];
    #pragma unroll
    for (int i = 0; i < 4; i++) {
        float m_ = ev[0][i];
        #pragma unroll
        for (int f = 1; f < 32; f++) m_ = fmaxf(m_, ev[f][i]);
        #pragma unroll
        for (int off = 1; off < 16; off <<= 1) m_ = fmaxf(m_, __shfl_xor(m_, off));
        rmax[i] = m_;
    }
    if (lm == 0) {
        #pragma unroll
        for (int i = 0; i < 4; i++) redM[wid][g * 4 + i] = rmax[i];
    }
    __syncthreads();
    #pragma unroll
    for (int i = 0; i < 4; i++) {
        float m_ = redM[0][g * 4 + i];
        #pragma unroll
        for (int ww = 1; ww < 8; ww++) m_ = fmaxf(m_, redM[ww][g * 4 + i]);
        rmax[i] = m_;
    }

    float rsum[4] = {0.f, 0.f, 0.f, 0.f};
    #pragma unroll
    for (int f = 0; f < 32; f++) {
        int ks = wid * 16 + (f >> 1);
        int gF = (f & 1) * 2 + (lm >> 3);
        int jF = lm & 7;
        #pragma unroll
        for (int i = 0; i < 4; i++) {
            float p = __expf(ev[f][i] - rmax[i]);
            uint32_t u = f_to_bf16(p);
            rsum[i] += bf16hi_to_f(u << 16);
            Pl[((ks * 4 + gF) * 16 + (g * 4 + i)) * 8 + jF] = (unsigned short)u;
        }
    }
    #pragma unroll
    for (int i = 0; i < 4; i++) {
        float s_ = rsum[i];
        #pragma unroll
        for (int off = 1; off < 16; off <<= 1) s_ += __shfl_xor(s_, off);
        rsum[i] = s_;
    }
    if (lm == 0) {
        #pragma unroll
        for (int i = 0; i < 4; i++) redS[wid][g * 4 + i] = rsum[i];
    }
    __syncthreads();
    float sinv[4];
    #pragma unroll
    for (int i = 0; i < 4; i++) {
        float s_ = 0.f;
        #pragma unroll
        for (int ww = 0; ww < 8; ww++) s_ += redS[ww][g * 4 + i];
        sinv[i] = 1.f / s_;
    }

    f32x4 o0 = (f32x4){0.f, 0.f, 0.f, 0.f};
    f32x4 o1 = (f32x4){0.f, 0.f, 0.f, 0.f};
    const unsigned short* vb = vF + (size_t)b * 1048576 + (wid * 2) * 512 + g * 128 + lm * 8;
    #pragma unroll 4
    for (int ks = 0; ks < 128; ks++) {
        bf16x8 pa = *(const bf16x8*)(Pl + ((ks * 4 + g) * 16 + lm) * 8);
        bf16x8 b0 = *(const bf16x8*)(vb + (size_t)ks * 8192);
        bf16x8 b1 = *(const bf16x8*)(vb + (size_t)ks * 8192 + 512);
        o0 = __builtin_amdgcn_mfma_f32_16x16x32_bf16(pa, b0, o0, 0, 0, 0);
        o1 = __builtin_amdgcn_mfma_f32_16x16x32_bf16(pa, b1, o1, 0, 0, 0);
    }

    int c0 = wid * 32;
    #pragma unroll
    for (int i = 0; i < 4; i++) {
        int m = mt * 16 + g * 4 + i;          // pixel index
        int hk2 = m >> 5, wk2 = m & 31;
        unsigned short* op = outsP + (((size_t)(b * 33 + hk2)) * 33 + wk2) * 256;
        op[c0 + lm]      = (unsigned short)f_to_bf16(o0[i] * sinv[i]);
        op[c0 + 16 + lm] = (unsigned short)f_to_bf16(o1[i] * sinv[i]);
    }
}

// ---------- K5: transpose-conv as balanced row-pair MFMA, frag-linear bf16 weights ----------
template<int LROW, int KH, int KW>
__device__ __forceinline__ void deconv_tap(
    const unsigned short* __restrict__ wdF,
    const char* lb, int ct0, int lane, int lm, f32x4 (&acc)[2][2][2]) {
    constexpr int wop = (KW == 1) ? 0 : 1;
    constexpr int dw = (KW == 0) ? 1 : 0;
    constexpr int tap = KH * 3 + KW;
    int g = lane >> 4;
    int p0 = LROW * 33 + lm + dw;
    int p1 = p0 + 16;
    uint32_t s0 = ((uint32_t)(p0 & 7)) << 4;
    uint32_t s1 = ((uint32_t)(p1 & 7)) << 4;
    uint32_t b0a = (uint32_t)p0 * 512 + (uint32_t)g * 16;
    uint32_t b1a = (uint32_t)p1 * 512 + (uint32_t)g * 16;
    const unsigned short* a0p = wdF + ((size_t)(tap * 32 + ct0) * 8) * 512 + lane * 8;
    const unsigned short* a1p = a0p + 8 * 512;     // ct0+1
    #pragma unroll
    for (int cs = 0; cs < 8; cs++) {
        bf16x8 bv0 = *(const bf16x8*)(lb + ((b0a + (uint32_t)cs * 64) ^ s0));
        bf16x8 bv1 = *(const bf16x8*)(lb + ((b1a + (uint32_t)cs * 64) ^ s1));
        bf16x8 a0 = *(const bf16x8*)(a0p + cs * 512);
        bf16x8 a1 = *(const bf16x8*)(a1p + cs * 512);
        acc[wop][0][0] = __builtin_amdgcn_mfma_f32_16x16x32_bf16(a0, bv0, acc[wop][0][0], 0, 0, 0);
        acc[wop][0][1] = __builtin_amdgcn_mfma_f32_16x16x32_bf16(a0, bv1, acc[wop][0][1], 0, 0, 0);
        acc[wop][1][0] = __builtin_amdgcn_mfma_f32_16x16x32_bf16(a1, bv0, acc[wop][1][0], 0, 0, 0);
        acc[wop][1][1] = __builtin_amdgcn_mfma_f32_16x16x32_bf16(a1, bv1, acc[wop][1][1], 0, 0, 0);
    }
}

__device__ __forceinline__ void deconv_epi(
    const f32x4 (&acc)[2][2][2], const float* __restrict__ affD,
    const float* __restrict__ x, float* __restrict__ out,
    int b, int ho, int co0, int lm, int g) {
    #pragma unroll
    for (int mf = 0; mf < 2; mf++) {
        #pragma unroll
        for (int i = 0; i < 4; i++) {
            int co = co0 + mf * 16 + g * 4 + i;
            float sc = affD[co], sh = affD[512 + co];
            const float* xr = x + (((size_t)b * 512 + co) * 64 + ho) * 64;
            float* orow = out + (((size_t)b * 512 + co) * 64 + ho) * 64;
            #pragma unroll
            for (int nf = 0; nf < 2; nf++) {
                int wp = nf * 16 + lm;
                float2 xv = *(const float2*)(xr + 2 * wp);
                float2 st;
                st.x = fmaxf(fmaf(acc[0][mf][nf][i], sc, sh), 0.f) + xv.x;
                st.y = fmaxf(fmaf(acc[1][mf][nf][i], sc, sh), 0.f) + xv.y;
                *(float2*)(orow + 2 * wp) = st;
            }
        }
    }
}

__global__ __launch_bounds__(1024, 4) void pam_deconv_mfma(
    const unsigned short* __restrict__ outsP,
    const unsigned short* __restrict__ wdF,
    const float* __restrict__ affD, const float* __restrict__ x, float* __restrict__ out) {
    __shared__ unsigned short Pb[16896];   // 2 rows x 33 px x 256 ci
    int t = threadIdx.x;
    int h0 = blockIdx.x, b = blockIdx.y;
    const unsigned short* src = outsP + ((size_t)(b * 33 + h0) * 33) * 256;
    for (int idx = t; idx < 2112; idx += 1024) {
        uint4 v = *(const uint4*)(src + (size_t)idx * 8);
        uint32_t byte = (uint32_t)idx * 16;
        byte ^= ((byte >> 9) & 7) << 4;
        *(uint4*)((char*)Pb + byte) = v;
    }
    __syncthreads();

    int wid = t >> 6, lane = t & 63, g = lane >> 4, lm = lane & 15;
    int ct0 = wid * 2, co0 = wid * 32;
    const char* lb = (const char*)Pb;

    {   // even output row ho = 2*h0 : kh=1, B row h0 (LDS row 0)
        f32x4 acc[2][2][2];
        #pragma unroll
        for (int a = 0; a < 2; a++)
            #pragma unroll
            for (int m = 0; m < 2; m++)
                #pragma unroll
                for (int n = 0; n < 2; n++) acc[a][m][n] = (f32x4){0.f, 0.f, 0.f, 0.f};
        deconv_tap<0, 1, 0>(wdF, lb, ct0, lane, lm, acc);
        deconv_tap<0, 1, 1>(wdF, lb, ct0, lane, lm, acc);
        deconv_tap<0, 1, 2>(wdF, lb, ct0, lane, lm, acc);
        deconv_epi(acc, affD, x, out, b, 2 * h0, co0, lm, g);
    }
    {   // odd output row ho = 2*h0+1 : kh=2 B row h0, kh=0 B row h0+1
        f32x4 acc[2][2][2];
        #pragma unroll
        for (int a = 0; a < 2; a++)
            #pragma unroll
            for (int m = 0; m < 2; m++)
                #pragma unroll
                for (int n = 0; n < 2; n++) acc[a][m][n] = (f32x4){0.f, 0.f, 0.f, 0.f};
        deconv_tap<0, 2, 0>(wdF, lb, ct0, lane, lm, acc);
        deconv_tap<0, 2, 1>(wdF, lb, ct0, lane, lm, acc);
        deconv_tap<0, 2, 2>(wdF, lb, ct0, lane, lm, acc);
        deconv_tap<1, 0, 0>(wdF, lb, ct0, lane, lm, acc);
        deconv_tap<1, 0, 1>(wdF, lb, ct0, lane, lm, acc);
        deconv_tap<1, 0, 2>(wdF, lb, ct0, lane, lm, acc);
        deconv_epi(acc, affD, x, out, b, 2 * h0 + 1, co0, lm, g);
    }
}

// ---------- launcher ----------
extern "C" void kernel_launch(void* const* d_in, const int* in_sizes, int n_in,
                              void* d_out, int out_size, void* d_ws, size_t ws_size,
                              hipStream_t stream) {
    const float* x   = (const float*)d_in[0];
    const float* w_q = (const float*)d_in[1];
    const float* b_q = (const float*)d_in[2];
    const float* qs  = (const float*)d_in[3];
    const float* qb  = (const float*)d_in[4];
    const float* qm  = (const float*)d_in[5];
    const float* qv  = (const float*)d_in[6];
    const float* w_k = (const float*)d_in[7];
    const float* b_k = (const float*)d_in[8];
    const float* ks  = (const float*)d_in[9];
    const float* kb  = (const float*)d_in[10];
    const float* km  = (const float*)d_in[11];
    const float* kv  = (const float*)d_in[12];
    const float* w_v = (const float*)d_in[13];
    const float* b_v = (const float*)d_in[14];
    const float* w_d = (const float*)d_in[15];
    const float* ds  = (const float*)d_in[16];
    const float* db  = (const float*)d_in[17];
    const float* dm  = (const float*)d_in[18];
    const float* dv  = (const float*)d_in[19];
    float* out = (float*)d_out;

    char* wsb = (char*)d_ws;
    unsigned short* qFhi  = (unsigned short*)(wsb);               //  4,194,304
    unsigned short* qFlo  = (unsigned short*)(wsb + 4194304);     //  4,194,304
    unsigned short* vF    = (unsigned short*)(wsb + 8388608);     // 16,777,216
    unsigned short* kFhi  = (unsigned short*)(wsb + 25165824);    //  1,048,576
    unsigned short* kFlo  = (unsigned short*)(wsb + 26214400);    //  1,048,576
    unsigned short* wkThi = (unsigned short*)(wsb + 27262976);    //    589,824
    unsigned short* wkTlo = (unsigned short*)(wsb + 27852800);    //    589,824
    float*          affQ  = (float*)(wsb + 28442624);             //        512
    float*          affK  = (float*)(wsb + 28443136);             //        512
    float*          affD  = (float*)(wsb + 28443648);             //      4,096
    // wqvF aliases the kF region (dead until kconv runs, which is after qv).
    unsigned short* wqvFhi = (unsigned short*)(wsb + 25165824);   //    327,680 (alias kFhi)
    unsigned short* wqvFlo = (unsigned short*)(wsb + 25493504);   //    327,680 (alias kFhi)
    // X region: xTp{hi,lo} live [pam_xt .. pam_kconv_mfma]; then reused:
    unsigned short* xTphi = (unsigned short*)(wsb + 28447744);    // 34,611,200
    unsigned short* xTplo = (unsigned short*)(wsb + 63058944);    // 34,611,200 -> end 97,670,144
    unsigned short* outsP = (unsigned short*)(wsb + 28447744);    //  4,460,544 (alias)
    unsigned short* wdF   = (unsigned short*)(wsb + 32908288);    //  2,359,296 (alias)

    hipLaunchKernelGGL(pam_aff_kernel, dim3(1), dim3(640), 0, stream,
                       b_q, qs, qb, qm, qv, b_k, ks, kb, km, kv, ds, db, dm, dv,
                       affQ, affK, affD);
    hipLaunchKernelGGL(pam_wkt, dim3(1152), dim3(256), 0, stream, w_k, wkThi, wkTlo);
    hipLaunchKernelGGL(pam_wqv, dim3(640), dim3(256), 0, stream, w_q, w_v, affQ, wqvFhi, wqvFlo);
    hipLaunchKernelGGL(pam_xt, dim3(65, 8), dim3(256), 0, stream, x, xTphi, xTplo);
    hipLaunchKernelGGL(pam_qv_mfma, dim3(64, 8), dim3(256), 0, stream,
                       xTphi, xTplo, wqvFhi, wqvFlo, affQ, b_v, qFhi, qFlo, vF);
    hipLaunchKernelGGL(pam_kconv_mfma, dim3(32, 8), dim3(256), 0, stream,
                       xTphi, xTplo, wkThi, wkTlo, affK, kFhi, kFlo);
    // xTp dead from here; aliased region reused for outsP / wdF.
    hipLaunchKernelGGL(pam_wdtb, dim3(4608), dim3(256), 0, stream, w_d, wdF);
    hipLaunchKernelGGL(pam_zeroP, dim3(1089), dim3(256), 0, stream, outsP);
    hipLaunchKernelGGL(pam_attn, dim3(8, 64), dim3(512), 0, stream,
                       qFhi, qFlo, kFhi, kFlo, vF, outsP);
    hipLaunchKernelGGL(pam_deconv_mfma, dim3(32, 8), dim3(1024), 0, stream,
                       outsP, wdF, affD, x, out);
}

// Round 9
// 372.664 us; speedup vs baseline: 5.0148x; 1.0730x over previous
//
#include <hip/hip_runtime.h>
#include <hip/hip_bf16.h>
#include <cstdint>

#define BN_EPS 1e-5f

typedef short bf16x8 __attribute__((ext_vector_type(8)));
typedef float f32x4 __attribute__((ext_vector_type(4)));

// ---------- helpers ----------
__device__ __forceinline__ float bf16hi_to_f(uint32_t hi) {
    union { uint32_t u; float f; } c; c.u = hi; return c.f;
}
__device__ __forceinline__ uint32_t f_to_bf16(float f) {
    union { float f; uint32_t u; } c; c.f = f;
    uint32_t r = c.u + 0x7fffu + ((c.u >> 16) & 1u);  // RNE
    return r >> 16;
}
__device__ __forceinline__ void split_bf16(float v, unsigned short& hi, unsigned short& lo) {
    uint32_t h = f_to_bf16(v);
    float fh = bf16hi_to_f(h << 16);
    uint32_t l = f_to_bf16(v - fh);
    hi = (unsigned short)h; lo = (unsigned short)l;
}

// ---------- K0: BN affine precompute ----------
__global__ void pam_aff_kernel(const float* bq, const float* qs, const float* qb, const float* qm, const float* qv,
                               const float* bk, const float* ks, const float* kb, const float* km, const float* kv,
                               const float* ds, const float* db, const float* dm, const float* dv,
                               float* affQ, float* affK, float* affD) {
    int t = threadIdx.x;
    if (t < 64) {
        float inv = qs[t] * rsqrtf(qv[t] + BN_EPS);
        affQ[t] = inv; affQ[64 + t] = bq[t] * inv + qb[t] - qm[t] * inv;
    } else if (t < 128) {
        int i = t - 64;
        float inv = ks[i] * rsqrtf(kv[i] + BN_EPS);
        affK[i] = inv; affK[64 + i] = bk[i] * inv + kb[i] - km[i] * inv;
    } else {
        int i = t - 128;
        if (i < 512) {
            float inv = ds[i] * rsqrtf(dv[i] + BN_EPS);
            affD[i] = inv; affD[512 + i] = db[i] - dm[i] * inv;
        }
    }
}

// ---------- K1: w_d (256,512,3,3) -> frag-linear bf16 wdF[tap][ct 32][cs 8][lane 64][j 8] ----------
__global__ void pam_wdtb(const float* __restrict__ wd, unsigned short* __restrict__ wdF) {
    int o = blockIdx.x * 256 + threadIdx.x;       // < 9*512*256 = 1,179,648
    int ci = o & 255; int co = (o >> 8) & 511; int tap = o >> 17;
    float v = wd[(size_t)ci * 4608 + co * 9 + tap];
    int ct = co >> 4, lmr = co & 15, cs = ci >> 5, g = (ci >> 3) & 3, j = ci & 7;
    size_t idx = (((size_t)(tap * 32 + ct) * 8 + cs) * 512) + g * 128 + lmr * 8 + j;
    wdF[idx] = (unsigned short)f_to_bf16(v);
}

// ---------- K1b: w_k (64,512,3,3) -> frag-linear hi/lo wkF[tap 9][dt 4][cs 16][lane 64][j 8] ----------
// element: B-frag (d = dt*16+lm, c = cs*32+g*8+j), lane = g*16+lm
__global__ void pam_wkt(const float* __restrict__ wk,
                        unsigned short* __restrict__ wkFhi, unsigned short* __restrict__ wkFlo) {
    int o = blockIdx.x * 256 + threadIdx.x;       // < 9*64*512 = 294912
    int c = o & 511; int d = (o >> 9) & 63; int tap = o >> 15;
    float v = wk[((size_t)d * 512 + c) * 9 + tap];
    unsigned short h, l;
    split_bf16(v, h, l);
    int dt = d >> 4, lm = d & 15, cs = c >> 5, g = (c >> 3) & 3, j = c & 7;
    size_t idx = (((size_t)((tap * 4 + dt) * 16 + cs)) * 64 + g * 16 + lm) * 8 + j;
    wkFhi[idx] = h; wkFlo[idx] = l;
}

// ---------- K1e: w_q (scaled) + w_v -> frag-linear hi/lo wqvF[ct 20][cs 16][lane 64][j 8] ----------
__global__ void pam_wqv(const float* __restrict__ wq, const float* __restrict__ wv,
                        const float* __restrict__ affQ,
                        unsigned short* __restrict__ wqvFhi, unsigned short* __restrict__ wqvFlo) {
    int o = blockIdx.x * 256 + threadIdx.x;   // < 320*512 = 163840
    int c = o & 511, R = o >> 9;
    float v = (R < 64) ? wq[(size_t)R * 512 + c] * affQ[R] : wv[(size_t)(R - 64) * 512 + c];
    unsigned short h, l;
    split_bf16(v, h, l);
    int ct = R >> 4, lmr = R & 15, cs = c >> 5, g = (c >> 3) & 3, j = c & 7;
    size_t idx = (((size_t)(ct * 16 + cs)) * 64 + g * 16 + lmr) * 8 + j;
    wqvFhi[idx] = h; wqvFlo[idx] = l;
}

// ---------- K1c: x -> xTp{hi,lo}[b][65][65][512]  (pixel-major, c-contig, -1 pad) ----------
__global__ __launch_bounds__(256) void pam_xt(const float* __restrict__ x,
                                              unsigned short* __restrict__ xTphi,
                                              unsigned short* __restrict__ xTplo) {
    int t = threadIdx.x;
    int ri = blockIdx.x;       // 0..64 ; input row hi = ri-1
    int b = blockIdx.y;
    size_t rowbase = ((size_t)b * 65 + ri) * 65 * 512;
    uint4 z = make_uint4(0, 0, 0, 0);
    if (ri == 0) {
        for (int idx = t; idx < 65 * 512 / 8; idx += 256) {
            *(uint4*)(xTphi + rowbase + (size_t)idx * 8) = z;
            *(uint4*)(xTplo + rowbase + (size_t)idx * 8) = z;
        }
        return;
    }
    if (t < 64) {
        *(uint4*)(xTphi + rowbase + (size_t)t * 8) = z;
        *(uint4*)(xTplo + rowbase + (size_t)t * 8) = z;
    }
    int hi = ri - 1;
    int wi = t & 63;
    const float* xb = x + (size_t)b * 512 * 4096 + (size_t)hi * 64 + wi;
    for (int it = 0; it < 16; ++it) {
        int cg = (t >> 6) + it * 4;     // 0..63
        int c0 = cg * 8;
        unsigned short h[8], l[8];
        #pragma unroll
        for (int j = 0; j < 8; j++) {
            float v = xb[(size_t)(c0 + j) * 4096];
            split_bf16(v, h[j], l[j]);
        }
        size_t dst = rowbase + (size_t)(wi + 1) * 512 + c0;
        uint4 ph = make_uint4((uint32_t)h[0] | ((uint32_t)h[1] << 16),
                              (uint32_t)h[2] | ((uint32_t)h[3] << 16),
                              (uint32_t)h[4] | ((uint32_t)h[5] << 16),
                              (uint32_t)h[6] | ((uint32_t)h[7] << 16));
        uint4 pl = make_uint4((uint32_t)l[0] | ((uint32_t)l[1] << 16),
                              (uint32_t)l[2] | ((uint32_t)l[3] << 16),
                              (uint32_t)l[4] | ((uint32_t)l[5] << 16),
                              (uint32_t)l[6] | ((uint32_t)l[7] << 16));
        *(uint4*)(xTphi + dst) = ph;
        *(uint4*)(xTplo + dst) = pl;
    }
}

// ---------- K1d: zero-fill outsP pad entries ----------
__global__ void pam_zeroP(unsigned short* __restrict__ p) {
    size_t i = ((size_t)blockIdx.x * 256 + threadIdx.x) * 8;   // total 2,230,272 ushorts
    uint4 z = make_uint4(0, 0, 0, 0);
    *(uint4*)(p + i) = z;
}

// ---------- K2: fused q+v 1x1 conv as MFMA GEMM (3-term hi/lo) ----------
__global__ __launch_bounds__(256) void pam_qv_mfma(
    const unsigned short* __restrict__ xTphi, const unsigned short* __restrict__ xTplo,
    const unsigned short* __restrict__ wqvFhi, const unsigned short* __restrict__ wqvFlo,
    const float* __restrict__ affQ, const float* __restrict__ bv,
    unsigned short* __restrict__ qFhi, unsigned short* __restrict__ qFlo,
    unsigned short* __restrict__ vF) {
    int t = threadIdx.x;
    int h = blockIdx.x, b = blockIdx.y;
    int wv_ = t >> 6, lane = t & 63, g = lane >> 4, lm = lane & 15;
    int ct0 = wv_ * 5;

    f32x4 acc[5][4];
    #pragma unroll
    for (int m = 0; m < 5; m++)
        #pragma unroll
        for (int n = 0; n < 4; n++) acc[m][n] = (f32x4){0.f, 0.f, 0.f, 0.f};

    const unsigned short* xbh = xTphi + (((size_t)(b * 65) + h + 1) * 65 + 1) * 512 + (size_t)lm * 512 + g * 8;
    const unsigned short* xbl = xTplo + (((size_t)(b * 65) + h + 1) * 65 + 1) * 512 + (size_t)lm * 512 + g * 8;
    const unsigned short* wh = wqvFhi + (size_t)lane * 8;
    const unsigned short* wl = wqvFlo + (size_t)lane * 8;

    #pragma unroll 2
    for (int cs = 0; cs < 16; cs++) {
        int coff = cs * 32;
        bf16x8 bh[4], bl[4];
        #pragma unroll
        for (int nt = 0; nt < 4; nt++) {
            bh[nt] = *(const bf16x8*)(xbh + (size_t)nt * 16 * 512 + coff);
            bl[nt] = *(const bf16x8*)(xbl + (size_t)nt * 16 * 512 + coff);
        }
        bf16x8 ah[5], al[5];
        #pragma unroll
        for (int m = 0; m < 5; m++) {
            size_t aoff = (size_t)((ct0 + m) * 16 + cs) * 512;
            ah[m] = *(const bf16x8*)(wh + aoff);
            al[m] = *(const bf16x8*)(wl + aoff);
        }
        #pragma unroll
        for (int m = 0; m < 5; m++)
            #pragma unroll
            for (int n = 0; n < 4; n++) {
                acc[m][n] = __builtin_amdgcn_mfma_f32_16x16x32_bf16(ah[m], bh[n], acc[m][n], 0, 0, 0);
                acc[m][n] = __builtin_amdgcn_mfma_f32_16x16x32_bf16(ah[m], bl[n], acc[m][n], 0, 0, 0);
                acc[m][n] = __builtin_amdgcn_mfma_f32_16x16x32_bf16(al[m], bh[n], acc[m][n], 0, 0, 0);
            }
    }

    #pragma unroll
    for (int m = 0; m < 5; m++) {
        #pragma unroll
        for (int i = 0; i < 4; i++) {
            int R = (ct0 + m) * 16 + g * 4 + i;
            float shift = (R < 64) ? affQ[64 + R] : bv[R - 64];
            if (R < 64) {
                int s_ = R >> 5, gF = (R >> 3) & 3, jF = R & 7;
                #pragma unroll
                for (int nt = 0; nt < 4; nt++) {
                    int p = h * 64 + nt * 16 + lm;
                    float val = acc[m][nt][i] + shift;
                    unsigned short hh, ll;
                    split_bf16(val, hh, ll);
                    size_t idx = (size_t)(b * 256 + (p >> 4)) * 1024 + s_ * 512 + gF * 128 + (p & 15) * 8 + jF;
                    qFhi[idx] = hh; qFlo[idx] = ll;
                }
            } else {
                int c = R - 64;
                #pragma unroll
                for (int nt = 0; nt < 4; nt++) {
                    int p = h * 64 + nt * 16 + lm;
                    float val = acc[m][nt][i] + shift;
                    size_t idx = (size_t)(b * 128 + (p >> 5)) * 8192 + (c >> 4) * 512 +
                                 ((p >> 3) & 3) * 128 + (c & 15) * 8 + (p & 7);
                    vF[idx] = (unsigned short)f_to_bf16(val);
                }
            }
        }
    }
}

// ---------- K3: k-conv as tap-decomposed MFMA GEMM, 16 waves, 4-way c-split ----------
// block = (hk, b), 1024 thr = 16 waves: wid = cq*4 + dt (cq = c-quarter, dt = d-tile).
// Each wave: C[32 px][16 d] over K-quarter (9 taps x 128 c), 2 acc chains.
// Quarters 1-3 dump partials to LDS; quarter 0 reduces + epilogue.
__global__ __launch_bounds__(1024, 4) void pam_kconv_mfma(
    const unsigned short* __restrict__ xTphi, const unsigned short* __restrict__ xTplo,
    const unsigned short* __restrict__ wkFhi, const unsigned short* __restrict__ wkFlo,
    const float* __restrict__ affK,
    unsigned short* __restrict__ kFhi, unsigned short* __restrict__ kFlo) {
    __shared__ float red[3 * 4 * 64 * 8];   // 24 KiB
    int t = threadIdx.x;
    int hk = blockIdx.x, b = blockIdx.y;
    int wid = t >> 6, lane = t & 63, g = lane >> 4, lm = lane & 15;
    int dt = wid & 3, cq = wid >> 2;
    int goff = g * 8;
    f32x4 acc0 = (f32x4){0.f, 0.f, 0.f, 0.f};
    f32x4 acc1 = (f32x4){0.f, 0.f, 0.f, 0.f};
    #pragma unroll
    for (int r = 0; r < 3; r++) {
        size_t arow = ((size_t)(b * 65 + 2 * hk + r)) * 65 * 512;
        #pragma unroll
        for (int s = 0; s < 3; s++) {
            size_t aoff = arow + (size_t)(2 * lm + s) * 512 + goff;   // pixel wk=lm
            const unsigned short* pa0h = xTphi + aoff;
            const unsigned short* pa0l = xTplo + aoff;
            int tap = r * 3 + s;
            const unsigned short* pb_h = wkFhi + (((size_t)(tap * 4 + dt) * 16) * 64 + lane) * 8;
            const unsigned short* pb_l = wkFlo + (((size_t)(tap * 4 + dt) * 16) * 64 + lane) * 8;
            #pragma unroll
            for (int k = 0; k < 4; k++) {
                int c0 = cq * 128 + k * 32;
                bf16x8 a0h = *(const bf16x8*)(pa0h + c0);
                bf16x8 a1h = *(const bf16x8*)(pa0h + 32 * 512 + c0);   // pixel wk=lm+16
                bf16x8 a0l = *(const bf16x8*)(pa0l + c0);
                bf16x8 a1l = *(const bf16x8*)(pa0l + 32 * 512 + c0);
                bf16x8 bh  = *(const bf16x8*)(pb_h + (size_t)(c0 >> 5) * 512);
                bf16x8 bl  = *(const bf16x8*)(pb_l + (size_t)(c0 >> 5) * 512);
                acc0 = __builtin_amdgcn_mfma_f32_16x16x32_bf16(a0h, bh, acc0, 0, 0, 0);
                acc1 = __builtin_amdgcn_mfma_f32_16x16x32_bf16(a1h, bh, acc1, 0, 0, 0);
                acc0 = __builtin_amdgcn_mfma_f32_16x16x32_bf16(a0l, bh, acc0, 0, 0, 0);
                acc1 = __builtin_amdgcn_mfma_f32_16x16x32_bf16(a1l, bh, acc1, 0, 0, 0);
                acc0 = __builtin_amdgcn_mfma_f32_16x16x32_bf16(a0h, bl, acc0, 0, 0, 0);
                acc1 = __builtin_amdgcn_mfma_f32_16x16x32_bf16(a1h, bl, acc1, 0, 0, 0);
            }
        }
    }
    if (cq > 0) {
        float* dst = red + (((size_t)(cq - 1) * 4 + dt) * 64 + lane) * 8;
        *(f32x4*)dst = acc0;
        *(f32x4*)(dst + 4) = acc1;
    }
    __syncthreads();
    if (cq != 0) return;
    #pragma unroll
    for (int q = 0; q < 3; q++) {
        const float* src = red + (((size_t)q * 4 + dt) * 64 + lane) * 8;
        f32x4 p0 = *(const f32x4*)src;
        f32x4 p1 = *(const f32x4*)(src + 4);
        acc0 += p0; acc1 += p1;
    }
    int d = dt * 16 + lm;
    float sc = affK[d], sh = affK[64 + d];
    int s_ = d >> 5, gF = (d >> 3) & 3, jF = d & 7;
    #pragma unroll
    for (int i = 0; i < 4; i++) {
        int m1 = hk * 32 + g * 4 + i;         // acc0 pixel
        int m2 = m1 + 16;                     // acc1 pixel
        float v0 = fmaf(acc0[i], sc, sh);
        float v1 = fmaf(acc1[i], sc, sh);
        unsigned short hh, ll;
        split_bf16(v0, hh, ll);
        size_t i1 = (size_t)(b * 64 + (m1 >> 4)) * 1024 + s_ * 512 + gF * 128 + (m1 & 15) * 8 + jF;
        kFhi[i1] = hh; kFlo[i1] = ll;
        split_bf16(v1, hh, ll);
        size_t i2 = (size_t)(b * 64 + (m2 >> 4)) * 1024 + s_ * 512 + gF * 128 + (m2 & 15) * 8 + jF;
        kFhi[i2] = hh; kFlo[i2] = ll;
    }
}

// ---------- K4: MFMA attention, frag-linear layouts, XCD-pinned grid ----------
__global__ __launch_bounds__(512, 2) void pam_attn(
    const unsigned short* __restrict__ qFhi, const unsigned short* __restrict__ qFlo,
    const unsigned short* __restrict__ kFhi, const unsigned short* __restrict__ kFlo,
    const unsigned short* __restrict__ vF, unsigned short* __restrict__ outsP) {
    __shared__ unsigned short Pl[65536];   // 128 KiB
    __shared__ float redM[8][16];
    __shared__ float redS[8][16];
    int t = threadIdx.x;
    int b = blockIdx.x, mt = blockIdx.y;
    int wid = t >> 6, lane = t & 63;
    int g = lane >> 4, lm = lane & 15;

    size_t kidx = (size_t)(b * 64 + mt) * 1024 + g * 128 + lm * 8;
    bf16x8 ah0 = *(const bf16x8*)(kFhi + kidx);
    bf16x8 ah1 = *(const bf16x8*)(kFhi + kidx + 512);
    bf16x8 al0 = *(const bf16x8*)(kFlo + kidx);
    bf16x8 al1 = *(const bf16x8*)(kFlo + kidx + 512);

    f32x4 ev[32];
    #pragma unroll
    for (int f = 0; f < 32; f++) ev[f] = (f32x4){0.f, 0.f, 0.f, 0.f};

    const unsigned short* qh = qFhi + (size_t)(b * 256 + wid * 32) * 1024 + g * 128 + lm * 8;
    const unsigned short* ql = qFlo + (size_t)(b * 256 + wid * 32) * 1024 + g * 128 + lm * 8;
    #pragma unroll
    for (int f = 0; f < 32; f++) {
        const unsigned short* qhp = qh + (size_t)f * 1024;
        const unsigned short* qlp = ql + (size_t)f * 1024;
        bf16x8 bh0 = *(const bf16x8*)(qhp);
        bf16x8 bh1 = *(const bf16x8*)(qhp + 512);
        bf16x8 bl0 = *(const bf16x8*)(qlp);
        bf16x8 bl1 = *(const bf16x8*)(qlp + 512);
        f32x4 e = ev[f];
        e = __builtin_amdgcn_mfma_f32_16x16x32_bf16(ah0, bh0, e, 0, 0, 0);
        e = __builtin_amdgcn_mfma_f32_16x16x32_bf16(ah1, bh1, e, 0, 0, 0);
        e = __builtin_amdgcn_mfma_f32_16x16x32_bf16(ah0, bl0, e, 0, 0, 0);
        e = __builtin_amdgcn_mfma_f32_16x16x32_bf16(ah1, bl1, e, 0, 0, 0);
        e = __builtin_amdgcn_mfma_f32_16x16x32_bf16(al0, bh0, e, 0, 0, 0);
        e = __builtin_amdgcn_mfma_f32_16x16x32_bf16(al1, bh1, e, 0, 0, 0);
        ev[f] = e;
    }

    float rmax[4];
    #pragma unroll
    for (int i = 0; i < 4; i++) {
        float m_ = ev[0][i];
        #pragma unroll
        for (int f = 1; f < 32; f++) m_ = fmaxf(m_, ev[f][i]);
        #pragma unroll
        for (int off = 1; off < 16; off <<= 1) m_ = fmaxf(m_, __shfl_xor(m_, off));
        rmax[i] = m_;
    }
    if (lm == 0) {
        #pragma unroll
        for (int i = 0; i < 4; i++) redM[wid][g * 4 + i] = rmax[i];
    }
    __syncthreads();
    #pragma unroll
    for (int i = 0; i < 4; i++) {
        float m_ = redM[0][g * 4 + i];
        #pragma unroll
        for (int ww = 1; ww < 8; ww++) m_ = fmaxf(m_, redM[ww][g * 4 + i]);
        rmax[i] = m_;
    }

    float rsum[4] = {0.f, 0.f, 0.f, 0.f};
    #pragma unroll
    for (int f = 0; f < 32; f++) {
        int ks = wid * 16 + (f >> 1);
        int gF = (f & 1) * 2 + (lm >> 3);
        int jF = lm & 7;
        #pragma unroll
        for (int i = 0; i < 4; i++) {
            float p = __expf(ev[f][i] - rmax[i]);
            uint32_t u = f_to_bf16(p);
            rsum[i] += bf16hi_to_f(u << 16);
            Pl[((ks * 4 + gF) * 16 + (g * 4 + i)) * 8 + jF] = (unsigned short)u;
        }
    }
    #pragma unroll
    for (int i = 0; i < 4; i++) {
        float s_ = rsum[i];
        #pragma unroll
        for (int off = 1; off < 16; off <<= 1) s_ += __shfl_xor(s_, off);
        rsum[i] = s_;
    }
    if (lm == 0) {
        #pragma unroll
        for (int i = 0; i < 4; i++) redS[wid][g * 4 + i] = rsum[i];
    }
    __syncthreads();
    float sinv[4];
    #pragma unroll
    for (int i = 0; i < 4; i++) {
        float s_ = 0.f;
        #pragma unroll
        for (int ww = 0; ww < 8; ww++) s_ += redS[ww][g * 4 + i];
        sinv[i] = 1.f / s_;
    }

    f32x4 o0 = (f32x4){0.f, 0.f, 0.f, 0.f};
    f32x4 o1 = (f32x4){0.f, 0.f, 0.f, 0.f};
    const unsigned short* vb = vF + (size_t)b * 1048576 + (wid * 2) * 512 + g * 128 + lm * 8;
    #pragma unroll 4
    for (int ks = 0; ks < 128; ks++) {
        bf16x8 pa = *(const bf16x8*)(Pl + ((ks * 4 + g) * 16 + lm) * 8);
        bf16x8 b0 = *(const bf16x8*)(vb + (size_t)ks * 8192);
        bf16x8 b1 = *(const bf16x8*)(vb + (size_t)ks * 8192 + 512);
        o0 = __builtin_amdgcn_mfma_f32_16x16x32_bf16(pa, b0, o0, 0, 0, 0);
        o1 = __builtin_amdgcn_mfma_f32_16x16x32_bf16(pa, b1, o1, 0, 0, 0);
    }

    int c0 = wid * 32;
    #pragma unroll
    for (int i = 0; i < 4; i++) {
        int m = mt * 16 + g * 4 + i;          // pixel index
        int hk2 = m >> 5, wk2 = m & 31;
        unsigned short* op = outsP + (((size_t)(b * 33 + hk2)) * 33 + wk2) * 256;
        op[c0 + lm]      = (unsigned short)f_to_bf16(o0[i] * sinv[i]);
        op[c0 + 16 + lm] = (unsigned short)f_to_bf16(o1[i] * sinv[i]);
    }
}

// ---------- K5: transpose-conv as balanced row-pair MFMA, frag-linear bf16 weights ----------
template<int LROW, int KH, int KW>
__device__ __forceinline__ void deconv_tap(
    const unsigned short* __restrict__ wdF,
    const char* lb, int ct0, int lane, int lm, f32x4 (&acc)[2][2][2]) {
    constexpr int wop = (KW == 1) ? 0 : 1;
    constexpr int dw = (KW == 0) ? 1 : 0;
    constexpr int tap = KH * 3 + KW;
    int g = lane >> 4;
    int p0 = LROW * 33 + lm + dw;
    int p1 = p0 + 16;
    uint32_t s0 = ((uint32_t)(p0 & 7)) << 4;
    uint32_t s1 = ((uint32_t)(p1 & 7)) << 4;
    uint32_t b0a = (uint32_t)p0 * 512 + (uint32_t)g * 16;
    uint32_t b1a = (uint32_t)p1 * 512 + (uint32_t)g * 16;
    const unsigned short* a0p = wdF + ((size_t)(tap * 32 + ct0) * 8) * 512 + lane * 8;
    const unsigned short* a1p = a0p + 8 * 512;     // ct0+1
    #pragma unroll
    for (int cs = 0; cs < 8; cs++) {
        bf16x8 bv0 = *(const bf16x8*)(lb + ((b0a + (uint32_t)cs * 64) ^ s0));
        bf16x8 bv1 = *(const bf16x8*)(lb + ((b1a + (uint32_t)cs * 64) ^ s1));
        bf16x8 a0 = *(const bf16x8*)(a0p + cs * 512);
        bf16x8 a1 = *(const bf16x8*)(a1p + cs * 512);
        acc[wop][0][0] = __builtin_amdgcn_mfma_f32_16x16x32_bf16(a0, bv0, acc[wop][0][0], 0, 0, 0);
        acc[wop][0][1] = __builtin_amdgcn_mfma_f32_16x16x32_bf16(a0, bv1, acc[wop][0][1], 0, 0, 0);
        acc[wop][1][0] = __builtin_amdgcn_mfma_f32_16x16x32_bf16(a1, bv0, acc[wop][1][0], 0, 0, 0);
        acc[wop][1][1] = __builtin_amdgcn_mfma_f32_16x16x32_bf16(a1, bv1, acc[wop][1][1], 0, 0, 0);
    }
}

__device__ __forceinline__ void deconv_epi(
    const f32x4 (&acc)[2][2][2], const float* __restrict__ affD,
    const float* __restrict__ x, float* __restrict__ out,
    int b, int ho, int co0, int lm, int g) {
    #pragma unroll
    for (int mf = 0; mf < 2; mf++) {
        #pragma unroll
        for (int i = 0; i < 4; i++) {
            int co = co0 + mf * 16 + g * 4 + i;
            float sc = affD[co], sh = affD[512 + co];
            const float* xr = x + (((size_t)b * 512 + co) * 64 + ho) * 64;
            float* orow = out + (((size_t)b * 512 + co) * 64 + ho) * 64;
            #pragma unroll
            for (int nf = 0; nf < 2; nf++) {
                int wp = nf * 16 + lm;
                float2 xv = *(const float2*)(xr + 2 * wp);
                float2 st;
                st.x = fmaxf(fmaf(acc[0][mf][nf][i], sc, sh), 0.f) + xv.x;
                st.y = fmaxf(fmaf(acc[1][mf][nf][i], sc, sh), 0.f) + xv.y;
                *(float2*)(orow + 2 * wp) = st;
            }
        }
    }
}

__global__ __launch_bounds__(1024, 4) void pam_deconv_mfma(
    const unsigned short* __restrict__ outsP,
    const unsigned short* __restrict__ wdF,
    const float* __restrict__ affD, const float* __restrict__ x, float* __restrict__ out) {
    __shared__ unsigned short Pb[16896];   // 2 rows x 33 px x 256 ci
    int t = threadIdx.x;
    int h0 = blockIdx.x, b = blockIdx.y;
    const unsigned short* src = outsP + ((size_t)(b * 33 + h0) * 33) * 256;
    for (int idx = t; idx < 2112; idx += 1024) {
        uint4 v = *(const uint4*)(src + (size_t)idx * 8);
        uint32_t byte = (uint32_t)idx * 16;
        byte ^= ((byte >> 9) & 7) << 4;
        *(uint4*)((char*)Pb + byte) = v;
    }
    __syncthreads();

    int wid = t >> 6, lane = t & 63, g = lane >> 4, lm = lane & 15;
    int ct0 = wid * 2, co0 = wid * 32;
    const char* lb = (const char*)Pb;

    {   // even output row ho = 2*h0 : kh=1, B row h0 (LDS row 0)
        f32x4 acc[2][2][2];
        #pragma unroll
        for (int a = 0; a < 2; a++)
            #pragma unroll
            for (int m = 0; m < 2; m++)
                #pragma unroll
                for (int n = 0; n < 2; n++) acc[a][m][n] = (f32x4){0.f, 0.f, 0.f, 0.f};
        deconv_tap<0, 1, 0>(wdF, lb, ct0, lane, lm, acc);
        deconv_tap<0, 1, 1>(wdF, lb, ct0, lane, lm, acc);
        deconv_tap<0, 1, 2>(wdF, lb, ct0, lane, lm, acc);
        deconv_epi(acc, affD, x, out, b, 2 * h0, co0, lm, g);
    }
    {   // odd output row ho = 2*h0+1 : kh=2 B row h0, kh=0 B row h0+1
        f32x4 acc[2][2][2];
        #pragma unroll
        for (int a = 0; a < 2; a++)
            #pragma unroll
            for (int m = 0; m < 2; m++)
                #pragma unroll
                for (int n = 0; n < 2; n++) acc[a][m][n] = (f32x4){0.f, 0.f, 0.f, 0.f};
        deconv_tap<0, 2, 0>(wdF, lb, ct0, lane, lm, acc);
        deconv_tap<0, 2, 1>(wdF, lb, ct0, lane, lm, acc);
        deconv_tap<0, 2, 2>(wdF, lb, ct0, lane, lm, acc);
        deconv_tap<1, 0, 0>(wdF, lb, ct0, lane, lm, acc);
        deconv_tap<1, 0, 1>(wdF, lb, ct0, lane, lm, acc);
        deconv_tap<1, 0, 2>(wdF, lb, ct0, lane, lm, acc);
        deconv_epi(acc, affD, x, out, b, 2 * h0 + 1, co0, lm, g);
    }
}

// ---------- launcher ----------
extern "C" void kernel_launch(void* const* d_in, const int* in_sizes, int n_in,
                              void* d_out, int out_size, void* d_ws, size_t ws_size,
                              hipStream_t stream) {
    const float* x   = (const float*)d_in[0];
    const float* w_q = (const float*)d_in[1];
    const float* b_q = (const float*)d_in[2];
    const float* qs  = (const float*)d_in[3];
    const float* qb  = (const float*)d_in[4];
    const float* qm  = (const float*)d_in[5];
    const float* qv  = (const float*)d_in[6];
    const float* w_k = (const float*)d_in[7];
    const float* b_k = (const float*)d_in[8];
    const float* ks  = (const float*)d_in[9];
    const float* kb  = (const float*)d_in[10];
    const float* km  = (const float*)d_in[11];
    const float* kv  = (const float*)d_in[12];
    const float* w_v = (const float*)d_in[13];
    const float* b_v = (const float*)d_in[14];
    const float* w_d = (const float*)d_in[15];
    const float* ds  = (const float*)d_in[16];
    const float* db  = (const float*)d_in[17];
    const float* dm  = (const float*)d_in[18];
    const float* dv  = (const float*)d_in[19];
    float* out = (float*)d_out;

    char* wsb = (char*)d_ws;
    unsigned short* qFhi  = (unsigned short*)(wsb);               //  4,194,304
    unsigned short* qFlo  = (unsigned short*)(wsb + 4194304);     //  4,194,304
    unsigned short* vF    = (unsigned short*)(wsb + 8388608);     // 16,777,216
    unsigned short* kFhi  = (unsigned short*)(wsb + 25165824);    //  1,048,576
    unsigned short* kFlo  = (unsigned short*)(wsb + 26214400);    //  1,048,576
    unsigned short* wkFhi = (unsigned short*)(wsb + 27262976);    //    589,824
    unsigned short* wkFlo = (unsigned short*)(wsb + 27852800);    //    589,824
    float*          affQ  = (float*)(wsb + 28442624);             //        512
    float*          affK  = (float*)(wsb + 28443136);             //        512
    float*          affD  = (float*)(wsb + 28443648);             //      4,096
    // wqvF aliases the kF region (dead until kconv runs, which is after qv).
    unsigned short* wqvFhi = (unsigned short*)(wsb + 25165824);   //    327,680 (alias kFhi)
    unsigned short* wqvFlo = (unsigned short*)(wsb + 25493504);   //    327,680 (alias kFhi)
    // X region: xTp{hi,lo} live [pam_xt .. pam_kconv_mfma]; then reused:
    unsigned short* xTphi = (unsigned short*)(wsb + 28447744);    // 34,611,200
    unsigned short* xTplo = (unsigned short*)(wsb + 63058944);    // 34,611,200 -> end 97,670,144
    unsigned short* outsP = (unsigned short*)(wsb + 28447744);    //  4,460,544 (alias)
    unsigned short* wdF   = (unsigned short*)(wsb + 32908288);    //  2,359,296 (alias)

    hipLaunchKernelGGL(pam_aff_kernel, dim3(1), dim3(640), 0, stream,
                       b_q, qs, qb, qm, qv, b_k, ks, kb, km, kv, ds, db, dm, dv,
                       affQ, affK, affD);
    hipLaunchKernelGGL(pam_wkt, dim3(1152), dim3(256), 0, stream, w_k, wkFhi, wkFlo);
    hipLaunchKernelGGL(pam_wqv, dim3(640), dim3(256), 0, stream, w_q, w_v, affQ, wqvFhi, wqvFlo);
    hipLaunchKernelGGL(pam_xt, dim3(65, 8), dim3(256), 0, stream, x, xTphi, xTplo);
    hipLaunchKernelGGL(pam_qv_mfma, dim3(64, 8), dim3(256), 0, stream,
                       xTphi, xTplo, wqvFhi, wqvFlo, affQ, b_v, qFhi, qFlo, vF);
    hipLaunchKernelGGL(pam_kconv_mfma, dim3(32, 8), dim3(1024), 0, stream,
                       xTphi, xTplo, wkFhi, wkFlo, affK, kFhi, kFlo);
    // xTp dead from here; aliased region reused for outsP / wdF.
    hipLaunchKernelGGL(pam_wdtb, dim3(4608), dim3(256), 0, stream, w_d, wdF);
    hipLaunchKernelGGL(pam_zeroP, dim3(1089), dim3(256), 0, stream, outsP);
    hipLaunchKernelGGL(pam_attn, dim3(8, 64), dim3(512), 0, stream,
                       qFhi, qFlo, kFhi, kFlo, vF, outsP);
    hipLaunchKernelGGL(pam_deconv_mfma, dim3(32, 8), dim3(1024), 0, stream,
                       outsP, wdF, affD, x, out);
}

// Round 10
// 370.331 us; speedup vs baseline: 5.0464x; 1.0063x over previous
//
#include <hip/hip_runtime.h>
#include <hip/hip_bf16.h>
#include <cstdint>

#define BN_EPS 1e-5f

typedef short bf16x8 __attribute__((ext_vector_type(8)));
typedef float f32x4 __attribute__((ext_vector_type(4)));

// ---------- helpers ----------
__device__ __forceinline__ float bf16hi_to_f(uint32_t hi) {
    union { uint32_t u; float f; } c; c.u = hi; return c.f;
}
__device__ __forceinline__ uint32_t f_to_bf16(float f) {
    union { float f; uint32_t u; } c; c.f = f;
    uint32_t r = c.u + 0x7fffu + ((c.u >> 16) & 1u);  // RNE
    return r >> 16;
}
__device__ __forceinline__ void split_bf16(float v, unsigned short& hi, unsigned short& lo) {
    uint32_t h = f_to_bf16(v);
    float fh = bf16hi_to_f(h << 16);
    uint32_t l = f_to_bf16(v - fh);
    hi = (unsigned short)h; lo = (unsigned short)l;
}

// ---------- K0: BN affine precompute ----------
__global__ void pam_aff_kernel(const float* bq, const float* qs, const float* qb, const float* qm, const float* qv,
                               const float* bk, const float* ks, const float* kb, const float* km, const float* kv,
                               const float* ds, const float* db, const float* dm, const float* dv,
                               float* affQ, float* affK, float* affD) {
    int t = threadIdx.x;
    if (t < 64) {
        float inv = qs[t] * rsqrtf(qv[t] + BN_EPS);
        affQ[t] = inv; affQ[64 + t] = bq[t] * inv + qb[t] - qm[t] * inv;
    } else if (t < 128) {
        int i = t - 64;
        float inv = ks[i] * rsqrtf(kv[i] + BN_EPS);
        affK[i] = inv; affK[64 + i] = bk[i] * inv + kb[i] - km[i] * inv;
    } else {
        int i = t - 128;
        if (i < 512) {
            float inv = ds[i] * rsqrtf(dv[i] + BN_EPS);
            affD[i] = inv; affD[512 + i] = db[i] - dm[i] * inv;
        }
    }
}

// ---------- K1: w_d (256,512,3,3) -> frag-linear bf16 wdF[tap][ct 32][cs 8][lane 64][j 8] ----------
__global__ void pam_wdtb(const float* __restrict__ wd, unsigned short* __restrict__ wdF) {
    int o = blockIdx.x * 256 + threadIdx.x;       // < 9*512*256 = 1,179,648
    int ci = o & 255; int co = (o >> 8) & 511; int tap = o >> 17;
    float v = wd[(size_t)ci * 4608 + co * 9 + tap];
    int ct = co >> 4, lmr = co & 15, cs = ci >> 5, g = (ci >> 3) & 3, j = ci & 7;
    size_t idx = (((size_t)(tap * 32 + ct) * 8 + cs) * 512) + g * 128 + lmr * 8 + j;
    wdF[idx] = (unsigned short)f_to_bf16(v);
}

// ---------- K1b: w_k (64,512,3,3) -> frag-linear hi/lo wkF[tap 9][dt 4][cs 16][lane 64][j 8] ----------
__global__ void pam_wkt(const float* __restrict__ wk,
                        unsigned short* __restrict__ wkFhi, unsigned short* __restrict__ wkFlo) {
    int o = blockIdx.x * 256 + threadIdx.x;       // < 9*64*512 = 294912
    int c = o & 511; int d = (o >> 9) & 63; int tap = o >> 15;
    float v = wk[((size_t)d * 512 + c) * 9 + tap];
    unsigned short h, l;
    split_bf16(v, h, l);
    int dt = d >> 4, lm = d & 15, cs = c >> 5, g = (c >> 3) & 3, j = c & 7;
    size_t idx = (((size_t)((tap * 4 + dt) * 16 + cs)) * 64 + g * 16 + lm) * 8 + j;
    wkFhi[idx] = h; wkFlo[idx] = l;
}

// ---------- K1e: w_q (scaled) + w_v -> frag-linear hi/lo wqvF[ct 20][cs 16][lane 64][j 8] ----------
__global__ void pam_wqv(const float* __restrict__ wq, const float* __restrict__ wv,
                        const float* __restrict__ affQ,
                        unsigned short* __restrict__ wqvFhi, unsigned short* __restrict__ wqvFlo) {
    int o = blockIdx.x * 256 + threadIdx.x;   // < 320*512 = 163840
    int c = o & 511, R = o >> 9;
    float v = (R < 64) ? wq[(size_t)R * 512 + c] * affQ[R] : wv[(size_t)(R - 64) * 512 + c];
    unsigned short h, l;
    split_bf16(v, h, l);
    int ct = R >> 4, lmr = R & 15, cs = c >> 5, g = (c >> 3) & 3, j = c & 7;
    size_t idx = (((size_t)(ct * 16 + cs)) * 64 + g * 16 + lmr) * 8 + j;
    wqvFhi[idx] = h; wqvFlo[idx] = l;
}

// ---------- K1c: x -> xTp{hi,lo}[b][65][65][512]  (pixel-major, c-contig, -1 pad) ----------
__global__ __launch_bounds__(256) void pam_xt(const float* __restrict__ x,
                                              unsigned short* __restrict__ xTphi,
                                              unsigned short* __restrict__ xTplo) {
    int t = threadIdx.x;
    int ri = blockIdx.x;       // 0..64 ; input row hi = ri-1
    int b = blockIdx.y;
    size_t rowbase = ((size_t)b * 65 + ri) * 65 * 512;
    uint4 z = make_uint4(0, 0, 0, 0);
    if (ri == 0) {
        for (int idx = t; idx < 65 * 512 / 8; idx += 256) {
            *(uint4*)(xTphi + rowbase + (size_t)idx * 8) = z;
            *(uint4*)(xTplo + rowbase + (size_t)idx * 8) = z;
        }
        return;
    }
    if (t < 64) {
        *(uint4*)(xTphi + rowbase + (size_t)t * 8) = z;
        *(uint4*)(xTplo + rowbase + (size_t)t * 8) = z;
    }
    int hi = ri - 1;
    int wi = t & 63;
    const float* xb = x + (size_t)b * 512 * 4096 + (size_t)hi * 64 + wi;
    for (int it = 0; it < 16; ++it) {
        int cg = (t >> 6) + it * 4;     // 0..63
        int c0 = cg * 8;
        unsigned short h[8], l[8];
        #pragma unroll
        for (int j = 0; j < 8; j++) {
            float v = xb[(size_t)(c0 + j) * 4096];
            split_bf16(v, h[j], l[j]);
        }
        size_t dst = rowbase + (size_t)(wi + 1) * 512 + c0;
        uint4 ph = make_uint4((uint32_t)h[0] | ((uint32_t)h[1] << 16),
                              (uint32_t)h[2] | ((uint32_t)h[3] << 16),
                              (uint32_t)h[4] | ((uint32_t)h[5] << 16),
                              (uint32_t)h[6] | ((uint32_t)h[7] << 16));
        uint4 pl = make_uint4((uint32_t)l[0] | ((uint32_t)l[1] << 16),
                              (uint32_t)l[2] | ((uint32_t)l[3] << 16),
                              (uint32_t)l[4] | ((uint32_t)l[5] << 16),
                              (uint32_t)l[6] | ((uint32_t)l[7] << 16));
        *(uint4*)(xTphi + dst) = ph;
        *(uint4*)(xTplo + dst) = pl;
    }
}

// ---------- K1d: zero-fill outsP pad entries ----------
__global__ void pam_zeroP(unsigned short* __restrict__ p) {
    size_t i = ((size_t)blockIdx.x * 256 + threadIdx.x) * 8;   // total 2,230,272 ushorts
    uint4 z = make_uint4(0, 0, 0, 0);
    *(uint4*)(p + i) = z;
}

// ---------- K2: fused q+v 1x1 conv as MFMA GEMM (3-term hi/lo) ----------
__global__ __launch_bounds__(256) void pam_qv_mfma(
    const unsigned short* __restrict__ xTphi, const unsigned short* __restrict__ xTplo,
    const unsigned short* __restrict__ wqvFhi, const unsigned short* __restrict__ wqvFlo,
    const float* __restrict__ affQ, const float* __restrict__ bv,
    unsigned short* __restrict__ qFhi, unsigned short* __restrict__ qFlo,
    unsigned short* __restrict__ vF) {
    int t = threadIdx.x;
    int h = blockIdx.x, b = blockIdx.y;
    int wv_ = t >> 6, lane = t & 63, g = lane >> 4, lm = lane & 15;
    int ct0 = wv_ * 5;

    f32x4 acc[5][4];
    #pragma unroll
    for (int m = 0; m < 5; m++)
        #pragma unroll
        for (int n = 0; n < 4; n++) acc[m][n] = (f32x4){0.f, 0.f, 0.f, 0.f};

    const unsigned short* xbh = xTphi + (((size_t)(b * 65) + h + 1) * 65 + 1) * 512 + (size_t)lm * 512 + g * 8;
    const unsigned short* xbl = xTplo + (((size_t)(b * 65) + h + 1) * 65 + 1) * 512 + (size_t)lm * 512 + g * 8;
    const unsigned short* wh = wqvFhi + (size_t)lane * 8;
    const unsigned short* wl = wqvFlo + (size_t)lane * 8;

    #pragma unroll 2
    for (int cs = 0; cs < 16; cs++) {
        int coff = cs * 32;
        bf16x8 bh[4], bl[4];
        #pragma unroll
        for (int nt = 0; nt < 4; nt++) {
            bh[nt] = *(const bf16x8*)(xbh + (size_t)nt * 16 * 512 + coff);
            bl[nt] = *(const bf16x8*)(xbl + (size_t)nt * 16 * 512 + coff);
        }
        bf16x8 ah[5], al[5];
        #pragma unroll
        for (int m = 0; m < 5; m++) {
            size_t aoff = (size_t)((ct0 + m) * 16 + cs) * 512;
            ah[m] = *(const bf16x8*)(wh + aoff);
            al[m] = *(const bf16x8*)(wl + aoff);
        }
        #pragma unroll
        for (int m = 0; m < 5; m++)
            #pragma unroll
            for (int n = 0; n < 4; n++) {
                acc[m][n] = __builtin_amdgcn_mfma_f32_16x16x32_bf16(ah[m], bh[n], acc[m][n], 0, 0, 0);
                acc[m][n] = __builtin_amdgcn_mfma_f32_16x16x32_bf16(ah[m], bl[n], acc[m][n], 0, 0, 0);
                acc[m][n] = __builtin_amdgcn_mfma_f32_16x16x32_bf16(al[m], bh[n], acc[m][n], 0, 0, 0);
            }
    }

    #pragma unroll
    for (int m = 0; m < 5; m++) {
        #pragma unroll
        for (int i = 0; i < 4; i++) {
            int R = (ct0 + m) * 16 + g * 4 + i;
            float shift = (R < 64) ? affQ[64 + R] : bv[R - 64];
            if (R < 64) {
                int s_ = R >> 5, gF = (R >> 3) & 3, jF = R & 7;
                #pragma unroll
                for (int nt = 0; nt < 4; nt++) {
                    int p = h * 64 + nt * 16 + lm;
                    float val = acc[m][nt][i] + shift;
                    unsigned short hh, ll;
                    split_bf16(val, hh, ll);
                    size_t idx = (size_t)(b * 256 + (p >> 4)) * 1024 + s_ * 512 + gF * 128 + (p & 15) * 8 + jF;
                    qFhi[idx] = hh; qFlo[idx] = ll;
                }
            } else {
                int c = R - 64;
                #pragma unroll
                for (int nt = 0; nt < 4; nt++) {
                    int p = h * 64 + nt * 16 + lm;
                    float val = acc[m][nt][i] + shift;
                    size_t idx = (size_t)(b * 128 + (p >> 5)) * 8192 + (c >> 4) * 512 +
                                 ((p >> 3) & 3) * 128 + (c & 15) * 8 + (p & 7);
                    vF[idx] = (unsigned short)f_to_bf16(val);
                }
            }
        }
    }
}

// ---------- K3: k-conv as tap-decomposed MFMA GEMM, 16 waves, 4-way c-split ----------
__global__ __launch_bounds__(1024, 4) void pam_kconv_mfma(
    const unsigned short* __restrict__ xTphi, const unsigned short* __restrict__ xTplo,
    const unsigned short* __restrict__ wkFhi, const unsigned short* __restrict__ wkFlo,
    const float* __restrict__ affK,
    unsigned short* __restrict__ kFhi, unsigned short* __restrict__ kFlo) {
    __shared__ float red[3 * 4 * 64 * 8];   // 24 KiB
    int t = threadIdx.x;
    int hk = blockIdx.x, b = blockIdx.y;
    int wid = t >> 6, lane = t & 63, g = lane >> 4, lm = lane & 15;
    int dt = wid & 3, cq = wid >> 2;
    int goff = g * 8;
    f32x4 acc0 = (f32x4){0.f, 0.f, 0.f, 0.f};
    f32x4 acc1 = (f32x4){0.f, 0.f, 0.f, 0.f};
    #pragma unroll
    for (int r = 0; r < 3; r++) {
        size_t arow = ((size_t)(b * 65 + 2 * hk + r)) * 65 * 512;
        #pragma unroll
        for (int s = 0; s < 3; s++) {
            size_t aoff = arow + (size_t)(2 * lm + s) * 512 + goff;   // pixel wk=lm
            const unsigned short* pa0h = xTphi + aoff;
            const unsigned short* pa0l = xTplo + aoff;
            int tap = r * 3 + s;
            const unsigned short* pb_h = wkFhi + (((size_t)(tap * 4 + dt) * 16) * 64 + lane) * 8;
            const unsigned short* pb_l = wkFlo + (((size_t)(tap * 4 + dt) * 16) * 64 + lane) * 8;
            #pragma unroll
            for (int k = 0; k < 4; k++) {
                int c0 = cq * 128 + k * 32;
                bf16x8 a0h = *(const bf16x8*)(pa0h + c0);
                bf16x8 a1h = *(const bf16x8*)(pa0h + 32 * 512 + c0);   // pixel wk=lm+16
                bf16x8 a0l = *(const bf16x8*)(pa0l + c0);
                bf16x8 a1l = *(const bf16x8*)(pa0l + 32 * 512 + c0);
                bf16x8 bh  = *(const bf16x8*)(pb_h + (size_t)(c0 >> 5) * 512);
                bf16x8 bl  = *(const bf16x8*)(pb_l + (size_t)(c0 >> 5) * 512);
                acc0 = __builtin_amdgcn_mfma_f32_16x16x32_bf16(a0h, bh, acc0, 0, 0, 0);
                acc1 = __builtin_amdgcn_mfma_f32_16x16x32_bf16(a1h, bh, acc1, 0, 0, 0);
                acc0 = __builtin_amdgcn_mfma_f32_16x16x32_bf16(a0l, bh, acc0, 0, 0, 0);
                acc1 = __builtin_amdgcn_mfma_f32_16x16x32_bf16(a1l, bh, acc1, 0, 0, 0);
                acc0 = __builtin_amdgcn_mfma_f32_16x16x32_bf16(a0h, bl, acc0, 0, 0, 0);
                acc1 = __builtin_amdgcn_mfma_f32_16x16x32_bf16(a1h, bl, acc1, 0, 0, 0);
            }
        }
    }
    if (cq > 0) {
        float* dst = red + (((size_t)(cq - 1) * 4 + dt) * 64 + lane) * 8;
        *(f32x4*)dst = acc0;
        *(f32x4*)(dst + 4) = acc1;
    }
    __syncthreads();
    if (cq != 0) return;
    #pragma unroll
    for (int q = 0; q < 3; q++) {
        const float* src = red + (((size_t)q * 4 + dt) * 64 + lane) * 8;
        f32x4 p0 = *(const f32x4*)src;
        f32x4 p1 = *(const f32x4*)(src + 4);
        acc0 += p0; acc1 += p1;
    }
    int d = dt * 16 + lm;
    float sc = affK[d], sh = affK[64 + d];
    int s_ = d >> 5, gF = (d >> 3) & 3, jF = d & 7;
    #pragma unroll
    for (int i = 0; i < 4; i++) {
        int m1 = hk * 32 + g * 4 + i;         // acc0 pixel
        int m2 = m1 + 16;                     // acc1 pixel
        float v0 = fmaf(acc0[i], sc, sh);
        float v1 = fmaf(acc1[i], sc, sh);
        unsigned short hh, ll;
        split_bf16(v0, hh, ll);
        size_t i1 = (size_t)(b * 64 + (m1 >> 4)) * 1024 + s_ * 512 + gF * 128 + (m1 & 15) * 8 + jF;
        kFhi[i1] = hh; kFlo[i1] = ll;
        split_bf16(v1, hh, ll);
        size_t i2 = (size_t)(b * 64 + (m2 >> 4)) * 1024 + s_ * 512 + gF * 128 + (m2 & 15) * 8 + jF;
        kFhi[i2] = hh; kFlo[i2] = ll;
    }
}

// ---------- K4: MFMA attention, 16 waves (1024 thr), frag-linear layouts, XCD-pinned grid ----------
// wave wid: energy n-range [wid*256, wid*256+256) (16 ftiles, ev[16] = 64 VGPR);
// PV: c-slice ct = wid (16 channels), 4 accumulator chains (ks&3 parity split).
__global__ __launch_bounds__(1024) void pam_attn(
    const unsigned short* __restrict__ qFhi, const unsigned short* __restrict__ qFlo,
    const unsigned short* __restrict__ kFhi, const unsigned short* __restrict__ kFlo,
    const unsigned short* __restrict__ vF, unsigned short* __restrict__ outsP) {
    __shared__ unsigned short Pl[65536];   // 128 KiB: [ks 128][gF 4][m 16][j 8]
    __shared__ float redM[16][16];
    __shared__ float redS[16][16];
    int t = threadIdx.x;
    int b = blockIdx.x, mt = blockIdx.y;
    int wid = t >> 6, lane = t & 63;
    int g = lane >> 4, lm = lane & 15;

    size_t kidx = (size_t)(b * 64 + mt) * 1024 + g * 128 + lm * 8;
    bf16x8 ah0 = *(const bf16x8*)(kFhi + kidx);
    bf16x8 ah1 = *(const bf16x8*)(kFhi + kidx + 512);
    bf16x8 al0 = *(const bf16x8*)(kFlo + kidx);
    bf16x8 al1 = *(const bf16x8*)(kFlo + kidx + 512);

    f32x4 ev[16];
    #pragma unroll
    for (int f = 0; f < 16; f++) ev[f] = (f32x4){0.f, 0.f, 0.f, 0.f};

    const unsigned short* qh = qFhi + (size_t)(b * 256 + wid * 16) * 1024 + g * 128 + lm * 8;
    const unsigned short* ql = qFlo + (size_t)(b * 256 + wid * 16) * 1024 + g * 128 + lm * 8;
    #pragma unroll
    for (int f = 0; f < 16; f++) {
        const unsigned short* qhp = qh + (size_t)f * 1024;
        const unsigned short* qlp = ql + (size_t)f * 1024;
        bf16x8 bh0 = *(const bf16x8*)(qhp);
        bf16x8 bh1 = *(const bf16x8*)(qhp + 512);
        bf16x8 bl0 = *(const bf16x8*)(qlp);
        bf16x8 bl1 = *(const bf16x8*)(qlp + 512);
        f32x4 e = ev[f];
        e = __builtin_amdgcn_mfma_f32_16x16x32_bf16(ah0, bh0, e, 0, 0, 0);
        e = __builtin_amdgcn_mfma_f32_16x16x32_bf16(ah1, bh1, e, 0, 0, 0);
        e = __builtin_amdgcn_mfma_f32_16x16x32_bf16(ah0, bl0, e, 0, 0, 0);
        e = __builtin_amdgcn_mfma_f32_16x16x32_bf16(ah1, bl1, e, 0, 0, 0);
        e = __builtin_amdgcn_mfma_f32_16x16x32_bf16(al0, bh0, e, 0, 0, 0);
        e = __builtin_amdgcn_mfma_f32_16x16x32_bf16(al1, bh1, e, 0, 0, 0);
        ev[f] = e;
    }

    // row max: lane-reduce over 16 lm, then cross-wave over 16 waves
    float rmax[4];
    #pragma unroll
    for (int i = 0; i < 4; i++) {
        float m_ = ev[0][i];
        #pragma unroll
        for (int f = 1; f < 16; f++) m_ = fmaxf(m_, ev[f][i]);
        #pragma unroll
        for (int off = 1; off < 16; off <<= 1) m_ = fmaxf(m_, __shfl_xor(m_, off));
        rmax[i] = m_;
    }
    if (lm == 0) {
        #pragma unroll
        for (int i = 0; i < 4; i++) redM[wid][g * 4 + i] = rmax[i];
    }
    __syncthreads();
    #pragma unroll
    for (int i = 0; i < 4; i++) {
        float m_ = redM[0][g * 4 + i];
        #pragma unroll
        for (int ww = 1; ww < 16; ww++) m_ = fmaxf(m_, redM[ww][g * 4 + i]);
        rmax[i] = m_;
    }

    // exp, bf16 round, sum of ROUNDED values, store frag-linear
    // ftile = wid*16+f ; ks = ftile>>1 = wid*8 + (f>>1)
    float rsum[4] = {0.f, 0.f, 0.f, 0.f};
    #pragma unroll
    for (int f = 0; f < 16; f++) {
        int ks = wid * 8 + (f >> 1);
        int gF = (f & 1) * 2 + (lm >> 3);
        int jF = lm & 7;
        #pragma unroll
        for (int i = 0; i < 4; i++) {
            float p = __expf(ev[f][i] - rmax[i]);
            uint32_t u = f_to_bf16(p);
            rsum[i] += bf16hi_to_f(u << 16);
            Pl[((ks * 4 + gF) * 16 + (g * 4 + i)) * 8 + jF] = (unsigned short)u;
        }
    }
    #pragma unroll
    for (int i = 0; i < 4; i++) {
        float s_ = rsum[i];
        #pragma unroll
        for (int off = 1; off < 16; off <<= 1) s_ += __shfl_xor(s_, off);
        rsum[i] = s_;
    }
    if (lm == 0) {
        #pragma unroll
        for (int i = 0; i < 4; i++) redS[wid][g * 4 + i] = rsum[i];
    }
    __syncthreads();   // P fully written + sums available
    float sinv[4];
    #pragma unroll
    for (int i = 0; i < 4; i++) {
        float s_ = 0.f;
        #pragma unroll
        for (int ww = 0; ww < 16; ww++) s_ += redS[ww][g * 4 + i];
        sinv[i] = 1.f / s_;
    }

    // PV: wave -> c-slice ct = wid (16 c); 4 acc chains via ks parity
    f32x4 o[4];
    #pragma unroll
    for (int p_ = 0; p_ < 4; p_++) o[p_] = (f32x4){0.f, 0.f, 0.f, 0.f};
    const unsigned short* vb = vF + (size_t)b * 1048576 + wid * 512 + g * 128 + lm * 8;
    #pragma unroll 8
    for (int ks = 0; ks < 128; ks++) {
        bf16x8 pa = *(const bf16x8*)(Pl + ((ks * 4 + g) * 16 + lm) * 8);
        bf16x8 bv = *(const bf16x8*)(vb + (size_t)ks * 8192);
        o[ks & 3] = __builtin_amdgcn_mfma_f32_16x16x32_bf16(pa, bv, o[ks & 3], 0, 0, 0);
    }
    f32x4 of = (o[0] + o[1]) + (o[2] + o[3]);

    #pragma unroll
    for (int i = 0; i < 4; i++) {
        int m = mt * 16 + g * 4 + i;          // pixel index
        int hk2 = m >> 5, wk2 = m & 31;
        unsigned short* op = outsP + (((size_t)(b * 33 + hk2)) * 33 + wk2) * 256;
        op[wid * 16 + lm] = (unsigned short)f_to_bf16(of[i] * sinv[i]);
    }
}

// ---------- K5: transpose-conv as balanced row-pair MFMA, frag-linear bf16 weights ----------
template<int LROW, int KH, int KW>
__device__ __forceinline__ void deconv_tap(
    const unsigned short* __restrict__ wdF,
    const char* lb, int ct0, int lane, int lm, f32x4 (&acc)[2][2][2]) {
    constexpr int wop = (KW == 1) ? 0 : 1;
    constexpr int dw = (KW == 0) ? 1 : 0;
    constexpr int tap = KH * 3 + KW;
    int g = lane >> 4;
    int p0 = LROW * 33 + lm + dw;
    int p1 = p0 + 16;
    uint32_t s0 = ((uint32_t)(p0 & 7)) << 4;
    uint32_t s1 = ((uint32_t)(p1 & 7)) << 4;
    uint32_t b0a = (uint32_t)p0 * 512 + (uint32_t)g * 16;
    uint32_t b1a = (uint32_t)p1 * 512 + (uint32_t)g * 16;
    const unsigned short* a0p = wdF + ((size_t)(tap * 32 + ct0) * 8) * 512 + lane * 8;
    const unsigned short* a1p = a0p + 8 * 512;     // ct0+1
    #pragma unroll
    for (int cs = 0; cs < 8; cs++) {
        bf16x8 bv0 = *(const bf16x8*)(lb + ((b0a + (uint32_t)cs * 64) ^ s0));
        bf16x8 bv1 = *(const bf16x8*)(lb + ((b1a + (uint32_t)cs * 64) ^ s1));
        bf16x8 a0 = *(const bf16x8*)(a0p + cs * 512);
        bf16x8 a1 = *(const bf16x8*)(a1p + cs * 512);
        acc[wop][0][0] = __builtin_amdgcn_mfma_f32_16x16x32_bf16(a0, bv0, acc[wop][0][0], 0, 0, 0);
        acc[wop][0][1] = __builtin_amdgcn_mfma_f32_16x16x32_bf16(a0, bv1, acc[wop][0][1], 0, 0, 0);
        acc[wop][1][0] = __builtin_amdgcn_mfma_f32_16x16x32_bf16(a1, bv0, acc[wop][1][0], 0, 0, 0);
        acc[wop][1][1] = __builtin_amdgcn_mfma_f32_16x16x32_bf16(a1, bv1, acc[wop][1][1], 0, 0, 0);
    }
}

__device__ __forceinline__ void deconv_epi(
    const f32x4 (&acc)[2][2][2], const float* __restrict__ affD,
    const float* __restrict__ x, float* __restrict__ out,
    int b, int ho, int co0, int lm, int g) {
    #pragma unroll
    for (int mf = 0; mf < 2; mf++) {
        #pragma unroll
        for (int i = 0; i < 4; i++) {
            int co = co0 + mf * 16 + g * 4 + i;
            float sc = affD[co], sh = affD[512 + co];
            const float* xr = x + (((size_t)b * 512 + co) * 64 + ho) * 64;
            float* orow = out + (((size_t)b * 512 + co) * 64 + ho) * 64;
            #pragma unroll
            for (int nf = 0; nf < 2; nf++) {
                int wp = nf * 16 + lm;
                float2 xv = *(const float2*)(xr + 2 * wp);
                float2 st;
                st.x = fmaxf(fmaf(acc[0][mf][nf][i], sc, sh), 0.f) + xv.x;
                st.y = fmaxf(fmaf(acc[1][mf][nf][i], sc, sh), 0.f) + xv.y;
                *(float2*)(orow + 2 * wp) = st;
            }
        }
    }
}

__global__ __launch_bounds__(1024, 4) void pam_deconv_mfma(
    const unsigned short* __restrict__ outsP,
    const unsigned short* __restrict__ wdF,
    const float* __restrict__ affD, const float* __restrict__ x, float* __restrict__ out) {
    __shared__ unsigned short Pb[16896];   // 2 rows x 33 px x 256 ci
    int t = threadIdx.x;
    int h0 = blockIdx.x, b = blockIdx.y;
    const unsigned short* src = outsP + ((size_t)(b * 33 + h0) * 33) * 256;
    for (int idx = t; idx < 2112; idx += 1024) {
        uint4 v = *(const uint4*)(src + (size_t)idx * 8);
        uint32_t byte = (uint32_t)idx * 16;
        byte ^= ((byte >> 9) & 7) << 4;
        *(uint4*)((char*)Pb + byte) = v;
    }
    __syncthreads();

    int wid = t >> 6, lane = t & 63, g = lane >> 4, lm = lane & 15;
    int ct0 = wid * 2, co0 = wid * 32;
    const char* lb = (const char*)Pb;

    {   // even output row ho = 2*h0 : kh=1, B row h0 (LDS row 0)
        f32x4 acc[2][2][2];
        #pragma unroll
        for (int a = 0; a < 2; a++)
            #pragma unroll
            for (int m = 0; m < 2; m++)
                #pragma unroll
                for (int n = 0; n < 2; n++) acc[a][m][n] = (f32x4){0.f, 0.f, 0.f, 0.f};
        deconv_tap<0, 1, 0>(wdF, lb, ct0, lane, lm, acc);
        deconv_tap<0, 1, 1>(wdF, lb, ct0, lane, lm, acc);
        deconv_tap<0, 1, 2>(wdF, lb, ct0, lane, lm, acc);
        deconv_epi(acc, affD, x, out, b, 2 * h0, co0, lm, g);
    }
    {   // odd output row ho = 2*h0+1 : kh=2 B row h0, kh=0 B row h0+1
        f32x4 acc[2][2][2];
        #pragma unroll
        for (int a = 0; a < 2; a++)
            #pragma unroll
            for (int m = 0; m < 2; m++)
                #pragma unroll
                for (int n = 0; n < 2; n++) acc[a][m][n] = (f32x4){0.f, 0.f, 0.f, 0.f};
        deconv_tap<0, 2, 0>(wdF, lb, ct0, lane, lm, acc);
        deconv_tap<0, 2, 1>(wdF, lb, ct0, lane, lm, acc);
        deconv_tap<0, 2, 2>(wdF, lb, ct0, lane, lm, acc);
        deconv_tap<1, 0, 0>(wdF, lb, ct0, lane, lm, acc);
        deconv_tap<1, 0, 1>(wdF, lb, ct0, lane, lm, acc);
        deconv_tap<1, 0, 2>(wdF, lb, ct0, lane, lm, acc);
        deconv_epi(acc, affD, x, out, b, 2 * h0 + 1, co0, lm, g);
    }
}

// ---------- launcher ----------
extern "C" void kernel_launch(void* const* d_in, const int* in_sizes, int n_in,
                              void* d_out, int out_size, void* d_ws, size_t ws_size,
                              hipStream_t stream) {
    const float* x   = (const float*)d_in[0];
    const float* w_q = (const float*)d_in[1];
    const float* b_q = (const float*)d_in[2];
    const float* qs  = (const float*)d_in[3];
    const float* qb  = (const float*)d_in[4];
    const float* qm  = (const float*)d_in[5];
    const float* qv  = (const float*)d_in[6];
    const float* w_k = (const float*)d_in[7];
    const float* b_k = (const float*)d_in[8];
    const float* ks  = (const float*)d_in[9];
    const float* kb  = (const float*)d_in[10];
    const float* km  = (const float*)d_in[11];
    const float* kv  = (const float*)d_in[12];
    const float* w_v = (const float*)d_in[13];
    const float* b_v = (const float*)d_in[14];
    const float* w_d = (const float*)d_in[15];
    const float* ds  = (const float*)d_in[16];
    const float* db  = (const float*)d_in[17];
    const float* dm  = (const float*)d_in[18];
    const float* dv  = (const float*)d_in[19];
    float* out = (float*)d_out;

    char* wsb = (char*)d_ws;
    unsigned short* qFhi  = (unsigned short*)(wsb);               //  4,194,304
    unsigned short* qFlo  = (unsigned short*)(wsb + 4194304);     //  4,194,304
    unsigned short* vF    = (unsigned short*)(wsb + 8388608);     // 16,777,216
    unsigned short* kFhi  = (unsigned short*)(wsb + 25165824);    //  1,048,576
    unsigned short* kFlo  = (unsigned short*)(wsb + 26214400);    //  1,048,576
    unsigned short* wkFhi = (unsigned short*)(wsb + 27262976);    //    589,824
    unsigned short* wkFlo = (unsigned short*)(wsb + 27852800);    //    589,824
    float*          affQ  = (float*)(wsb + 28442624);             //        512
    float*          affK  = (float*)(wsb + 28443136);             //        512
    float*          affD  = (float*)(wsb + 28443648);             //      4,096
    // wqvF aliases the kF region (dead until kconv runs, which is after qv).
    unsigned short* wqvFhi = (unsigned short*)(wsb + 25165824);   //    327,680 (alias kFhi)
    unsigned short* wqvFlo = (unsigned short*)(wsb + 25493504);   //    327,680 (alias kFhi)
    // X region: xTp{hi,lo} live [pam_xt .. pam_kconv_mfma]; then reused:
    unsigned short* xTphi = (unsigned short*)(wsb + 28447744);    // 34,611,200
    unsigned short* xTplo = (unsigned short*)(wsb + 63058944);    // 34,611,200 -> end 97,670,144
    unsigned short* outsP = (unsigned short*)(wsb + 28447744);    //  4,460,544 (alias)
    unsigned short* wdF   = (unsigned short*)(wsb + 32908288);    //  2,359,296 (alias)

    hipLaunchKernelGGL(pam_aff_kernel, dim3(1), dim3(640), 0, stream,
                       b_q, qs, qb, qm, qv, b_k, ks, kb, km, kv, ds, db, dm, dv,
                       affQ, affK, affD);
    hipLaunchKernelGGL(pam_wkt, dim3(1152), dim3(256), 0, stream, w_k, wkFhi, wkFlo);
    hipLaunchKernelGGL(pam_wqv, dim3(640), dim3(256), 0, stream, w_q, w_v, affQ, wqvFhi, wqvFlo);
    hipLaunchKernelGGL(pam_xt, dim3(65, 8), dim3(256), 0, stream, x, xTphi, xTplo);
    hipLaunchKernelGGL(pam_qv_mfma, dim3(64, 8), dim3(256), 0, stream,
                       xTphi, xTplo, wqvFhi, wqvFlo, affQ, b_v, qFhi, qFlo, vF);
    hipLaunchKernelGGL(pam_kconv_mfma, dim3(32, 8), dim3(1024), 0, stream,
                       xTphi, xTplo, wkFhi, wkFlo, affK, kFhi, kFlo);
    // xTp dead from here; aliased region reused for outsP / wdF.
    hipLaunchKernelGGL(pam_wdtb, dim3(4608), dim3(256), 0, stream, w_d, wdF);
    hipLaunchKernelGGL(pam_zeroP, dim3(1089), dim3(256), 0, stream, outsP);
    hipLaunchKernelGGL(pam_attn, dim3(8, 64), dim3(1024), 0, stream,
                       qFhi, qFlo, kFhi, kFlo, vF, outsP);
    hipLaunchKernelGGL(pam_deconv_mfma, dim3(32, 8), dim3(1024), 0, stream,
                       outsP, wdF, affD, x, out);
}

// Round 11
// 368.849 us; speedup vs baseline: 5.0667x; 1.0040x over previous
//
#include <hip/hip_runtime.h>
#include <hip/hip_bf16.h>
#include <cstdint>

#define BN_EPS 1e-5f

typedef short bf16x8 __attribute__((ext_vector_type(8)));
typedef float f32x4 __attribute__((ext_vector_type(4)));

// ---------- helpers ----------
__device__ __forceinline__ float bf16hi_to_f(uint32_t hi) {
    union { uint32_t u; float f; } c; c.u = hi; return c.f;
}
__device__ __forceinline__ uint32_t f_to_bf16(float f) {
    union { float f; uint32_t u; } c; c.f = f;
    uint32_t r = c.u + 0x7fffu + ((c.u >> 16) & 1u);  // RNE
    return r >> 16;
}
__device__ __forceinline__ void split_bf16(float v, unsigned short& hi, unsigned short& lo) {
    uint32_t h = f_to_bf16(v);
    float fh = bf16hi_to_f(h << 16);
    uint32_t l = f_to_bf16(v - fh);
    hi = (unsigned short)h; lo = (unsigned short)l;
}

// ---------- K0: BN affine precompute ----------
__global__ void pam_aff_kernel(const float* bq, const float* qs, const float* qb, const float* qm, const float* qv,
                               const float* bk, const float* ks, const float* kb, const float* km, const float* kv,
                               const float* ds, const float* db, const float* dm, const float* dv,
                               float* affQ, float* affK, float* affD) {
    int t = threadIdx.x;
    if (t < 64) {
        float inv = qs[t] * rsqrtf(qv[t] + BN_EPS);
        affQ[t] = inv; affQ[64 + t] = bq[t] * inv + qb[t] - qm[t] * inv;
    } else if (t < 128) {
        int i = t - 64;
        float inv = ks[i] * rsqrtf(kv[i] + BN_EPS);
        affK[i] = inv; affK[64 + i] = bk[i] * inv + kb[i] - km[i] * inv;
    } else {
        int i = t - 128;
        if (i < 512) {
            float inv = ds[i] * rsqrtf(dv[i] + BN_EPS);
            affD[i] = inv; affD[512 + i] = db[i] - dm[i] * inv;
        }
    }
}

// ---------- K1: w_d (256,512,3,3) -> frag-linear bf16 wdF[tap][ct 32][cs 8][lane 64][j 8] ----------
__global__ void pam_wdtb(const float* __restrict__ wd, unsigned short* __restrict__ wdF) {
    int o = blockIdx.x * 256 + threadIdx.x;       // < 9*512*256 = 1,179,648
    int ci = o & 255; int co = (o >> 8) & 511; int tap = o >> 17;
    float v = wd[(size_t)ci * 4608 + co * 9 + tap];
    int ct = co >> 4, lmr = co & 15, cs = ci >> 5, g = (ci >> 3) & 3, j = ci & 7;
    size_t idx = (((size_t)(tap * 32 + ct) * 8 + cs) * 512) + g * 128 + lmr * 8 + j;
    wdF[idx] = (unsigned short)f_to_bf16(v);
}

// ---------- K1b: w_k (64,512,3,3) -> frag-linear hi/lo wkF[tap 9][dt 4][cs 16][lane 64][j 8] ----------
__global__ void pam_wkt(const float* __restrict__ wk,
                        unsigned short* __restrict__ wkFhi, unsigned short* __restrict__ wkFlo) {
    int o = blockIdx.x * 256 + threadIdx.x;       // < 9*64*512 = 294912
    int c = o & 511; int d = (o >> 9) & 63; int tap = o >> 15;
    float v = wk[((size_t)d * 512 + c) * 9 + tap];
    unsigned short h, l;
    split_bf16(v, h, l);
    int dt = d >> 4, lm = d & 15, cs = c >> 5, g = (c >> 3) & 3, j = c & 7;
    size_t idx = (((size_t)((tap * 4 + dt) * 16 + cs)) * 64 + g * 16 + lm) * 8 + j;
    wkFhi[idx] = h; wkFlo[idx] = l;
}

// ---------- K1e: w_q (scaled) + w_v -> frag-linear hi/lo wqvF[ct 20][cs 16][lane 64][j 8] ----------
__global__ void pam_wqv(const float* __restrict__ wq, const float* __restrict__ wv,
                        const float* __restrict__ affQ,
                        unsigned short* __restrict__ wqvFhi, unsigned short* __restrict__ wqvFlo) {
    int o = blockIdx.x * 256 + threadIdx.x;   // < 320*512 = 163840
    int c = o & 511, R = o >> 9;
    float v = (R < 64) ? wq[(size_t)R * 512 + c] * affQ[R] : wv[(size_t)(R - 64) * 512 + c];
    unsigned short h, l;
    split_bf16(v, h, l);
    int ct = R >> 4, lmr = R & 15, cs = c >> 5, g = (c >> 3) & 3, j = c & 7;
    size_t idx = (((size_t)(ct * 16 + cs)) * 64 + g * 16 + lmr) * 8 + j;
    wqvFhi[idx] = h; wqvFlo[idx] = l;
}

// ---------- K1c: x -> xTp{hi,lo}[b][65][65][512]  (pixel-major, c-contig, -1 pad) ----------
__global__ __launch_bounds__(256) void pam_xt(const float* __restrict__ x,
                                              unsigned short* __restrict__ xTphi,
                                              unsigned short* __restrict__ xTplo) {
    int t = threadIdx.x;
    int ri = blockIdx.x;       // 0..64 ; input row hi = ri-1
    int b = blockIdx.y;
    size_t rowbase = ((size_t)b * 65 + ri) * 65 * 512;
    uint4 z = make_uint4(0, 0, 0, 0);
    if (ri == 0) {
        for (int idx = t; idx < 65 * 512 / 8; idx += 256) {
            *(uint4*)(xTphi + rowbase + (size_t)idx * 8) = z;
            *(uint4*)(xTplo + rowbase + (size_t)idx * 8) = z;
        }
        return;
    }
    if (t < 64) {
        *(uint4*)(xTphi + rowbase + (size_t)t * 8) = z;
        *(uint4*)(xTplo + rowbase + (size_t)t * 8) = z;
    }
    int hi = ri - 1;
    int wi = t & 63;
    const float* xb = x + (size_t)b * 512 * 4096 + (size_t)hi * 64 + wi;
    for (int it = 0; it < 16; ++it) {
        int cg = (t >> 6) + it * 4;     // 0..63
        int c0 = cg * 8;
        unsigned short h[8], l[8];
        #pragma unroll
        for (int j = 0; j < 8; j++) {
            float v = xb[(size_t)(c0 + j) * 4096];
            split_bf16(v, h[j], l[j]);
        }
        size_t dst = rowbase + (size_t)(wi + 1) * 512 + c0;
        uint4 ph = make_uint4((uint32_t)h[0] | ((uint32_t)h[1] << 16),
                              (uint32_t)h[2] | ((uint32_t)h[3] << 16),
                              (uint32_t)h[4] | ((uint32_t)h[5] << 16),
                              (uint32_t)h[6] | ((uint32_t)h[7] << 16));
        uint4 pl = make_uint4((uint32_t)l[0] | ((uint32_t)l[1] << 16),
                              (uint32_t)l[2] | ((uint32_t)l[3] << 16),
                              (uint32_t)l[4] | ((uint32_t)l[5] << 16),
                              (uint32_t)l[6] | ((uint32_t)l[7] << 16));
        *(uint4*)(xTphi + dst) = ph;
        *(uint4*)(xTplo + dst) = pl;
    }
}

// ---------- K1d: zero-fill outsP pad entries ----------
__global__ void pam_zeroP(unsigned short* __restrict__ p) {
    size_t i = ((size_t)blockIdx.x * 256 + threadIdx.x) * 8;   // total 2,230,272 ushorts
    uint4 z = make_uint4(0, 0, 0, 0);
    *(uint4*)(p + i) = z;
}

// ---------- K2: fused q+v 1x1 conv as MFMA GEMM (3-term hi/lo) ----------
__global__ __launch_bounds__(256) void pam_qv_mfma(
    const unsigned short* __restrict__ xTphi, const unsigned short* __restrict__ xTplo,
    const unsigned short* __restrict__ wqvFhi, const unsigned short* __restrict__ wqvFlo,
    const float* __restrict__ affQ, const float* __restrict__ bv,
    unsigned short* __restrict__ qFhi, unsigned short* __restrict__ qFlo,
    unsigned short* __restrict__ vF) {
    int t = threadIdx.x;
    int h = blockIdx.x, b = blockIdx.y;
    int wv_ = t >> 6, lane = t & 63, g = lane >> 4, lm = lane & 15;
    int ct0 = wv_ * 5;

    f32x4 acc[5][4];
    #pragma unroll
    for (int m = 0; m < 5; m++)
        #pragma unroll
        for (int n = 0; n < 4; n++) acc[m][n] = (f32x4){0.f, 0.f, 0.f, 0.f};

    const unsigned short* xbh = xTphi + (((size_t)(b * 65) + h + 1) * 65 + 1) * 512 + (size_t)lm * 512 + g * 8;
    const unsigned short* xbl = xTplo + (((size_t)(b * 65) + h + 1) * 65 + 1) * 512 + (size_t)lm * 512 + g * 8;
    const unsigned short* wh = wqvFhi + (size_t)lane * 8;
    const unsigned short* wl = wqvFlo + (size_t)lane * 8;

    #pragma unroll 2
    for (int cs = 0; cs < 16; cs++) {
        int coff = cs * 32;
        bf16x8 bh[4], bl[4];
        #pragma unroll
        for (int nt = 0; nt < 4; nt++) {
            bh[nt] = *(const bf16x8*)(xbh + (size_t)nt * 16 * 512 + coff);
            bl[nt] = *(const bf16x8*)(xbl + (size_t)nt * 16 * 512 + coff);
        }
        bf16x8 ah[5], al[5];
        #pragma unroll
        for (int m = 0; m < 5; m++) {
            size_t aoff = (size_t)((ct0 + m) * 16 + cs) * 512;
            ah[m] = *(const bf16x8*)(wh + aoff);
            al[m] = *(const bf16x8*)(wl + aoff);
        }
        #pragma unroll
        for (int m = 0; m < 5; m++)
            #pragma unroll
            for (int n = 0; n < 4; n++) {
                acc[m][n] = __builtin_amdgcn_mfma_f32_16x16x32_bf16(ah[m], bh[n], acc[m][n], 0, 0, 0);
                acc[m][n] = __builtin_amdgcn_mfma_f32_16x16x32_bf16(ah[m], bl[n], acc[m][n], 0, 0, 0);
                acc[m][n] = __builtin_amdgcn_mfma_f32_16x16x32_bf16(al[m], bh[n], acc[m][n], 0, 0, 0);
            }
    }

    #pragma unroll
    for (int m = 0; m < 5; m++) {
        #pragma unroll
        for (int i = 0; i < 4; i++) {
            int R = (ct0 + m) * 16 + g * 4 + i;
            float shift = (R < 64) ? affQ[64 + R] : bv[R - 64];
            if (R < 64) {
                int s_ = R >> 5, gF = (R >> 3) & 3, jF = R & 7;
                #pragma unroll
                for (int nt = 0; nt < 4; nt++) {
                    int p = h * 64 + nt * 16 + lm;
                    float val = acc[m][nt][i] + shift;
                    unsigned short hh, ll;
                    split_bf16(val, hh, ll);
                    size_t idx = (size_t)(b * 256 + (p >> 4)) * 1024 + s_ * 512 + gF * 128 + (p & 15) * 8 + jF;
                    qFhi[idx] = hh; qFlo[idx] = ll;
                }
            } else {
                int c = R - 64;
                #pragma unroll
                for (int nt = 0; nt < 4; nt++) {
                    int p = h * 64 + nt * 16 + lm;
                    float val = acc[m][nt][i] + shift;
                    size_t idx = (size_t)(b * 128 + (p >> 5)) * 8192 + (c >> 4) * 512 +
                                 ((p >> 3) & 3) * 128 + (c & 15) * 8 + (p & 7);
                    vF[idx] = (unsigned short)f_to_bf16(val);
                }
            }
        }
    }
}

// ---------- K3: k-conv as tap-decomposed MFMA GEMM, 16 waves, 4-way c-split ----------
__global__ __launch_bounds__(1024, 4) void pam_kconv_mfma(
    const unsigned short* __restrict__ xTphi, const unsigned short* __restrict__ xTplo,
    const unsigned short* __restrict__ wkFhi, const unsigned short* __restrict__ wkFlo,
    const float* __restrict__ affK,
    unsigned short* __restrict__ kFhi, unsigned short* __restrict__ kFlo) {
    __shared__ float red[3 * 4 * 64 * 8];   // 24 KiB
    int t = threadIdx.x;
    int hk = blockIdx.x, b = blockIdx.y;
    int wid = t >> 6, lane = t & 63, g = lane >> 4, lm = lane & 15;
    int dt = wid & 3, cq = wid >> 2;
    int goff = g * 8;
    f32x4 acc0 = (f32x4){0.f, 0.f, 0.f, 0.f};
    f32x4 acc1 = (f32x4){0.f, 0.f, 0.f, 0.f};
    #pragma unroll
    for (int r = 0; r < 3; r++) {
        size_t arow = ((size_t)(b * 65 + 2 * hk + r)) * 65 * 512;
        #pragma unroll
        for (int s = 0; s < 3; s++) {
            size_t aoff = arow + (size_t)(2 * lm + s) * 512 + goff;   // pixel wk=lm
            const unsigned short* pa0h = xTphi + aoff;
            const unsigned short* pa0l = xTplo + aoff;
            int tap = r * 3 + s;
            const unsigned short* pb_h = wkFhi + (((size_t)(tap * 4 + dt) * 16) * 64 + lane) * 8;
            const unsigned short* pb_l = wkFlo + (((size_t)(tap * 4 + dt) * 16) * 64 + lane) * 8;
            #pragma unroll
            for (int k = 0; k < 4; k++) {
                int c0 = cq * 128 + k * 32;
                bf16x8 a0h = *(const bf16x8*)(pa0h + c0);
                bf16x8 a1h = *(const bf16x8*)(pa0h + 32 * 512 + c0);   // pixel wk=lm+16
                bf16x8 a0l = *(const bf16x8*)(pa0l + c0);
                bf16x8 a1l = *(const bf16x8*)(pa0l + 32 * 512 + c0);
                bf16x8 bh  = *(const bf16x8*)(pb_h + (size_t)(c0 >> 5) * 512);
                bf16x8 bl  = *(const bf16x8*)(pb_l + (size_t)(c0 >> 5) * 512);
                acc0 = __builtin_amdgcn_mfma_f32_16x16x32_bf16(a0h, bh, acc0, 0, 0, 0);
                acc1 = __builtin_amdgcn_mfma_f32_16x16x32_bf16(a1h, bh, acc1, 0, 0, 0);
                acc0 = __builtin_amdgcn_mfma_f32_16x16x32_bf16(a0l, bh, acc0, 0, 0, 0);
                acc1 = __builtin_amdgcn_mfma_f32_16x16x32_bf16(a1l, bh, acc1, 0, 0, 0);
                acc0 = __builtin_amdgcn_mfma_f32_16x16x32_bf16(a0h, bl, acc0, 0, 0, 0);
                acc1 = __builtin_amdgcn_mfma_f32_16x16x32_bf16(a1h, bl, acc1, 0, 0, 0);
            }
        }
    }
    if (cq > 0) {
        float* dst = red + (((size_t)(cq - 1) * 4 + dt) * 64 + lane) * 8;
        *(f32x4*)dst = acc0;
        *(f32x4*)(dst + 4) = acc1;
    }
    __syncthreads();
    if (cq != 0) return;
    #pragma unroll
    for (int q = 0; q < 3; q++) {
        const float* src = red + (((size_t)q * 4 + dt) * 64 + lane) * 8;
        f32x4 p0 = *(const f32x4*)src;
        f32x4 p1 = *(const f32x4*)(src + 4);
        acc0 += p0; acc1 += p1;
    }
    int d = dt * 16 + lm;
    float sc = affK[d], sh = affK[64 + d];
    int s_ = d >> 5, gF = (d >> 3) & 3, jF = d & 7;
    #pragma unroll
    for (int i = 0; i < 4; i++) {
        int m1 = hk * 32 + g * 4 + i;         // acc0 pixel
        int m2 = m1 + 16;                     // acc1 pixel
        float v0 = fmaf(acc0[i], sc, sh);
        float v1 = fmaf(acc1[i], sc, sh);
        unsigned short hh, ll;
        split_bf16(v0, hh, ll);
        size_t i1 = (size_t)(b * 64 + (m1 >> 4)) * 1024 + s_ * 512 + gF * 128 + (m1 & 15) * 8 + jF;
        kFhi[i1] = hh; kFlo[i1] = ll;
        split_bf16(v1, hh, ll);
        size_t i2 = (size_t)(b * 64 + (m2 >> 4)) * 1024 + s_ * 512 + gF * 128 + (m2 & 15) * 8 + jF;
        kFhi[i2] = hh; kFlo[i2] = ll;
    }
}

// ---------- K4: flash-style MFMA attention, 32 m-rows/block, 4 n-phases ----------
// grid (8 b, 32 mt2), 1024 thr = 16 waves. Energy wave: (mtl = wid&1, n-slice wp = wid>>1),
// 8 frags/phase (n=1024). Online softmax across phases (running max, rescale o & sums).
// P bf16 in 64KB LDS [ks 32][gF 4][m 32][j 8]; PV wave: c-slice wid, both m-tiles.
__global__ __launch_bounds__(1024) void pam_attn(
    const unsigned short* __restrict__ qFhi, const unsigned short* __restrict__ qFlo,
    const unsigned short* __restrict__ kFhi, const unsigned short* __restrict__ kFlo,
    const unsigned short* __restrict__ vF, unsigned short* __restrict__ outsP) {
    __shared__ unsigned short Pl[32768];   // 64 KiB
    __shared__ float redM[2][8][16];
    __shared__ float redS[2][8][16];
    int t = threadIdx.x;
    int b = blockIdx.x, mt2 = blockIdx.y;
    int wid = t >> 6, lane = t & 63;
    int g = lane >> 4, lm = lane & 15;
    int mtl = wid & 1, wp = wid >> 1;

    // K frags for this wave's energy m-tile (global m-tile = mt2*2 + mtl)
    size_t kidx = (size_t)(b * 64 + mt2 * 2 + mtl) * 1024 + g * 128 + lm * 8;
    bf16x8 ah0 = *(const bf16x8*)(kFhi + kidx);
    bf16x8 ah1 = *(const bf16x8*)(kFhi + kidx + 512);
    bf16x8 al0 = *(const bf16x8*)(kFlo + kidx);
    bf16x8 al1 = *(const bf16x8*)(kFlo + kidx + 512);

    float Mrun[2][4], rsum[4];
    #pragma unroll
    for (int i = 0; i < 4; i++) { Mrun[0][i] = -3e38f; Mrun[1][i] = -3e38f; rsum[i] = 0.f; }
    f32x4 o00 = (f32x4){0.f,0.f,0.f,0.f}, o01 = o00, o10 = o00, o11 = o00;  // o[mt][parity]

    const unsigned short* qhb = qFhi + (size_t)(b * 256) * 1024 + g * 128 + lm * 8;
    const unsigned short* qlb = qFlo + (size_t)(b * 256) * 1024 + g * 128 + lm * 8;
    const unsigned short* vb  = vF + (size_t)b * 1048576 + wid * 512 + g * 128 + lm * 8;

    for (int ph = 0; ph < 4; ++ph) {
        // --- energy: 8 ftiles (n = ph*1024 + wp*128 + [0,128)) ---
        f32x4 ev[8];
        #pragma unroll
        for (int f = 0; f < 8; f++) ev[f] = (f32x4){0.f, 0.f, 0.f, 0.f};
        int ft0 = ph * 64 + wp * 8;
        #pragma unroll
        for (int f = 0; f < 8; f++) {
            const unsigned short* qhp = qhb + (size_t)(ft0 + f) * 1024;
            const unsigned short* qlp = qlb + (size_t)(ft0 + f) * 1024;
            bf16x8 bh0 = *(const bf16x8*)(qhp);
            bf16x8 bh1 = *(const bf16x8*)(qhp + 512);
            bf16x8 bl0 = *(const bf16x8*)(qlp);
            bf16x8 bl1 = *(const bf16x8*)(qlp + 512);
            f32x4 e = ev[f];
            e = __builtin_amdgcn_mfma_f32_16x16x32_bf16(ah0, bh0, e, 0, 0, 0);
            e = __builtin_amdgcn_mfma_f32_16x16x32_bf16(ah1, bh1, e, 0, 0, 0);
            e = __builtin_amdgcn_mfma_f32_16x16x32_bf16(ah0, bl0, e, 0, 0, 0);
            e = __builtin_amdgcn_mfma_f32_16x16x32_bf16(ah1, bl1, e, 0, 0, 0);
            e = __builtin_amdgcn_mfma_f32_16x16x32_bf16(al0, bh0, e, 0, 0, 0);
            e = __builtin_amdgcn_mfma_f32_16x16x32_bf16(al1, bh1, e, 0, 0, 0);
            ev[f] = e;
        }
        // --- per-wave local max for own rows ---
        float pm[4];
        #pragma unroll
        for (int i = 0; i < 4; i++) {
            float m_ = ev[0][i];
            #pragma unroll
            for (int f = 1; f < 8; f++) m_ = fmaxf(m_, ev[f][i]);
            #pragma unroll
            for (int off = 1; off < 16; off <<= 1) m_ = fmaxf(m_, __shfl_xor(m_, off));
            pm[i] = m_;
        }
        __syncthreads();   // prev phase's PV (Pl reads) and redM reads complete
        if (lm == 0) {
            #pragma unroll
            for (int i = 0; i < 4; i++) redM[mtl][wp][g * 4 + i] = pm[i];
        }
        __syncthreads();
        // --- running max update + rescale factors (both m-tiles, consistent across threads) ---
        float rfac[2][4];
        #pragma unroll
        for (int mt = 0; mt < 2; mt++) {
            #pragma unroll
            for (int i = 0; i < 4; i++) {
                float pmax = redM[mt][0][g * 4 + i];
                #pragma unroll
                for (int w2 = 1; w2 < 8; w2++) pmax = fmaxf(pmax, redM[mt][w2][g * 4 + i]);
                float Mn = fmaxf(Mrun[mt][i], pmax);
                rfac[mt][i] = __expf(Mrun[mt][i] - Mn);
                Mrun[mt][i] = Mn;
            }
        }
        #pragma unroll
        for (int i = 0; i < 4; i++) rsum[i] *= rfac[mtl][i];
        #pragma unroll
        for (int i = 0; i < 4; i++) {
            o00[i] *= rfac[0][i]; o01[i] *= rfac[0][i];
            o10[i] *= rfac[1][i]; o11[i] *= rfac[1][i];
        }
        // --- exp, bf16 round, sum of ROUNDED values, store P frag-linear ---
        #pragma unroll
        for (int f = 0; f < 8; f++) {
            int ntl = wp * 8 + f;            // local ntile 0..63
            int ks = ntl >> 1;               // 0..31
            int gF = (ntl & 1) * 2 + (lm >> 3);
            int jF = lm & 7;
            #pragma unroll
            for (int i = 0; i < 4; i++) {
                float p = __expf(ev[f][i] - Mrun[mtl][i]);
                uint32_t u = f_to_bf16(p);
                rsum[i] += bf16hi_to_f(u << 16);
                Pl[((ks * 4 + gF) * 32 + mtl * 16 + g * 4 + i) * 8 + jF] = (unsigned short)u;
            }
        }
        __syncthreads();   // P ready
        // --- PV: c-slice wid, both m-tiles, 2 parity chains each ---
        #pragma unroll 4
        for (int ks2 = 0; ks2 < 16; ks2++) {
            int ksA = ks2 * 2, ksB = ks2 * 2 + 1;
            bf16x8 bvA = *(const bf16x8*)(vb + (size_t)(ph * 32 + ksA) * 8192);
            bf16x8 paA0 = *(const bf16x8*)(Pl + ((ksA * 4 + g) * 32 + lm) * 8);
            bf16x8 paA1 = *(const bf16x8*)(Pl + ((ksA * 4 + g) * 32 + 16 + lm) * 8);
            o00 = __builtin_amdgcn_mfma_f32_16x16x32_bf16(paA0, bvA, o00, 0, 0, 0);
            o10 = __builtin_amdgcn_mfma_f32_16x16x32_bf16(paA1, bvA, o10, 0, 0, 0);
            bf16x8 bvB = *(const bf16x8*)(vb + (size_t)(ph * 32 + ksB) * 8192);
            bf16x8 paB0 = *(const bf16x8*)(Pl + ((ksB * 4 + g) * 32 + lm) * 8);
            bf16x8 paB1 = *(const bf16x8*)(Pl + ((ksB * 4 + g) * 32 + 16 + lm) * 8);
            o01 = __builtin_amdgcn_mfma_f32_16x16x32_bf16(paB0, bvB, o01, 0, 0, 0);
            o11 = __builtin_amdgcn_mfma_f32_16x16x32_bf16(paB1, bvB, o11, 0, 0, 0);
        }
    }

    // --- final sum reduction + normalize + write ---
    #pragma unroll
    for (int i = 0; i < 4; i++) {
        float s_ = rsum[i];
        #pragma unroll
        for (int off = 1; off < 16; off <<= 1) s_ += __shfl_xor(s_, off);
        rsum[i] = s_;
    }
    __syncthreads();
    if (lm == 0) {
        #pragma unroll
        for (int i = 0; i < 4; i++) redS[mtl][wp][g * 4 + i] = rsum[i];
    }
    __syncthreads();
    f32x4 of0 = o00 + o01;
    f32x4 of1 = o10 + o11;
    #pragma unroll
    for (int mt = 0; mt < 2; mt++) {
        #pragma unroll
        for (int i = 0; i < 4; i++) {
            float s_ = 0.f;
            #pragma unroll
            for (int w2 = 0; w2 < 8; w2++) s_ += redS[mt][w2][g * 4 + i];
            float sinv = 1.f / s_;
            int m = mt2 * 32 + mt * 16 + g * 4 + i;
            int hk2 = m >> 5, wk2 = m & 31;
            float ofv = (mt == 0) ? of0[i] : of1[i];
            outsP[(((size_t)(b * 33 + hk2)) * 33 + wk2) * 256 + wid * 16 + lm] =
                (unsigned short)f_to_bf16(ofv * sinv);
        }
    }
}

// ---------- K5: transpose-conv as balanced row-pair MFMA, frag-linear bf16 weights ----------
template<int LROW, int KH, int KW>
__device__ __forceinline__ void deconv_tap(
    const unsigned short* __restrict__ wdF,
    const char* lb, int ct0, int lane, int lm, f32x4 (&acc)[2][2][2]) {
    constexpr int wop = (KW == 1) ? 0 : 1;
    constexpr int dw = (KW == 0) ? 1 : 0;
    constexpr int tap = KH * 3 + KW;
    int g = lane >> 4;
    int p0 = LROW * 33 + lm + dw;
    int p1 = p0 + 16;
    uint32_t s0 = ((uint32_t)(p0 & 7)) << 4;
    uint32_t s1 = ((uint32_t)(p1 & 7)) << 4;
    uint32_t b0a = (uint32_t)p0 * 512 + (uint32_t)g * 16;
    uint32_t b1a = (uint32_t)p1 * 512 + (uint32_t)g * 16;
    const unsigned short* a0p = wdF + ((size_t)(tap * 32 + ct0) * 8) * 512 + lane * 8;
    const unsigned short* a1p = a0p + 8 * 512;     // ct0+1
    #pragma unroll
    for (int cs = 0; cs < 8; cs++) {
        bf16x8 bv0 = *(const bf16x8*)(lb + ((b0a + (uint32_t)cs * 64) ^ s0));
        bf16x8 bv1 = *(const bf16x8*)(lb + ((b1a + (uint32_t)cs * 64) ^ s1));
        bf16x8 a0 = *(const bf16x8*)(a0p + cs * 512);
        bf16x8 a1 = *(const bf16x8*)(a1p + cs * 512);
        acc[wop][0][0] = __builtin_amdgcn_mfma_f32_16x16x32_bf16(a0, bv0, acc[wop][0][0], 0, 0, 0);
        acc[wop][0][1] = __builtin_amdgcn_mfma_f32_16x16x32_bf16(a0, bv1, acc[wop][0][1], 0, 0, 0);
        acc[wop][1][0] = __builtin_amdgcn_mfma_f32_16x16x32_bf16(a1, bv0, acc[wop][1][0], 0, 0, 0);
        acc[wop][1][1] = __builtin_amdgcn_mfma_f32_16x16x32_bf16(a1, bv1, acc[wop][1][1], 0, 0, 0);
    }
}

__device__ __forceinline__ void deconv_epi(
    const f32x4 (&acc)[2][2][2], const float* __restrict__ affD,
    const float* __restrict__ x, float* __restrict__ out,
    int b, int ho, int co0, int lm, int g) {
    #pragma unroll
    for (int mf = 0; mf < 2; mf++) {
        #pragma unroll
        for (int i = 0; i < 4; i++) {
            int co = co0 + mf * 16 + g * 4 + i;
            float sc = affD[co], sh = affD[512 + co];
            const float* xr = x + (((size_t)b * 512 + co) * 64 + ho) * 64;
            float* orow = out + (((size_t)b * 512 + co) * 64 + ho) * 64;
            #pragma unroll
            for (int nf = 0; nf < 2; nf++) {
                int wp = nf * 16 + lm;
                float2 xv = *(const float2*)(xr + 2 * wp);
                float2 st;
                st.x = fmaxf(fmaf(acc[0][mf][nf][i], sc, sh), 0.f) + xv.x;
                st.y = fmaxf(fmaf(acc[1][mf][nf][i], sc, sh), 0.f) + xv.y;
                *(float2*)(orow + 2 * wp) = st;
            }
        }
    }
}

__global__ __launch_bounds__(1024, 4) void pam_deconv_mfma(
    const unsigned short* __restrict__ outsP,
    const unsigned short* __restrict__ wdF,
    const float* __restrict__ affD, const float* __restrict__ x, float* __restrict__ out) {
    __shared__ unsigned short Pb[16896];   // 2 rows x 33 px x 256 ci
    int t = threadIdx.x;
    int h0 = blockIdx.x, b = blockIdx.y;
    const unsigned short* src = outsP + ((size_t)(b * 33 + h0) * 33) * 256;
    for (int idx = t; idx < 2112; idx += 1024) {
        uint4 v = *(const uint4*)(src + (size_t)idx * 8);
        uint32_t byte = (uint32_t)idx * 16;
        byte ^= ((byte >> 9) & 7) << 4;
        *(uint4*)((char*)Pb + byte) = v;
    }
    __syncthreads();

    int wid = t >> 6, lane = t & 63, g = lane >> 4, lm = lane & 15;
    int ct0 = wid * 2, co0 = wid * 32;
    const char* lb = (const char*)Pb;

    {   // even output row ho = 2*h0 : kh=1, B row h0 (LDS row 0)
        f32x4 acc[2][2][2];
        #pragma unroll
        for (int a = 0; a < 2; a++)
            #pragma unroll
            for (int m = 0; m < 2; m++)
                #pragma unroll
                for (int n = 0; n < 2; n++) acc[a][m][n] = (f32x4){0.f, 0.f, 0.f, 0.f};
        deconv_tap<0, 1, 0>(wdF, lb, ct0, lane, lm, acc);
        deconv_tap<0, 1, 1>(wdF, lb, ct0, lane, lm, acc);
        deconv_tap<0, 1, 2>(wdF, lb, ct0, lane, lm, acc);
        deconv_epi(acc, affD, x, out, b, 2 * h0, co0, lm, g);
    }
    {   // odd output row ho = 2*h0+1 : kh=2 B row h0, kh=0 B row h0+1
        f32x4 acc[2][2][2];
        #pragma unroll
        for (int a = 0; a < 2; a++)
            #pragma unroll
            for (int m = 0; m < 2; m++)
                #pragma unroll
                for (int n = 0; n < 2; n++) acc[a][m][n] = (f32x4){0.f, 0.f, 0.f, 0.f};
        deconv_tap<0, 2, 0>(wdF, lb, ct0, lane, lm, acc);
        deconv_tap<0, 2, 1>(wdF, lb, ct0, lane, lm, acc);
        deconv_tap<0, 2, 2>(wdF, lb, ct0, lane, lm, acc);
        deconv_tap<1, 0, 0>(wdF, lb, ct0, lane, lm, acc);
        deconv_tap<1, 0, 1>(wdF, lb, ct0, lane, lm, acc);
        deconv_tap<1, 0, 2>(wdF, lb, ct0, lane, lm, acc);
        deconv_epi(acc, affD, x, out, b, 2 * h0 + 1, co0, lm, g);
    }
}

// ---------- launcher ----------
extern "C" void kernel_launch(void* const* d_in, const int* in_sizes, int n_in,
                              void* d_out, int out_size, void* d_ws, size_t ws_size,
                              hipStream_t stream) {
    const float* x   = (const float*)d_in[0];
    const float* w_q = (const float*)d_in[1];
    const float* b_q = (const float*)d_in[2];
    const float* qs  = (const float*)d_in[3];
    const float* qb  = (const float*)d_in[4];
    const float* qm  = (const float*)d_in[5];
    const float* qv  = (const float*)d_in[6];
    const float* w_k = (const float*)d_in[7];
    const float* b_k = (const float*)d_in[8];
    const float* ks  = (const float*)d_in[9];
    const float* kb  = (const float*)d_in[10];
    const float* km  = (const float*)d_in[11];
    const float* kv  = (const float*)d_in[12];
    const float* w_v = (const float*)d_in[13];
    const float* b_v = (const float*)d_in[14];
    const float* w_d = (const float*)d_in[15];
    const float* ds  = (const float*)d_in[16];
    const float* db  = (const float*)d_in[17];
    const float* dm  = (const float*)d_in[18];
    const float* dv  = (const float*)d_in[19];
    float* out = (float*)d_out;

    char* wsb = (char*)d_ws;
    unsigned short* qFhi  = (unsigned short*)(wsb);               //  4,194,304
    unsigned short* qFlo  = (unsigned short*)(wsb + 4194304);     //  4,194,304
    unsigned short* vF    = (unsigned short*)(wsb + 8388608);     // 16,777,216
    unsigned short* kFhi  = (unsigned short*)(wsb + 25165824);    //  1,048,576
    unsigned short* kFlo  = (unsigned short*)(wsb + 26214400);    //  1,048,576
    unsigned short* wkFhi = (unsigned short*)(wsb + 27262976);    //    589,824
    unsigned short* wkFlo = (unsigned short*)(wsb + 27852800);    //    589,824
    float*          affQ  = (float*)(wsb + 28442624);             //        512
    float*          affK  = (float*)(wsb + 28443136);             //        512
    float*          affD  = (float*)(wsb + 28443648);             //      4,096
    // wqvF aliases the kF region (dead until kconv runs, which is after qv).
    unsigned short* wqvFhi = (unsigned short*)(wsb + 25165824);   //    327,680 (alias kFhi)
    unsigned short* wqvFlo = (unsigned short*)(wsb + 25493504);   //    327,680 (alias kFhi)
    // X region: xTp{hi,lo} live [pam_xt .. pam_kconv_mfma]; then reused:
    unsigned short* xTphi = (unsigned short*)(wsb + 28447744);    // 34,611,200
    unsigned short* xTplo = (unsigned short*)(wsb + 63058944);    // 34,611,200 -> end 97,670,144
    unsigned short* outsP = (unsigned short*)(wsb + 28447744);    //  4,460,544 (alias)
    unsigned short* wdF   = (unsigned short*)(wsb + 32908288);    //  2,359,296 (alias)

    hipLaunchKernelGGL(pam_aff_kernel, dim3(1), dim3(640), 0, stream,
                       b_q, qs, qb, qm, qv, b_k, ks, kb, km, kv, ds, db, dm, dv,
                       affQ, affK, affD);
    hipLaunchKernelGGL(pam_wkt, dim3(1152), dim3(256), 0, stream, w_k, wkFhi, wkFlo);
    hipLaunchKernelGGL(pam_wqv, dim3(640), dim3(256), 0, stream, w_q, w_v, affQ, wqvFhi, wqvFlo);
    hipLaunchKernelGGL(pam_xt, dim3(65, 8), dim3(256), 0, stream, x, xTphi, xTplo);
    hipLaunchKernelGGL(pam_qv_mfma, dim3(64, 8), dim3(256), 0, stream,
                       xTphi, xTplo, wqvFhi, wqvFlo, affQ, b_v, qFhi, qFlo, vF);
    hipLaunchKernelGGL(pam_kconv_mfma, dim3(32, 8), dim3(1024), 0, stream,
                       xTphi, xTplo, wkFhi, wkFlo, affK, kFhi, kFlo);
    // xTp dead from here; aliased region reused for outsP / wdF.
    hipLaunchKernelGGL(pam_wdtb, dim3(4608), dim3(256), 0, stream, w_d, wdF);
    hipLaunchKernelGGL(pam_zeroP, dim3(1089), dim3(256), 0, stream, outsP);
    hipLaunchKernelGGL(pam_attn, dim3(8, 32), dim3(1024), 0, stream,
                       qFhi, qFlo, kFhi, kFlo, vF, outsP);
    hipLaunchKernelGGL(pam_deconv_mfma, dim3(32, 8), dim3(1024), 0, stream,
                       outsP, wdF, affD, x, out);
}

// Round 13
// 353.554 us; speedup vs baseline: 5.2858x; 1.0433x over previous
//
#include <hip/hip_runtime.h>
#include <hip/hip_bf16.h>
#include <cstdint>

#define BN_EPS 1e-5f

typedef short bf16x8 __attribute__((ext_vector_type(8)));
typedef _Float16 f16x8 __attribute__((ext_vector_type(8)));
typedef float f32x4 __attribute__((ext_vector_type(4)));

// ---------- helpers ----------
__device__ __forceinline__ float bf16hi_to_f(uint32_t hi) {
    union { uint32_t u; float f; } c; c.u = hi; return c.f;
}
__device__ __forceinline__ uint32_t f_to_bf16(float f) {
    union { float f; uint32_t u; } c; c.f = f;
    uint32_t r = c.u + 0x7fffu + ((c.u >> 16) & 1u);  // RNE
    return r >> 16;
}
__device__ __forceinline__ unsigned short f_to_f16(float f) {
    _Float16 h = (_Float16)f;      // v_cvt_f16_f32, RNE
    union { _Float16 h; unsigned short u; } c; c.h = h; return c.u;
}
__device__ __forceinline__ void split_bf16(float v, unsigned short& hi, unsigned short& lo) {
    uint32_t h = f_to_bf16(v);
    float fh = bf16hi_to_f(h << 16);
    uint32_t l = f_to_bf16(v - fh);
    hi = (unsigned short)h; lo = (unsigned short)l;
}

// ---------- K0: BN affine precompute ----------
__global__ void pam_aff_kernel(const float* bq, const float* qs, const float* qb, const float* qm, const float* qv,
                               const float* bk, const float* ks, const float* kb, const float* km, const float* kv,
                               const float* ds, const float* db, const float* dm, const float* dv,
                               float* affQ, float* affK, float* affD) {
    int t = threadIdx.x;
    if (t < 64) {
        float inv = qs[t] * rsqrtf(qv[t] + BN_EPS);
        affQ[t] = inv; affQ[64 + t] = bq[t] * inv + qb[t] - qm[t] * inv;
    } else if (t < 128) {
        int i = t - 64;
        float inv = ks[i] * rsqrtf(kv[i] + BN_EPS);
        affK[i] = inv; affK[64 + i] = bk[i] * inv + kb[i] - km[i] * inv;
    } else {
        int i = t - 128;
        if (i < 512) {
            float inv = ds[i] * rsqrtf(dv[i] + BN_EPS);
            affD[i] = inv; affD[512 + i] = db[i] - dm[i] * inv;
        }
    }
}

// ---------- K1: w_d (256,512,3,3) -> frag-linear bf16 wdF[tap][ct 32][cs 8][lane 64][j 8] ----------
__global__ void pam_wdtb(const float* __restrict__ wd, unsigned short* __restrict__ wdF) {
    int o = blockIdx.x * 256 + threadIdx.x;       // < 9*512*256 = 1,179,648
    int ci = o & 255; int co = (o >> 8) & 511; int tap = o >> 17;
    float v = wd[(size_t)ci * 4608 + co * 9 + tap];
    int ct = co >> 4, lmr = co & 15, cs = ci >> 5, g = (ci >> 3) & 3, j = ci & 7;
    size_t idx = (((size_t)(tap * 32 + ct) * 8 + cs) * 512) + g * 128 + lmr * 8 + j;
    wdF[idx] = (unsigned short)f_to_bf16(v);
}

// ---------- K1b: w_k (64,512,3,3) -> frag-linear hi/lo wkF[tap 9][dt 4][cs 16][lane 64][j 8] ----------
__global__ void pam_wkt(const float* __restrict__ wk,
                        unsigned short* __restrict__ wkFhi, unsigned short* __restrict__ wkFlo) {
    int o = blockIdx.x * 256 + threadIdx.x;       // < 9*64*512 = 294912
    int c = o & 511; int d = (o >> 9) & 63; int tap = o >> 15;
    float v = wk[((size_t)d * 512 + c) * 9 + tap];
    unsigned short h, l;
    split_bf16(v, h, l);
    int dt = d >> 4, lm = d & 15, cs = c >> 5, g = (c >> 3) & 3, j = c & 7;
    size_t idx = (((size_t)((tap * 4 + dt) * 16 + cs)) * 64 + g * 16 + lm) * 8 + j;
    wkFhi[idx] = h; wkFlo[idx] = l;
}

// ---------- K1e: w_q (scaled) + w_v -> frag-linear hi/lo wqvF[ct 20][cs 16][lane 64][j 8] ----------
__global__ void pam_wqv(const float* __restrict__ wq, const float* __restrict__ wv,
                        const float* __restrict__ affQ,
                        unsigned short* __restrict__ wqvFhi, unsigned short* __restrict__ wqvFlo) {
    int o = blockIdx.x * 256 + threadIdx.x;   // < 320*512 = 163840
    int c = o & 511, R = o >> 9;
    float v = (R < 64) ? wq[(size_t)R * 512 + c] * affQ[R] : wv[(size_t)(R - 64) * 512 + c];
    unsigned short h, l;
    split_bf16(v, h, l);
    int ct = R >> 4, lmr = R & 15, cs = c >> 5, g = (c >> 3) & 3, j = c & 7;
    size_t idx = (((size_t)(ct * 16 + cs)) * 64 + g * 16 + lmr) * 8 + j;
    wqvFhi[idx] = h; wqvFlo[idx] = l;
}

// ---------- K1c: x -> xTp{hi,lo}[b][65][65][512]  (pixel-major, c-contig, -1 pad) ----------
__global__ __launch_bounds__(256) void pam_xt(const float* __restrict__ x,
                                              unsigned short* __restrict__ xTphi,
                                              unsigned short* __restrict__ xTplo) {
    int t = threadIdx.x;
    int ri = blockIdx.x;       // 0..64 ; input row hi = ri-1
    int b = blockIdx.y;
    size_t rowbase = ((size_t)b * 65 + ri) * 65 * 512;
    uint4 z = make_uint4(0, 0, 0, 0);
    if (ri == 0) {
        for (int idx = t; idx < 65 * 512 / 8; idx += 256) {
            *(uint4*)(xTphi + rowbase + (size_t)idx * 8) = z;
            *(uint4*)(xTplo + rowbase + (size_t)idx * 8) = z;
        }
        return;
    }
    if (t < 64) {
        *(uint4*)(xTphi + rowbase + (size_t)t * 8) = z;
        *(uint4*)(xTplo + rowbase + (size_t)t * 8) = z;
    }
    int hi = ri - 1;
    int wi = t & 63;
    const float* xb = x + (size_t)b * 512 * 4096 + (size_t)hi * 64 + wi;
    for (int it = 0; it < 16; ++it) {
        int cg = (t >> 6) + it * 4;     // 0..63
        int c0 = cg * 8;
        unsigned short h[8], l[8];
        #pragma unroll
        for (int j = 0; j < 8; j++) {
            float v = xb[(size_t)(c0 + j) * 4096];
            split_bf16(v, h[j], l[j]);
        }
        size_t dst = rowbase + (size_t)(wi + 1) * 512 + c0;
        uint4 ph = make_uint4((uint32_t)h[0] | ((uint32_t)h[1] << 16),
                              (uint32_t)h[2] | ((uint32_t)h[3] << 16),
                              (uint32_t)h[4] | ((uint32_t)h[5] << 16),
                              (uint32_t)h[6] | ((uint32_t)h[7] << 16));
        uint4 pl = make_uint4((uint32_t)l[0] | ((uint32_t)l[1] << 16),
                              (uint32_t)l[2] | ((uint32_t)l[3] << 16),
                              (uint32_t)l[4] | ((uint32_t)l[5] << 16),
                              (uint32_t)l[6] | ((uint32_t)l[7] << 16));
        *(uint4*)(xTphi + dst) = ph;
        *(uint4*)(xTplo + dst) = pl;
    }
}

// ---------- K1d: zero-fill outsP pad entries ----------
__global__ void pam_zeroP(unsigned short* __restrict__ p) {
    size_t i = ((size_t)blockIdx.x * 256 + threadIdx.x) * 8;   // total 2,230,272 ushorts
    uint4 z = make_uint4(0, 0, 0, 0);
    *(uint4*)(p + i) = z;
}

// ---------- K2: fused q+v 1x1 conv as MFMA GEMM (3-term hi/lo); q stored fp16 ----------
__global__ __launch_bounds__(256) void pam_qv_mfma(
    const unsigned short* __restrict__ xTphi, const unsigned short* __restrict__ xTplo,
    const unsigned short* __restrict__ wqvFhi, const unsigned short* __restrict__ wqvFlo,
    const float* __restrict__ affQ, const float* __restrict__ bv,
    unsigned short* __restrict__ qF,
    unsigned short* __restrict__ vF) {
    int t = threadIdx.x;
    int h = blockIdx.x, b = blockIdx.y;
    int wv_ = t >> 6, lane = t & 63, g = lane >> 4, lm = lane & 15;
    int ct0 = wv_ * 5;

    f32x4 acc[5][4];
    #pragma unroll
    for (int m = 0; m < 5; m++)
        #pragma unroll
        for (int n = 0; n < 4; n++) acc[m][n] = (f32x4){0.f, 0.f, 0.f, 0.f};

    const unsigned short* xbh = xTphi + (((size_t)(b * 65) + h + 1) * 65 + 1) * 512 + (size_t)lm * 512 + g * 8;
    const unsigned short* xbl = xTplo + (((size_t)(b * 65) + h + 1) * 65 + 1) * 512 + (size_t)lm * 512 + g * 8;
    const unsigned short* wh = wqvFhi + (size_t)lane * 8;
    const unsigned short* wl = wqvFlo + (size_t)lane * 8;

    #pragma unroll 2
    for (int cs = 0; cs < 16; cs++) {
        int coff = cs * 32;
        bf16x8 bh[4], bl[4];
        #pragma unroll
        for (int nt = 0; nt < 4; nt++) {
            bh[nt] = *(const bf16x8*)(xbh + (size_t)nt * 16 * 512 + coff);
            bl[nt] = *(const bf16x8*)(xbl + (size_t)nt * 16 * 512 + coff);
        }
        bf16x8 ah[5], al[5];
        #pragma unroll
        for (int m = 0; m < 5; m++) {
            size_t aoff = (size_t)((ct0 + m) * 16 + cs) * 512;
            ah[m] = *(const bf16x8*)(wh + aoff);
            al[m] = *(const bf16x8*)(wl + aoff);
        }
        #pragma unroll
        for (int m = 0; m < 5; m++)
            #pragma unroll
            for (int n = 0; n < 4; n++) {
                acc[m][n] = __builtin_amdgcn_mfma_f32_16x16x32_bf16(ah[m], bh[n], acc[m][n], 0, 0, 0);
                acc[m][n] = __builtin_amdgcn_mfma_f32_16x16x32_bf16(ah[m], bl[n], acc[m][n], 0, 0, 0);
                acc[m][n] = __builtin_amdgcn_mfma_f32_16x16x32_bf16(al[m], bh[n], acc[m][n], 0, 0, 0);
            }
    }

    #pragma unroll
    for (int m = 0; m < 5; m++) {
        #pragma unroll
        for (int i = 0; i < 4; i++) {
            int R = (ct0 + m) * 16 + g * 4 + i;
            float shift = (R < 64) ? affQ[64 + R] : bv[R - 64];
            if (R < 64) {
                int s_ = R >> 5, gF = (R >> 3) & 3, jF = R & 7;
                #pragma unroll
                for (int nt = 0; nt < 4; nt++) {
                    int p = h * 64 + nt * 16 + lm;
                    float val = acc[m][nt][i] + shift;
                    size_t idx = (size_t)(b * 256 + (p >> 4)) * 1024 + s_ * 512 + gF * 128 + (p & 15) * 8 + jF;
                    qF[idx] = f_to_f16(val);
                }
            } else {
                int c = R - 64;
                #pragma unroll
                for (int nt = 0; nt < 4; nt++) {
                    int p = h * 64 + nt * 16 + lm;
                    float val = acc[m][nt][i] + shift;
                    size_t idx = (size_t)(b * 128 + (p >> 5)) * 8192 + (c >> 4) * 512 +
                                 ((p >> 3) & 3) * 128 + (c & 15) * 8 + (p & 7);
                    vF[idx] = (unsigned short)f_to_bf16(val);
                }
            }
        }
    }
}

// ---------- K3: k-conv as tap-decomposed MFMA GEMM, 16 waves, 4-way c-split; kF fp16 ----------
__global__ __launch_bounds__(1024, 4) void pam_kconv_mfma(
    const unsigned short* __restrict__ xTphi, const unsigned short* __restrict__ xTplo,
    const unsigned short* __restrict__ wkFhi, const unsigned short* __restrict__ wkFlo,
    const float* __restrict__ affK,
    unsigned short* __restrict__ kF) {
    __shared__ float red[3 * 4 * 64 * 8];   // 24 KiB
    int t = threadIdx.x;
    int hk = blockIdx.x, b = blockIdx.y;
    int wid = t >> 6, lane = t & 63, g = lane >> 4, lm = lane & 15;
    int dt = wid & 3, cq = wid >> 2;
    int goff = g * 8;
    f32x4 acc0 = (f32x4){0.f, 0.f, 0.f, 0.f};
    f32x4 acc1 = (f32x4){0.f, 0.f, 0.f, 0.f};
    #pragma unroll
    for (int r = 0; r < 3; r++) {
        size_t arow = ((size_t)(b * 65 + 2 * hk + r)) * 65 * 512;
        #pragma unroll
        for (int s = 0; s < 3; s++) {
            size_t aoff = arow + (size_t)(2 * lm + s) * 512 + goff;   // pixel wk=lm
            const unsigned short* pa0h = xTphi + aoff;
            const unsigned short* pa0l = xTplo + aoff;
            int tap = r * 3 + s;
            const unsigned short* pb_h = wkFhi + (((size_t)(tap * 4 + dt) * 16) * 64 + lane) * 8;
            const unsigned short* pb_l = wkFlo + (((size_t)(tap * 4 + dt) * 16) * 64 + lane) * 8;
            #pragma unroll
            for (int k = 0; k < 4; k++) {
                int c0 = cq * 128 + k * 32;
                bf16x8 a0h = *(const bf16x8*)(pa0h + c0);
                bf16x8 a1h = *(const bf16x8*)(pa0h + 32 * 512 + c0);   // pixel wk=lm+16
                bf16x8 a0l = *(const bf16x8*)(pa0l + c0);
                bf16x8 a1l = *(const bf16x8*)(pa0l + 32 * 512 + c0);
                bf16x8 bh  = *(const bf16x8*)(pb_h + (size_t)(c0 >> 5) * 512);
                bf16x8 bl  = *(const bf16x8*)(pb_l + (size_t)(c0 >> 5) * 512);
                acc0 = __builtin_amdgcn_mfma_f32_16x16x32_bf16(a0h, bh, acc0, 0, 0, 0);
                acc1 = __builtin_amdgcn_mfma_f32_16x16x32_bf16(a1h, bh, acc1, 0, 0, 0);
                acc0 = __builtin_amdgcn_mfma_f32_16x16x32_bf16(a0l, bh, acc0, 0, 0, 0);
                acc1 = __builtin_amdgcn_mfma_f32_16x16x32_bf16(a1l, bh, acc1, 0, 0, 0);
                acc0 = __builtin_amdgcn_mfma_f32_16x16x32_bf16(a0h, bl, acc0, 0, 0, 0);
                acc1 = __builtin_amdgcn_mfma_f32_16x16x32_bf16(a1h, bl, acc1, 0, 0, 0);
            }
        }
    }
    if (cq > 0) {
        float* dst = red + (((size_t)(cq - 1) * 4 + dt) * 64 + lane) * 8;
        *(f32x4*)dst = acc0;
        *(f32x4*)(dst + 4) = acc1;
    }
    __syncthreads();
    if (cq != 0) return;
    #pragma unroll
    for (int q = 0; q < 3; q++) {
        const float* src = red + (((size_t)q * 4 + dt) * 64 + lane) * 8;
        f32x4 p0 = *(const f32x4*)src;
        f32x4 p1 = *(const f32x4*)(src + 4);
        acc0 += p0; acc1 += p1;
    }
    int d = dt * 16 + lm;
    float sc = affK[d], sh = affK[64 + d];
    int s_ = d >> 5, gF = (d >> 3) & 3, jF = d & 7;
    #pragma unroll
    for (int i = 0; i < 4; i++) {
        int m1 = hk * 32 + g * 4 + i;         // acc0 pixel
        int m2 = m1 + 16;                     // acc1 pixel
        float v0 = fmaf(acc0[i], sc, sh);
        float v1 = fmaf(acc1[i], sc, sh);
        size_t i1 = (size_t)(b * 64 + (m1 >> 4)) * 1024 + s_ * 512 + gF * 128 + (m1 & 15) * 8 + jF;
        kF[i1] = f_to_f16(v0);
        size_t i2 = (size_t)(b * 64 + (m2 >> 4)) * 1024 + s_ * 512 + gF * 128 + (m2 & 15) * 8 + jF;
        kF[i2] = f_to_f16(v1);
    }
}

// ---------- K4: flash-style MFMA attention, fp16 Q/K energy, 32 m-rows/block, 4 n-phases ----------
// grid (8 b, 32 mt2), 1024 thr = 16 waves. Energy: 2 f16 MFMA/ftile.
// Per-XCD working set: Q 0.5MB + V 2MB << 4MiB L2; ~66KB LDS -> 2 blocks/CU.
__global__ __launch_bounds__(1024) void pam_attn(
    const unsigned short* __restrict__ qF,
    const unsigned short* __restrict__ kF,
    const unsigned short* __restrict__ vF, unsigned short* __restrict__ outsP) {
    __shared__ unsigned short Pl[32768];   // 64 KiB
    __shared__ float redM[2][8][16];
    __shared__ float redS[2][8][16];
    int t = threadIdx.x;
    int b = blockIdx.x, mt2 = blockIdx.y;
    int wid = t >> 6, lane = t & 63;
    int g = lane >> 4, lm = lane & 15;
    int mtl = wid & 1, wp = wid >> 1;

    size_t kidx = (size_t)(b * 64 + mt2 * 2 + mtl) * 1024 + g * 128 + lm * 8;
    f16x8 kf0 = *(const f16x8*)(kF + kidx);
    f16x8 kf1 = *(const f16x8*)(kF + kidx + 512);

    float Mrun[2][4], rsum[4];
    #pragma unroll
    for (int i = 0; i < 4; i++) { Mrun[0][i] = -3e38f; Mrun[1][i] = -3e38f; rsum[i] = 0.f; }
    f32x4 o00 = (f32x4){0.f,0.f,0.f,0.f}, o01 = o00, o10 = o00, o11 = o00;  // o[mt][parity]

    const unsigned short* qhb = qF + (size_t)(b * 256) * 1024 + g * 128 + lm * 8;
    const unsigned short* vb  = vF + (size_t)b * 1048576 + wid * 512 + g * 128 + lm * 8;

    for (int ph = 0; ph < 4; ++ph) {
        // --- energy: 8 ftiles (n = ph*1024 + wp*128 + [0,128)), fp16 K x fp16 Q ---
        f32x4 ev[8];
        #pragma unroll
        for (int f = 0; f < 8; f++) ev[f] = (f32x4){0.f, 0.f, 0.f, 0.f};
        int ft0 = ph * 64 + wp * 8;
        #pragma unroll
        for (int f = 0; f < 8; f++) {
            const unsigned short* qhp = qhb + (size_t)(ft0 + f) * 1024;
            f16x8 qf0 = *(const f16x8*)(qhp);
            f16x8 qf1 = *(const f16x8*)(qhp + 512);
            f32x4 e = ev[f];
            e = __builtin_amdgcn_mfma_f32_16x16x32_f16(kf0, qf0, e, 0, 0, 0);
            e = __builtin_amdgcn_mfma_f32_16x16x32_f16(kf1, qf1, e, 0, 0, 0);
            ev[f] = e;
        }
        // --- per-wave local max for own rows ---
        float pm[4];
        #pragma unroll
        for (int i = 0; i < 4; i++) {
            float m_ = ev[0][i];
            #pragma unroll
            for (int f = 1; f < 8; f++) m_ = fmaxf(m_, ev[f][i]);
            #pragma unroll
            for (int off = 1; off < 16; off <<= 1) m_ = fmaxf(m_, __shfl_xor(m_, off));
            pm[i] = m_;
        }
        __syncthreads();   // prev phase's PV (Pl reads) and redM reads complete
        if (lm == 0) {
            #pragma unroll
            for (int i = 0; i < 4; i++) redM[mtl][wp][g * 4 + i] = pm[i];
        }
        __syncthreads();
        // --- running max update + rescale factors ---
        float rfac[2][4];
        #pragma unroll
        for (int mt = 0; mt < 2; mt++) {
            #pragma unroll
            for (int i = 0; i < 4; i++) {
                float pmax = redM[mt][0][g * 4 + i];
                #pragma unroll
                for (int w2 = 1; w2 < 8; w2++) pmax = fmaxf(pmax, redM[mt][w2][g * 4 + i]);
                float Mn = fmaxf(Mrun[mt][i], pmax);
                rfac[mt][i] = __expf(Mrun[mt][i] - Mn);
                Mrun[mt][i] = Mn;
            }
        }
        #pragma unroll
        for (int i = 0; i < 4; i++) rsum[i] *= rfac[mtl][i];
        #pragma unroll
        for (int i = 0; i < 4; i++) {
            o00[i] *= rfac[0][i]; o01[i] *= rfac[0][i];
            o10[i] *= rfac[1][i]; o11[i] *= rfac[1][i];
        }
        // --- exp, bf16 round, sum of ROUNDED values, store P frag-linear ---
        #pragma unroll
        for (int f = 0; f < 8; f++) {
            int ntl = wp * 8 + f;            // local ntile 0..63
            int ks = ntl >> 1;               // 0..31
            int gF = (ntl & 1) * 2 + (lm >> 3);
            int jF = lm & 7;
            #pragma unroll
            for (int i = 0; i < 4; i++) {
                float p = __expf(ev[f][i] - Mrun[mtl][i]);
                uint32_t u = f_to_bf16(p);
                rsum[i] += bf16hi_to_f(u << 16);
                Pl[((ks * 4 + gF) * 32 + mtl * 16 + g * 4 + i) * 8 + jF] = (unsigned short)u;
            }
        }
        __syncthreads();   // P ready
        // --- PV: c-slice wid, both m-tiles, 2 parity chains each ---
        #pragma unroll 4
        for (int ks2 = 0; ks2 < 16; ks2++) {
            int ksA = ks2 * 2, ksB = ks2 * 2 + 1;
            bf16x8 bvA = *(const bf16x8*)(vb + (size_t)(ph * 32 + ksA) * 8192);
            bf16x8 paA0 = *(const bf16x8*)(Pl + ((ksA * 4 + g) * 32 + lm) * 8);
            bf16x8 paA1 = *(const bf16x8*)(Pl + ((ksA * 4 + g) * 32 + 16 + lm) * 8);
            o00 = __builtin_amdgcn_mfma_f32_16x16x32_bf16(paA0, bvA, o00, 0, 0, 0);
            o10 = __builtin_amdgcn_mfma_f32_16x16x32_bf16(paA1, bvA, o10, 0, 0, 0);
            bf16x8 bvB = *(const bf16x8*)(vb + (size_t)(ph * 32 + ksB) * 8192);
            bf16x8 paB0 = *(const bf16x8*)(Pl + ((ksB * 4 + g) * 32 + lm) * 8);
            bf16x8 paB1 = *(const bf16x8*)(Pl + ((ksB * 4 + g) * 32 + 16 + lm) * 8);
            o01 = __builtin_amdgcn_mfma_f32_16x16x32_bf16(paB0, bvB, o01, 0, 0, 0);
            o11 = __builtin_amdgcn_mfma_f32_16x16x32_bf16(paB1, bvB, o11, 0, 0, 0);
        }
    }

    // --- final sum reduction + normalize + write ---
    #pragma unroll
    for (int i = 0; i < 4; i++) {
        float s_ = rsum[i];
        #pragma unroll
        for (int off = 1; off < 16; off <<= 1) s_ += __shfl_xor(s_, off);
        rsum[i] = s_;
    }
    __syncthreads();
    if (lm == 0) {
        #pragma unroll
        for (int i = 0; i < 4; i++) redS[mtl][wp][g * 4 + i] = rsum[i];
    }
    __syncthreads();
    f32x4 of0 = o00 + o01;
    f32x4 of1 = o10 + o11;
    #pragma unroll
    for (int mt = 0; mt < 2; mt++) {
        #pragma unroll
        for (int i = 0; i < 4; i++) {
            float s_ = 0.f;
            #pragma unroll
            for (int w2 = 0; w2 < 8; w2++) s_ += redS[mt][w2][g * 4 + i];
            float sinv = 1.f / s_;
            int m = mt2 * 32 + mt * 16 + g * 4 + i;
            int hk2 = m >> 5, wk2 = m & 31;
            float ofv = (mt == 0) ? of0[i] : of1[i];
            outsP[(((size_t)(b * 33 + hk2)) * 33 + wk2) * 256 + wid * 16 + lm] =
                (unsigned short)f_to_bf16(ofv * sinv);
        }
    }
}

// ---------- K5: transpose-conv as balanced row-pair MFMA, frag-linear bf16 weights ----------
template<int LROW, int KH, int KW>
__device__ __forceinline__ void deconv_tap(
    const unsigned short* __restrict__ wdF,
    const char* lb, int ct0, int lane, int lm, f32x4 (&acc)[2][2][2]) {
    constexpr int wop = (KW == 1) ? 0 : 1;
    constexpr int dw = (KW == 0) ? 1 : 0;
    constexpr int tap = KH * 3 + KW;
    int g = lane >> 4;
    int p0 = LROW * 33 + lm + dw;
    int p1 = p0 + 16;
    uint32_t s0 = ((uint32_t)(p0 & 7)) << 4;
    uint32_t s1 = ((uint32_t)(p1 & 7)) << 4;
    uint32_t b0a = (uint32_t)p0 * 512 + (uint32_t)g * 16;
    uint32_t b1a = (uint32_t)p1 * 512 + (uint32_t)g * 16;
    const unsigned short* a0p = wdF + ((size_t)(tap * 32 + ct0) * 8) * 512 + lane * 8;
    const unsigned short* a1p = a0p + 8 * 512;     // ct0+1
    #pragma unroll
    for (int cs = 0; cs < 8; cs++) {
        bf16x8 bv0 = *(const bf16x8*)(lb + ((b0a + (uint32_t)cs * 64) ^ s0));
        bf16x8 bv1 = *(const bf16x8*)(lb + ((b1a + (uint32_t)cs * 64) ^ s1));
        bf16x8 a0 = *(const bf16x8*)(a0p + cs * 512);
        bf16x8 a1 = *(const bf16x8*)(a1p + cs * 512);
        acc[wop][0][0] = __builtin_amdgcn_mfma_f32_16x16x32_bf16(a0, bv0, acc[wop][0][0], 0, 0, 0);
        acc[wop][0][1] = __builtin_amdgcn_mfma_f32_16x16x32_bf16(a0, bv1, acc[wop][0][1], 0, 0, 0);
        acc[wop][1][0] = __builtin_amdgcn_mfma_f32_16x16x32_bf16(a1, bv0, acc[wop][1][0], 0, 0, 0);
        acc[wop][1][1] = __builtin_amdgcn_mfma_f32_16x16x32_bf16(a1, bv1, acc[wop][1][1], 0, 0, 0);
    }
}

__device__ __forceinline__ void deconv_epi(
    const f32x4 (&acc)[2][2][2], const float* __restrict__ affD,
    const float* __restrict__ x, float* __restrict__ out,
    int b, int ho, int co0, int lm, int g) {
    #pragma unroll
    for (int mf = 0; mf < 2; mf++) {
        #pragma unroll
        for (int i = 0; i < 4; i++) {
            int co = co0 + mf * 16 + g * 4 + i;
            float sc = affD[co], sh = affD[512 + co];
            const float* xr = x + (((size_t)b * 512 + co) * 64 + ho) * 64;
            float* orow = out + (((size_t)b * 512 + co) * 64 + ho) * 64;
            #pragma unroll
            for (int nf = 0; nf < 2; nf++) {
                int wp = nf * 16 + lm;
                float2 xv = *(const float2*)(xr + 2 * wp);
                float2 st;
                st.x = fmaxf(fmaf(acc[0][mf][nf][i], sc, sh), 0.f) + xv.x;
                st.y = fmaxf(fmaf(acc[1][mf][nf][i], sc, sh), 0.f) + xv.y;
                *(float2*)(orow + 2 * wp) = st;
            }
        }
    }
}

__global__ __launch_bounds__(1024, 4) void pam_deconv_mfma(
    const unsigned short* __restrict__ outsP,
    const unsigned short* __restrict__ wdF,
    const float* __restrict__ affD, const float* __restrict__ x, float* __restrict__ out) {
    __shared__ unsigned short Pb[16896];   // 2 rows x 33 px x 256 ci
    int t = threadIdx.x;
    int h0 = blockIdx.x, b = blockIdx.y;
    const unsigned short* src = outsP + ((size_t)(b * 33 + h0) * 33) * 256;
    for (int idx = t; idx < 2112; idx += 1024) {
        uint4 v = *(const uint4*)(src + (size_t)idx * 8);
        uint32_t byte = (uint32_t)idx * 16;
        byte ^= ((byte >> 9) & 7) << 4;
        *(uint4*)((char*)Pb + byte) = v;
    }
    __syncthreads();

    int wid = t >> 6, lane = t & 63, g = lane >> 4, lm = lane & 15;
    int ct0 = wid * 2, co0 = wid * 32;
    const char* lb = (const char*)Pb;

    {   // even output row ho = 2*h0 : kh=1, B row h0 (LDS row 0)
        f32x4 acc[2][2][2];
        #pragma unroll
        for (int a = 0; a < 2; a++)
            #pragma unroll
            for (int m = 0; m < 2; m++)
                #pragma unroll
                for (int n = 0; n < 2; n++) acc[a][m][n] = (f32x4){0.f, 0.f, 0.f, 0.f};
        deconv_tap<0, 1, 0>(wdF, lb, ct0, lane, lm, acc);
        deconv_tap<0, 1, 1>(wdF, lb, ct0, lane, lm, acc);
        deconv_tap<0, 1, 2>(wdF, lb, ct0, lane, lm, acc);
        deconv_epi(acc, affD, x, out, b, 2 * h0, co0, lm, g);
    }
    {   // odd output row ho = 2*h0+1 : kh=2 B row h0, kh=0 B row h0+1
        f32x4 acc[2][2][2];
        #pragma unroll
        for (int a = 0; a < 2; a++)
            #pragma unroll
            for (int m = 0; m < 2; m++)
                #pragma unroll
                for (int n = 0; n < 2; n++) acc[a][m][n] = (f32x4){0.f, 0.f, 0.f, 0.f};
        deconv_tap<0, 2, 0>(wdF, lb, ct0, lane, lm, acc);
        deconv_tap<0, 2, 1>(wdF, lb, ct0, lane, lm, acc);
        deconv_tap<0, 2, 2>(wdF, lb, ct0, lane, lm, acc);
        deconv_tap<1, 0, 0>(wdF, lb, ct0, lane, lm, acc);
        deconv_tap<1, 0, 1>(wdF, lb, ct0, lane, lm, acc);
        deconv_tap<1, 0, 2>(wdF, lb, ct0, lane, lm, acc);
        deconv_epi(acc, affD, x, out, b, 2 * h0 + 1, co0, lm, g);
    }
}

// ---------- launcher ----------
extern "C" void kernel_launch(void* const* d_in, const int* in_sizes, int n_in,
                              void* d_out, int out_size, void* d_ws, size_t ws_size,
                              hipStream_t stream) {
    const float* x   = (const float*)d_in[0];
    const float* w_q = (const float*)d_in[1];
    const float* b_q = (const float*)d_in[2];
    const float* qs  = (const float*)d_in[3];
    const float* qb  = (const float*)d_in[4];
    const float* qm  = (const float*)d_in[5];
    const float* qv  = (const float*)d_in[6];
    const float* w_k = (const float*)d_in[7];
    const float* b_k = (const float*)d_in[8];
    const float* ks  = (const float*)d_in[9];
    const float* kb  = (const float*)d_in[10];
    const float* km  = (const float*)d_in[11];
    const float* kv  = (const float*)d_in[12];
    const float* w_v = (const float*)d_in[13];
    const float* b_v = (const float*)d_in[14];
    const float* w_d = (const float*)d_in[15];
    const float* ds  = (const float*)d_in[16];
    const float* db  = (const float*)d_in[17];
    const float* dm  = (const float*)d_in[18];
    const float* dv  = (const float*)d_in[19];
    float* out = (float*)d_out;

    char* wsb = (char*)d_ws;
    unsigned short* qF    = (unsigned short*)(wsb);               //  4,194,304 (f16, half used)
    unsigned short* vF    = (unsigned short*)(wsb + 8388608);     // 16,777,216
    unsigned short* kF    = (unsigned short*)(wsb + 25165824);    //  1,048,576 (f16)
    unsigned short* wkFhi = (unsigned short*)(wsb + 27262976);    //    589,824
    unsigned short* wkFlo = (unsigned short*)(wsb + 27852800);    //    589,824
    float*          affQ  = (float*)(wsb + 28442624);             //        512
    float*          affK  = (float*)(wsb + 28443136);             //        512
    float*          affD  = (float*)(wsb + 28443648);             //      4,096
    // wqvF aliases the region after kF (dead until kconv, which runs after qv).
    unsigned short* wqvFhi = (unsigned short*)(wsb + 26214400);   //    327,680
    unsigned short* wqvFlo = (unsigned short*)(wsb + 26542080);   //    327,680
    // X region: xTp{hi,lo} live [pam_xt .. pam_kconv_mfma]; then reused:
    unsigned short* xTphi = (unsigned short*)(wsb + 28447744);    // 34,611,200
    unsigned short* xTplo = (unsigned short*)(wsb + 63058944);    // 34,611,200 -> end 97,670,144
    unsigned short* outsP = (unsigned short*)(wsb + 28447744);    //  4,460,544 (alias)
    unsigned short* wdF   = (unsigned short*)(wsb + 32908288);    //  2,359,296 (alias)

    hipLaunchKernelGGL(pam_aff_kernel, dim3(1), dim3(640), 0, stream,
                       b_q, qs, qb, qm, qv, b_k, ks, kb, km, kv, ds, db, dm, dv,
                       affQ, affK, affD);
    hipLaunchKernelGGL(pam_wkt, dim3(1152), dim3(256), 0, stream, w_k, wkFhi, wkFlo);
    hipLaunchKernelGGL(pam_wqv, dim3(640), dim3(256), 0, stream, w_q, w_v, affQ, wqvFhi, wqvFlo);
    hipLaunchKernelGGL(pam_xt, dim3(65, 8), dim3(256), 0, stream, x, xTphi, xTplo);
    hipLaunchKernelGGL(pam_qv_mfma, dim3(64, 8), dim3(256), 0, stream,
                       xTphi, xTplo, wqvFhi, wqvFlo, affQ, b_v, qF, vF);
    hipLaunchKernelGGL(pam_kconv_mfma, dim3(32, 8), dim3(1024), 0, stream,
                       xTphi, xTplo, wkFhi, wkFlo, affK, kF);
    // xTp dead from here; aliased region reused for outsP / wdF.
    hipLaunchKernelGGL(pam_wdtb, dim3(4608), dim3(256), 0, stream, w_d, wdF);
    hipLaunchKernelGGL(pam_zeroP, dim3(1089), dim3(256), 0, stream, outsP);
    hipLaunchKernelGGL(pam_attn, dim3(8, 32), dim3(1024), 0, stream,
                       qF, kF, vF, outsP);
    hipLaunchKernelGGL(pam_deconv_mfma, dim3(32, 8), dim3(1024), 0, stream,
                       outsP, wdF, affD, x, out);
}